// Round 9
// baseline (881.940 us; speedup 1.0000x reference)
//
#include <hip/hip_runtime.h>
#include <hip/hip_bf16.h>

// ---------------- constants ----------------
#define BQ 2
#define NQ 1024
#define CM 256
#define HEADS 8
#define DH 32
#define FFD 2048
#define TV 16
#define HV 128
#define WV 128
#define TD 8
#define HD 16
#define WD 16
#define LS 2048              // TD*HD*WD samples per group
#define NG 16                // B * HEADS groups
#define MROWS 2048           // B*NQ token rows

// ---------------- generic f32 NT GEMM 64x64: C = A@W^T (+bias)(+res)(+relu) ----------------
template <bool RELU>
__global__ __launch_bounds__(256) void gemm_nt(const float* __restrict__ A,
                                               const float* __restrict__ Wt,
                                               const float* __restrict__ bias,
                                               const float* __restrict__ res,
                                               float* __restrict__ C,
                                               int M, int N, int K) {
  __shared__ float As[16 * 68];
  __shared__ float Ws[16 * 68];
  const int tm = threadIdx.x & 15;
  const int tn = threadIdx.x >> 4;
  const int m0 = blockIdx.x * 64, n0 = blockIdx.y * 64;
  const int lr = threadIdx.x >> 2;
  const int lk = (threadIdx.x & 3) * 4;
  float acc[4][4] = {};
  for (int k0 = 0; k0 < K; k0 += 16) {
    float4 a4 = *(const float4*)(A + (size_t)(m0 + lr) * K + k0 + lk);
    float4 w4 = *(const float4*)(Wt + (size_t)(n0 + lr) * K + k0 + lk);
    As[(lk + 0) * 68 + lr] = a4.x;
    As[(lk + 1) * 68 + lr] = a4.y;
    As[(lk + 2) * 68 + lr] = a4.z;
    As[(lk + 3) * 68 + lr] = a4.w;
    Ws[(lk + 0) * 68 + lr] = w4.x;
    Ws[(lk + 1) * 68 + lr] = w4.y;
    Ws[(lk + 2) * 68 + lr] = w4.z;
    Ws[(lk + 3) * 68 + lr] = w4.w;
    __syncthreads();
#pragma unroll
    for (int k = 0; k < 16; ++k) {
      float4 av = *(const float4*)&As[k * 68 + tm * 4];
      float4 wv = *(const float4*)&Ws[k * 68 + tn * 4];
      float a[4] = {av.x, av.y, av.z, av.w};
      float w[4] = {wv.x, wv.y, wv.z, wv.w};
#pragma unroll
      for (int i = 0; i < 4; ++i)
#pragma unroll
        for (int j = 0; j < 4; ++j) acc[i][j] += a[i] * w[j];
    }
    __syncthreads();
  }
#pragma unroll
  for (int i = 0; i < 4; ++i) {
    const int row = m0 + tm * 4 + i;
    const int col = n0 + tn * 4;
    float4 bv = bias ? *(const float4*)(bias + col) : make_float4(0.f, 0.f, 0.f, 0.f);
    float4 rv = res ? *(const float4*)(res + (size_t)row * N + col) : make_float4(0.f, 0.f, 0.f, 0.f);
    float4 o;
    o.x = acc[i][0] + bv.x + rv.x;
    o.y = acc[i][1] + bv.y + rv.y;
    o.z = acc[i][2] + bv.z + rv.z;
    o.w = acc[i][3] + bv.w + rv.w;
    if (RELU) {
      o.x = fmaxf(o.x, 0.f); o.y = fmaxf(o.y, 0.f);
      o.z = fmaxf(o.z, 0.f); o.w = fmaxf(o.w, 0.f);
    }
    *(float4*)(C + (size_t)row * N + col) = o;
  }
}

// ---------------- 128x128-tile f32 NT GEMM, 8x8 acc/thread ----------------
template <bool RELU>
__global__ __launch_bounds__(256) void gemm_nt128(const float* __restrict__ A,
                                                  const float* __restrict__ Wt,
                                                  const float* __restrict__ bias,
                                                  const float* __restrict__ res,
                                                  float* __restrict__ C,
                                                  int M, int N, int K) {
  __shared__ float As[8][132];
  __shared__ float Bs[8][132];
  const int tid = threadIdx.x;
  const int tm = tid & 15, tn = tid >> 4;
  const int m0 = blockIdx.x * 128, n0 = blockIdx.y * 128;
  const int lr = tid >> 1, lk = (tid & 1) * 4;
  float acc[8][8] = {};
  const float* Ap = A + (size_t)(m0 + lr) * K + lk;
  const float* Wp = Wt + (size_t)(n0 + lr) * K + lk;
  for (int k0 = 0; k0 < K; k0 += 8) {
    float4 a4 = *(const float4*)(Ap + k0);
    float4 w4 = *(const float4*)(Wp + k0);
    __syncthreads();
    As[lk + 0][lr] = a4.x; As[lk + 1][lr] = a4.y; As[lk + 2][lr] = a4.z; As[lk + 3][lr] = a4.w;
    Bs[lk + 0][lr] = w4.x; Bs[lk + 1][lr] = w4.y; Bs[lk + 2][lr] = w4.z; Bs[lk + 3][lr] = w4.w;
    __syncthreads();
#pragma unroll
    for (int k = 0; k < 8; ++k) {
      float4 a0 = *(const float4*)&As[k][tm * 8];
      float4 a1 = *(const float4*)&As[k][tm * 8 + 4];
      float4 w0 = *(const float4*)&Bs[k][tn * 8];
      float4 w1 = *(const float4*)&Bs[k][tn * 8 + 4];
      float av[8] = {a0.x, a0.y, a0.z, a0.w, a1.x, a1.y, a1.z, a1.w};
      float wv[8] = {w0.x, w0.y, w0.z, w0.w, w1.x, w1.y, w1.z, w1.w};
#pragma unroll
      for (int i = 0; i < 8; ++i)
#pragma unroll
        for (int j = 0; j < 8; ++j) acc[i][j] += av[i] * wv[j];
    }
  }
#pragma unroll
  for (int i = 0; i < 8; ++i) {
    const int row = m0 + tm * 8 + i;
#pragma unroll
    for (int jj = 0; jj < 2; ++jj) {
      const int col = n0 + tn * 8 + jj * 4;
      float4 o = make_float4(acc[i][jj * 4 + 0], acc[i][jj * 4 + 1],
                             acc[i][jj * 4 + 2], acc[i][jj * 4 + 3]);
      if (bias) {
        float4 bv = *(const float4*)(bias + col);
        o.x += bv.x; o.y += bv.y; o.z += bv.z; o.w += bv.w;
      }
      if (res) {
        float4 rv = *(const float4*)(res + (size_t)row * N + col);
        o.x += rv.x; o.y += rv.y; o.z += rv.z; o.w += rv.w;
      }
      if (RELU) {
        o.x = fmaxf(o.x, 0.f); o.y = fmaxf(o.y, 0.f);
        o.z = fmaxf(o.z, 0.f); o.w = fmaxf(o.w, 0.f);
      }
      *(float4*)(C + (size_t)row * N + col) = o;
    }
  }
}

// ---------------- split-K 64x64 GEMM: P[slice][M][N] partials ----------------
__global__ __launch_bounds__(256) void gemm_nt_sk(const float* __restrict__ A,
                                                  const float* __restrict__ Wt,
                                                  float* __restrict__ P,
                                                  int M, int N, int K, int KS) {
  __shared__ float As[16 * 68];
  __shared__ float Ws[16 * 68];
  const int tm = threadIdx.x & 15;
  const int tn = threadIdx.x >> 4;
  const int m0 = blockIdx.x * 64, n0 = blockIdx.y * 64;
  const int kb = blockIdx.z * KS;
  const int lr = threadIdx.x >> 2;
  const int lk = (threadIdx.x & 3) * 4;
  float acc[4][4] = {};
  for (int k0 = kb; k0 < kb + KS; k0 += 16) {
    float4 a4 = *(const float4*)(A + (size_t)(m0 + lr) * K + k0 + lk);
    float4 w4 = *(const float4*)(Wt + (size_t)(n0 + lr) * K + k0 + lk);
    As[(lk + 0) * 68 + lr] = a4.x;
    As[(lk + 1) * 68 + lr] = a4.y;
    As[(lk + 2) * 68 + lr] = a4.z;
    As[(lk + 3) * 68 + lr] = a4.w;
    Ws[(lk + 0) * 68 + lr] = w4.x;
    Ws[(lk + 1) * 68 + lr] = w4.y;
    Ws[(lk + 2) * 68 + lr] = w4.z;
    Ws[(lk + 3) * 68 + lr] = w4.w;
    __syncthreads();
#pragma unroll
    for (int k = 0; k < 16; ++k) {
      float4 av = *(const float4*)&As[k * 68 + tm * 4];
      float4 wv = *(const float4*)&Ws[k * 68 + tn * 4];
      float a[4] = {av.x, av.y, av.z, av.w};
      float w[4] = {wv.x, wv.y, wv.z, wv.w};
#pragma unroll
      for (int i = 0; i < 4; ++i)
#pragma unroll
        for (int j = 0; j < 4; ++j) acc[i][j] += a[i] * w[j];
    }
    __syncthreads();
  }
  float* Pb = P + (size_t)blockIdx.z * M * N;
#pragma unroll
  for (int i = 0; i < 4; ++i) {
    const int row = m0 + tm * 4 + i;
    const int col = n0 + tn * 4;
    *(float4*)(Pb + (size_t)row * N + col) =
        make_float4(acc[i][0], acc[i][1], acc[i][2], acc[i][3]);
  }
}

// ---------------- split-K reduce (+bias+res), N must be 256 ----------------
__global__ __launch_bounds__(256) void skred_kernel(const float* __restrict__ P,
                                                    const float* __restrict__ bias,
                                                    const float* __restrict__ res,
                                                    float* __restrict__ C) {
  const int idx = blockIdx.x * 256 + threadIdx.x;   // MROWS*CM/4 = 131072
  const int col4 = idx & 63;
  const int row = idx >> 6;
  const float4* P4 = (const float4*)P;
  const int MN4 = MROWS * CM / 4;
  float4 s = P4[idx];
  float4 s1 = P4[idx + MN4];
  float4 s2 = P4[idx + 2 * MN4];
  float4 s3 = P4[idx + 3 * MN4];
  s.x += s1.x + s2.x + s3.x;
  s.y += s1.y + s2.y + s3.y;
  s.z += s1.z + s2.z + s3.z;
  s.w += s1.w + s2.w + s3.w;
  float4 bv = ((const float4*)bias)[col4];
  float4 rv = ((const float4*)(res + (size_t)row * CM))[col4];
  s.x += bv.x + rv.x; s.y += bv.y + rv.y;
  s.z += bv.z + rv.z; s.w += bv.w + rv.w;
  ((float4*)C)[idx] = s;
}

// ---------------- self-attention: single-pass flash (scores provably tiny -> no max) ----------------
#define SKC 64
#define SNC (NQ / SKC)
__global__ __launch_bounds__(256) void sa_flash_kernel(const float* __restrict__ qkv,
                                                       float* __restrict__ o) {
  __shared__ float Qs[16][36];
  __shared__ float Ks[SKC][36];
  __shared__ float Vs[SKC][36];
  __shared__ float Ps[16][68];
  __shared__ float Ored[8 * 16 * 32];

  const int swz = (blockIdx.x & 7) * 128 + (blockIdx.x >> 3);
  const int bh = swz >> 6, qt = swz & 63;
  const int n0 = qt * 16;
  const int b = bh >> 3, h = bh & 7;
  const int tid = threadIdx.x;
  const int lane = tid & 63, wave = tid >> 6;

  const float* rowbase = qkv + (size_t)b * NQ * 768 + h * DH;

  if (tid < 128) {
    const int r = tid >> 3, c4 = (tid & 7) * 4;
    *(float4*)&Qs[r][c4] = *(const float4*)(rowbase + (size_t)(n0 + r) * 768 + c4);
  }
  __syncthreads();

  const int dslot = (tid >> 3) & 7;
  const int kg = tid & 7;
  float ssum[4] = {0.f, 0.f, 0.f, 0.f};
  float o0[4] = {}, o1[4] = {}, o2[4] = {}, o3[4] = {};

#pragma unroll 1
  for (int c = 0; c < SNC; ++c) {
    {
      const int r0 = tid >> 3, c40 = (tid & 7) * 4;
      const int r1 = r0 + 32;
      *(float4*)&Ks[r0][c40] =
          *(const float4*)(rowbase + (size_t)(c * SKC + r0) * 768 + 256 + c40);
      *(float4*)&Ks[r1][c40] =
          *(const float4*)(rowbase + (size_t)(c * SKC + r1) * 768 + 256 + c40);
      *(float4*)&Vs[r0][c40] =
          *(const float4*)(rowbase + (size_t)(c * SKC + r0) * 768 + 512 + c40);
      *(float4*)&Vs[r1][c40] =
          *(const float4*)(rowbase + (size_t)(c * SKC + r1) * 768 + 512 + c40);
    }
    __syncthreads();
    float4 kr[8];
#pragma unroll
    for (int d4 = 0; d4 < 8; ++d4) kr[d4] = *(const float4*)&Ks[lane][d4 * 4];
#pragma unroll
    for (int qi = 0; qi < 4; ++qi) {
      const int q = wave * 4 + qi;
      float s = 0.f;
#pragma unroll
      for (int d4 = 0; d4 < 8; ++d4) {
        float4 q4 = *(const float4*)&Qs[q][d4 * 4];
        s += q4.x * kr[d4].x + q4.y * kr[d4].y + q4.z * kr[d4].z + q4.w * kr[d4].w;
      }
      const float e = __expf(s * 0.17677669529663687f);
      ssum[qi] += e;
      Ps[q][lane] = e;
    }
#pragma unroll
    for (int j = 0; j < 8; ++j) {
      const int kk = kg * 8 + j;
      float4 v4 = *(const float4*)&Vs[kk][dslot * 4];
      const float p0 = Ps[wave * 4 + 0][kk];
      const float p1 = Ps[wave * 4 + 1][kk];
      const float p2 = Ps[wave * 4 + 2][kk];
      const float p3 = Ps[wave * 4 + 3][kk];
      o0[0] += p0 * v4.x; o0[1] += p0 * v4.y; o0[2] += p0 * v4.z; o0[3] += p0 * v4.w;
      o1[0] += p1 * v4.x; o1[1] += p1 * v4.y; o1[2] += p1 * v4.z; o1[3] += p1 * v4.w;
      o2[0] += p2 * v4.x; o2[1] += p2 * v4.y; o2[2] += p2 * v4.z; o2[3] += p2 * v4.w;
      o3[0] += p3 * v4.x; o3[1] += p3 * v4.y; o3[2] += p3 * v4.z; o3[3] += p3 * v4.w;
    }
    __syncthreads();
  }

  float inv[4];
#pragma unroll
  for (int qi = 0; qi < 4; ++qi) {
    float ss = ssum[qi];
#pragma unroll
    for (int off = 32; off > 0; off >>= 1) ss += __shfl_xor(ss, off, 64);
    inv[qi] = 1.f / ss;
  }

#pragma unroll
  for (int j = 0; j < 4; ++j) {
    Ored[kg * (16 * 32) + (wave * 4 + 0) * 32 + dslot * 4 + j] = o0[j] * inv[0];
    Ored[kg * (16 * 32) + (wave * 4 + 1) * 32 + dslot * 4 + j] = o1[j] * inv[1];
    Ored[kg * (16 * 32) + (wave * 4 + 2) * 32 + dslot * 4 + j] = o2[j] * inv[2];
    Ored[kg * (16 * 32) + (wave * 4 + 3) * 32 + dslot * 4 + j] = o3[j] * inv[3];
  }
  __syncthreads();
#pragma unroll
  for (int i = 0; i < 2; ++i) {
    const int idx = tid * 2 + i;
    const int q = idx >> 5, d = idx & 31;
    float s = 0.f;
#pragma unroll
    for (int k = 0; k < 8; ++k) s += Ored[k * (16 * 32) + q * 32 + d];
    o[((size_t)(b * NQ + n0 + q)) * CM + h * DH + d] = s;
  }
}

// ---------------- layer norm (one wave per 256-dim row), f32 out ----------------
__global__ __launch_bounds__(256) void ln_kernel(const float* __restrict__ in,
                                                 const float* __restrict__ w,
                                                 const float* __restrict__ b,
                                                 float* __restrict__ out) {
  const int wv = threadIdx.x >> 6, lane = threadIdx.x & 63;
  const int row = blockIdx.x * 4 + wv;
  float4 v = ((const float4*)(in + (size_t)row * CM))[lane];
  float s = v.x + v.y + v.z + v.w;
#pragma unroll
  for (int off = 32; off > 0; off >>= 1) s += __shfl_xor(s, off, 64);
  const float mu = s * (1.f / 256.f);
  float dx = v.x - mu, dy = v.y - mu, dz = v.z - mu, dw = v.w - mu;
  float q = dx * dx + dy * dy + dz * dz + dw * dw;
#pragma unroll
  for (int off = 32; off > 0; off >>= 1) q += __shfl_xor(q, off, 64);
  const float r = rsqrtf(q * (1.f / 256.f) + 1e-5f);
  float4 wv4 = ((const float4*)w)[lane];
  float4 bv4 = ((const float4*)b)[lane];
  float4 o;
  o.x = dx * r * wv4.x + bv4.x;
  o.y = dy * r * wv4.y + bv4.y;
  o.z = dz * r * wv4.z + bv4.z;
  o.w = dw * r * wv4.w + bv4.w;
  ((float4*)(out + (size_t)row * CM))[lane] = o;
}

// ---------------- depthwise strided conv v3: LDS plane staging ----------------
// block = (cid, zh, yh): 2048 blocks x 128 threads. Stage 66-row slab of each
// z-plane into LDS (coalesced float4), compute 10-wide windows from LDS.
__global__ __launch_bounds__(128) void conv_off3_kernel(const float* __restrict__ gt,
                                                        const float* __restrict__ w1,
                                                        const float* __restrict__ b1,
                                                        float* __restrict__ off1) {
  const int bid = blockIdx.x;
  const int yh = bid & 1, zh = (bid >> 1) & 1, cid = bid >> 2;
  const int c = cid & 31;
  const int tid = threadIdx.x;
  const int xo = tid & 15, yo8 = tid >> 4;     // yo8: 0..7
  __shared__ float pl[66 * 132];
  const float* __restrict__ xp = gt + (size_t)cid * (TV * HV * WV);
  const float* __restrict__ wc = w1 + c * 400;
  const int ygbase = yh * 64 - 1;              // global y of pl row 0
  float acc[4] = {0.f, 0.f, 0.f, 0.f};

#pragma unroll
  for (int zz = 0; zz < 10; ++zz) {
    const int z = 8 * zh - 1 + zz;
    const int idxA = zz >> 1, idxB = idxA - 1; // compile-time acc indices
    const int kzA = zz & 1, kzB = kzA + 2;
    if (z >= 0 && z <= 15) {                   // block-uniform
      __syncthreads();
      const float* __restrict__ zp = xp + (size_t)z * (HV * WV);
      for (int i = tid; i < 66 * 32; i += 128) {
        const int r = i >> 5, q = i & 31;
        const int y = ygbase + r;
        float4 f = make_float4(0.f, 0.f, 0.f, 0.f);
        if ((unsigned)y < 128u) f = *(const float4*)(zp + y * WV + q * 4);
        *(float4*)&pl[r * 132 + q * 4] = f;
      }
      __syncthreads();
#pragma unroll 1
      for (int ky = 0; ky < 10; ++ky) {
        const int r = yo8 * 8 + ky;
        const float* __restrict__ row = &pl[r * 132];
        const float left = (xo > 0) ? row[8 * xo - 1] : 0.f;
        const float4 A0 = *(const float4*)&row[8 * xo];
        const float4 A1 = *(const float4*)&row[8 * xo + 4];
        const float right = (xo < 15) ? row[8 * xo + 8] : 0.f;
        if (idxA < 4) {
          const float* wr = wc + kzA * 100 + ky * 10;
          acc[idxA & 3] += wr[0] * left + wr[1] * A0.x + wr[2] * A0.y + wr[3] * A0.z +
                           wr[4] * A0.w + wr[5] * A1.x + wr[6] * A1.y + wr[7] * A1.z +
                           wr[8] * A1.w + wr[9] * right;
        }
        if (idxB >= 0) {
          const float* wr = wc + kzB * 100 + ky * 10;
          acc[idxB & 3] += wr[0] * left + wr[1] * A0.x + wr[2] * A0.y + wr[3] * A0.z +
                           wr[4] * A0.w + wr[5] * A1.x + wr[6] * A1.y + wr[7] * A1.z +
                           wr[8] * A1.w + wr[9] * right;
        }
      }
    }
  }

  const float bias = b1[c];
  const int yo = yh * 8 + yo8;
#pragma unroll
  for (int i = 0; i < 4; ++i) {
    const int zo = zh * 4 + i;
    float a = acc[i] + bias;
    const float u = 0.7978845608028654f * (a + 0.044715f * a * a * a);
    const float gv = 0.5f * a * (1.f + tanhf(u));
    off1[((size_t)cid * TD + zo) * (HD * WD) + yo * WD + xo] = gv;
  }
}

// ---------------- offset projection + tanh*scale + pixel coords ----------------
__global__ __launch_bounds__(256) void offproj_kernel(const float* __restrict__ off1,
                                                      const float* __restrict__ w2,
                                                      float* __restrict__ pc) {
  const int gid = blockIdx.x * 256 + threadIdx.x;  // 16*2048
  const int bg = gid >> 11, sp = gid & 2047;
  const float* base = off1 + (size_t)bg * 32 * LS + sp;
  float o0 = 0.f, o1 = 0.f, o2 = 0.f;
#pragma unroll
  for (int c = 0; c < 32; ++c) {
    const float v = base[(size_t)c * LS];
    o0 += w2[c] * v;
    o1 += w2[32 + c] * v;
    o2 += w2[64 + c] * v;
  }
  const int gz = sp >> 8, gy = (sp >> 4) & 15, gx = sp & 15;
  const float oz = tanhf(o0) * 2.f;
  const float oy = tanhf(o1) * 8.f;
  const float ox = tanhf(o2) * 8.f;
  float* p = pc + (size_t)gid * 3;
  p[0] = ((float)gz + oz) * (16.f / 7.f) - 0.5f;
  p[1] = ((float)gy + oy) * (128.f / 15.f) - 0.5f;
  p[2] = ((float)gx + ox) * (128.f / 15.f) - 0.5f;
}

// ---------------- trilinear grid sample + per-group k/v projection ----------------
__global__ __launch_bounds__(256) void gsample_kernel(const float* __restrict__ gt,
                                                      const float* __restrict__ pc,
                                                      const float* __restrict__ kw,
                                                      const float* __restrict__ vw,
                                                      float* __restrict__ kbuf,
                                                      float* __restrict__ vbuf) {
  __shared__ float kvv[8][33];
  __shared__ float kws[32][33], vws[32][33];
  const int swz = (blockIdx.x & 7) * 512 + (blockIdx.x >> 3);
  const int bg = swz >> 8, l0 = (swz & 255) * 8;
  const int g = bg & 7;
  const int s = threadIdx.x >> 5, c = threadIdx.x & 31;
  for (int i = threadIdx.x; i < 1024; i += 256) {
    kws[i >> 5][i & 31] = kw[g * 1024 + i];
    vws[i >> 5][i & 31] = vw[g * 1024 + i];
  }
  const int l = l0 + s;
  const float* p = pc + ((size_t)bg * LS + l) * 3;
  const float pz = p[0], py = p[1], px = p[2];
  const float zf = floorf(pz), yf = floorf(py), xf = floorf(px);
  const int z0 = (int)zf, y0 = (int)yf, x0 = (int)xf;
  const float fz = pz - zf, fy = py - yf, fx = px - xf;
  const float* vp = gt + (size_t)(bg * 32 + c) * (TV * HV * WV);
  float acc = 0.f;
#pragma unroll
  for (int dz = 0; dz < 2; ++dz) {
    const int z = z0 + dz;
    if ((unsigned)z >= (unsigned)TV) continue;
    const float wz = dz ? fz : 1.f - fz;
#pragma unroll
    for (int dy = 0; dy < 2; ++dy) {
      const int y = y0 + dy;
      if ((unsigned)y >= (unsigned)HV) continue;
      const float wzy = wz * (dy ? fy : 1.f - fy);
#pragma unroll
      for (int dx = 0; dx < 2; ++dx) {
        const int x = x0 + dx;
        if ((unsigned)x >= (unsigned)WV) continue;
        acc += wzy * (dx ? fx : 1.f - fx) * vp[((size_t)z * HV + y) * WV + x];
      }
    }
  }
  kvv[s][c] = acc;
  __syncthreads();
  float ka = 0.f, va = 0.f;
#pragma unroll
  for (int f = 0; f < 32; ++f) {
    const float kv = kvv[s][f];
    ka += kws[c][f] * kv;
    va += vws[c][f] * kv;
  }
  kbuf[((size_t)bg * LS + l) * 32 + c] = ka;
  vbuf[((size_t)bg * LS + l) * 32 + c] = va;
}

// ---------------- deformable attention: single pass + in-kernel normalize tail ----------------
#define DQT 16
#define DKC 64
#define DNC (LS / DKC)
__global__ __launch_bounds__(256) void dattn_kernel(const float* __restrict__ qb,
                                                    const float* __restrict__ kbuf,
                                                    const float* __restrict__ vbuf,
                                                    float* __restrict__ da_o,
                                                    float* __restrict__ attn_out) {
  __shared__ float Qs[DQT][36];
  __shared__ float Ks[DKC][36];
  __shared__ float Vs[DKC][36];
  __shared__ float Ps[DQT][68];
  __shared__ float Ored[8 * DQT * 32];
  __shared__ float invs[DQT];

  const int swz = (blockIdx.x & 7) * 128 + (blockIdx.x >> 3);
  const int bg = swz >> 6, qt = swz & 63;
  const int n0 = qt * DQT;
  const int b = bg >> 3, g = bg & 7;
  const int tid = threadIdx.x;
  const int lane = tid & 63, wave = tid >> 6;

  const float* kB = kbuf + (size_t)bg * LS * 32;
  const float* vB = vbuf + (size_t)bg * LS * 32;

  if (tid < 128) {
    const int r = tid >> 3, c4 = (tid & 7) * 4;
    *(float4*)&Qs[r][c4] =
        *(const float4*)(qb + ((size_t)(b * NQ + n0 + r)) * CM + g * DH + c4);
  }
  __syncthreads();

  const int dslot = (tid >> 3) & 7;
  const int kg = tid & 7;
  float ssum[4] = {0.f, 0.f, 0.f, 0.f};
  float o0[4] = {}, o1[4] = {}, o2[4] = {}, o3[4] = {};

#pragma unroll 1
  for (int c = 0; c < DNC; ++c) {
    {
      const int r0 = tid >> 3, c40 = (tid & 7) * 4;
      const int r1 = r0 + 32;
      *(float4*)&Ks[r0][c40] = *(const float4*)(kB + (size_t)(c * DKC + r0) * 32 + c40);
      *(float4*)&Ks[r1][c40] = *(const float4*)(kB + (size_t)(c * DKC + r1) * 32 + c40);
      *(float4*)&Vs[r0][c40] = *(const float4*)(vB + (size_t)(c * DKC + r0) * 32 + c40);
      *(float4*)&Vs[r1][c40] = *(const float4*)(vB + (size_t)(c * DKC + r1) * 32 + c40);
    }
    __syncthreads();
    float4 kr[8];
#pragma unroll
    for (int d4 = 0; d4 < 8; ++d4) kr[d4] = *(const float4*)&Ks[lane][d4 * 4];
#pragma unroll
    for (int qi = 0; qi < 4; ++qi) {
      const int q = wave * 4 + qi;
      float s = 0.f;
#pragma unroll
      for (int d4 = 0; d4 < 8; ++d4) {
        float4 q4 = *(const float4*)&Qs[q][d4 * 4];
        s += q4.x * kr[d4].x + q4.y * kr[d4].y + q4.z * kr[d4].z + q4.w * kr[d4].w;
      }
      const float e = __expf(s * 0.17677669529663687f);
      ssum[qi] += e;
      Ps[q][lane] = e;
      attn_out[((size_t)(bg * NQ + n0 + q)) * LS + c * DKC + lane] = e;  // unnormalized
    }
#pragma unroll
    for (int j = 0; j < 8; ++j) {
      const int kk = kg * 8 + j;
      float4 v4 = *(const float4*)&Vs[kk][dslot * 4];
      const float p0 = Ps[wave * 4 + 0][kk];
      const float p1 = Ps[wave * 4 + 1][kk];
      const float p2 = Ps[wave * 4 + 2][kk];
      const float p3 = Ps[wave * 4 + 3][kk];
      o0[0] += p0 * v4.x; o0[1] += p0 * v4.y; o0[2] += p0 * v4.z; o0[3] += p0 * v4.w;
      o1[0] += p1 * v4.x; o1[1] += p1 * v4.y; o1[2] += p1 * v4.z; o1[3] += p1 * v4.w;
      o2[0] += p2 * v4.x; o2[1] += p2 * v4.y; o2[2] += p2 * v4.z; o2[3] += p2 * v4.w;
      o3[0] += p3 * v4.x; o3[1] += p3 * v4.y; o3[2] += p3 * v4.z; o3[3] += p3 * v4.w;
    }
    __syncthreads();
  }

  float inv[4];
#pragma unroll
  for (int qi = 0; qi < 4; ++qi) {
    float ss = ssum[qi];
#pragma unroll
    for (int off = 32; off > 0; off >>= 1) ss += __shfl_xor(ss, off, 64);
    inv[qi] = 1.f / ss;
  }
  if (lane == 0) {
#pragma unroll
    for (int qi = 0; qi < 4; ++qi) invs[wave * 4 + qi] = inv[qi];
  }

#pragma unroll
  for (int j = 0; j < 4; ++j) {
    Ored[kg * (DQT * 32) + (wave * 4 + 0) * 32 + dslot * 4 + j] = o0[j] * inv[0];
    Ored[kg * (DQT * 32) + (wave * 4 + 1) * 32 + dslot * 4 + j] = o1[j] * inv[1];
    Ored[kg * (DQT * 32) + (wave * 4 + 2) * 32 + dslot * 4 + j] = o2[j] * inv[2];
    Ored[kg * (DQT * 32) + (wave * 4 + 3) * 32 + dslot * 4 + j] = o3[j] * inv[3];
  }
  __syncthreads();
#pragma unroll
  for (int i = 0; i < 2; ++i) {
    const int idx = tid * 2 + i;
    const int q = idx >> 5, d = idx & 31;
    float s = 0.f;
#pragma unroll
    for (int k = 0; k < 8; ++k) s += Ored[k * (DQT * 32) + q * 32 + d];
    da_o[((size_t)(b * NQ + n0 + q)) * CM + g * DH + d] = s;
  }

  // ---- normalize attn rows in-place (rows just written -> L2-hot) ----
  const int qrow = tid >> 4;
  const float qinv = invs[qrow];
  float4* arow = (float4*)(attn_out + ((size_t)(bg * NQ + n0 + qrow)) * LS);
#pragma unroll 4
  for (int j = 0; j < 32; ++j) {
    const int col = (tid & 15) + j * 16;
    float4 a = arow[col];
    a.x *= qinv; a.y *= qinv; a.z *= qinv; a.w *= qinv;
    arow[col] = a;
  }
}

// ---------------- launch ----------------
extern "C" void kernel_launch(void* const* d_in, const int* in_sizes, int n_in,
                              void* d_out, int out_size, void* d_ws, size_t ws_size,
                              hipStream_t stream) {
  const float* query    = (const float*)d_in[0];
  const float* gt       = (const float*)d_in[1];
  const float* sa_in_w  = (const float*)d_in[2];
  const float* sa_in_b  = (const float*)d_in[3];
  const float* sa_out_w = (const float*)d_in[4];
  const float* sa_out_b = (const float*)d_in[5];
  const float* q_w      = (const float*)d_in[6];
  const float* off_w1   = (const float*)d_in[7];
  const float* off_b1   = (const float*)d_in[8];
  const float* off_w2   = (const float*)d_in[9];
  const float* k_w      = (const float*)d_in[10];
  const float* v_w      = (const float*)d_in[11];
  const float* da_out_w = (const float*)d_in[12];
  const float* da_out_b = (const float*)d_in[13];
  const float* lin1_w   = (const float*)d_in[14];
  const float* lin1_b   = (const float*)d_in[15];
  const float* lin2_w   = (const float*)d_in[16];
  const float* lin2_b   = (const float*)d_in[17];
  const float* ln1_w    = (const float*)d_in[18];
  const float* ln1_b    = (const float*)d_in[19];
  const float* ln2_w    = (const float*)d_in[20];
  const float* ln2_b    = (const float*)d_in[21];
  const float* ln3_w    = (const float*)d_in[22];
  const float* ln3_b    = (const float*)d_in[23];

  float* ws = (float*)d_ws;
  float* t1      = ws + 0;            // 524288
  float* t2      = ws + 524288;       // 524288
  float* off1    = ws + 1048576;      // 1048576
  float* pcoords = ws + 2097152;      // 98304
  float* k_buf   = ws + 2195456;      // 1048576
  float* v_buf   = ws + 3244032;      // 1048576
  float* q_buf   = ws + 4292608;      // 524288
  float* da_o    = ws + 4816896;      // 524288
  float* qkv_buf = ws + 5341184;      // 1572864
  float* sa_o    = ws + 6914048;      // 524288
  float* t0      = ws + 7438336;      // 524288
  float* u2      = ws + 7962624;      // 524288
  float* skp     = ws + 8486912;      // 2097152 (split-K partials, 4 x 2048 x 256)
  float* hbuf    = ws + 2097152;      // 4194304 (reuses pcoords/k/v/q regions, dead by then)
  float* u3      = ws + 6291456;      // 524288  (reuses qkv region)

  float* out_t    = (float*)d_out;
  float* out_attn = out_t + (size_t)MROWS * CM;

  gemm_nt128<false><<<dim3(MROWS / 128, 768 / 128), 256, 0, stream>>>(
      query, sa_in_w, sa_in_b, nullptr, qkv_buf, MROWS, 768, CM);
  sa_flash_kernel<<<1024, 256, 0, stream>>>(qkv_buf, sa_o);
  gemm_nt<false><<<dim3(MROWS / 64, CM / 64), 256, 0, stream>>>(
      sa_o, sa_out_w, sa_out_b, query, t0, MROWS, CM, CM);
  ln_kernel<<<512, 256, 0, stream>>>(t0, ln1_w, ln1_b, t1);
  conv_off3_kernel<<<2048, 128, 0, stream>>>(gt, off_w1, off_b1, off1);
  offproj_kernel<<<128, 256, 0, stream>>>(off1, off_w2, pcoords);
  gsample_kernel<<<4096, 256, 0, stream>>>(gt, pcoords, k_w, v_w, k_buf, v_buf);
  gemm_nt<false><<<dim3(MROWS / 64, CM / 64), 256, 0, stream>>>(
      t1, q_w, nullptr, nullptr, q_buf, MROWS, CM, CM);
  dattn_kernel<<<1024, 256, 0, stream>>>(q_buf, k_buf, v_buf, da_o, out_attn);
  gemm_nt<false><<<dim3(MROWS / 64, CM / 64), 256, 0, stream>>>(
      da_o, da_out_w, da_out_b, t1, u2, MROWS, CM, CM);
  ln_kernel<<<512, 256, 0, stream>>>(u2, ln2_w, ln2_b, t2);
  gemm_nt128<true><<<dim3(MROWS / 128, FFD / 128), 256, 0, stream>>>(
      t2, lin1_w, lin1_b, nullptr, hbuf, MROWS, FFD, CM);
  gemm_nt_sk<<<dim3(MROWS / 64, CM / 64, 4), 256, 0, stream>>>(
      hbuf, lin2_w, skp, MROWS, CM, FFD, FFD / 4);
  skred_kernel<<<512, 256, 0, stream>>>(skp, lin2_b, t2, u3);
  ln_kernel<<<512, 256, 0, stream>>>(u3, ln3_w, ln3_b, out_t);
}

// Round 10
// 782.507 us; speedup vs baseline: 1.1271x; 1.1271x over previous
//
#include <hip/hip_runtime.h>
#include <hip/hip_bf16.h>

// ---------------- constants ----------------
#define BQ 2
#define NQ 1024
#define CM 256
#define HEADS 8
#define DH 32
#define FFD 2048
#define TV 16
#define HV 128
#define WV 128
#define TD 8
#define HD 16
#define WD 16
#define LS 2048              // TD*HD*WD samples per group
#define NG 16                // B * HEADS groups
#define MROWS 2048           // B*NQ token rows

// ---------------- generic f32 NT GEMM 64x64: C = A@W^T (+bias)(+res)(+relu) ----------------
template <bool RELU>
__global__ __launch_bounds__(256) void gemm_nt(const float* __restrict__ A,
                                               const float* __restrict__ Wt,
                                               const float* __restrict__ bias,
                                               const float* __restrict__ res,
                                               float* __restrict__ C,
                                               int M, int N, int K) {
  __shared__ float As[16 * 68];
  __shared__ float Ws[16 * 68];
  const int tm = threadIdx.x & 15;
  const int tn = threadIdx.x >> 4;
  const int m0 = blockIdx.x * 64, n0 = blockIdx.y * 64;
  const int lr = threadIdx.x >> 2;
  const int lk = (threadIdx.x & 3) * 4;
  float acc[4][4] = {};
  for (int k0 = 0; k0 < K; k0 += 16) {
    float4 a4 = *(const float4*)(A + (size_t)(m0 + lr) * K + k0 + lk);
    float4 w4 = *(const float4*)(Wt + (size_t)(n0 + lr) * K + k0 + lk);
    As[(lk + 0) * 68 + lr] = a4.x;
    As[(lk + 1) * 68 + lr] = a4.y;
    As[(lk + 2) * 68 + lr] = a4.z;
    As[(lk + 3) * 68 + lr] = a4.w;
    Ws[(lk + 0) * 68 + lr] = w4.x;
    Ws[(lk + 1) * 68 + lr] = w4.y;
    Ws[(lk + 2) * 68 + lr] = w4.z;
    Ws[(lk + 3) * 68 + lr] = w4.w;
    __syncthreads();
#pragma unroll
    for (int k = 0; k < 16; ++k) {
      float4 av = *(const float4*)&As[k * 68 + tm * 4];
      float4 wv = *(const float4*)&Ws[k * 68 + tn * 4];
      float a[4] = {av.x, av.y, av.z, av.w};
      float w[4] = {wv.x, wv.y, wv.z, wv.w};
#pragma unroll
      for (int i = 0; i < 4; ++i)
#pragma unroll
        for (int j = 0; j < 4; ++j) acc[i][j] += a[i] * w[j];
    }
    __syncthreads();
  }
#pragma unroll
  for (int i = 0; i < 4; ++i) {
    const int row = m0 + tm * 4 + i;
    const int col = n0 + tn * 4;
    float4 bv = bias ? *(const float4*)(bias + col) : make_float4(0.f, 0.f, 0.f, 0.f);
    float4 rv = res ? *(const float4*)(res + (size_t)row * N + col) : make_float4(0.f, 0.f, 0.f, 0.f);
    float4 o;
    o.x = acc[i][0] + bv.x + rv.x;
    o.y = acc[i][1] + bv.y + rv.y;
    o.z = acc[i][2] + bv.z + rv.z;
    o.w = acc[i][3] + bv.w + rv.w;
    if (RELU) {
      o.x = fmaxf(o.x, 0.f); o.y = fmaxf(o.y, 0.f);
      o.z = fmaxf(o.z, 0.f); o.w = fmaxf(o.w, 0.f);
    }
    *(float4*)(C + (size_t)row * N + col) = o;
  }
}

// ---------------- 128x128-tile f32 NT GEMM, 8x8 acc/thread ----------------
template <bool RELU>
__global__ __launch_bounds__(256) void gemm_nt128(const float* __restrict__ A,
                                                  const float* __restrict__ Wt,
                                                  const float* __restrict__ bias,
                                                  const float* __restrict__ res,
                                                  float* __restrict__ C,
                                                  int M, int N, int K) {
  __shared__ float As[8][132];
  __shared__ float Bs[8][132];
  const int tid = threadIdx.x;
  const int tm = tid & 15, tn = tid >> 4;
  const int m0 = blockIdx.x * 128, n0 = blockIdx.y * 128;
  const int lr = tid >> 1, lk = (tid & 1) * 4;
  float acc[8][8] = {};
  const float* Ap = A + (size_t)(m0 + lr) * K + lk;
  const float* Wp = Wt + (size_t)(n0 + lr) * K + lk;
  for (int k0 = 0; k0 < K; k0 += 8) {
    float4 a4 = *(const float4*)(Ap + k0);
    float4 w4 = *(const float4*)(Wp + k0);
    __syncthreads();
    As[lk + 0][lr] = a4.x; As[lk + 1][lr] = a4.y; As[lk + 2][lr] = a4.z; As[lk + 3][lr] = a4.w;
    Bs[lk + 0][lr] = w4.x; Bs[lk + 1][lr] = w4.y; Bs[lk + 2][lr] = w4.z; Bs[lk + 3][lr] = w4.w;
    __syncthreads();
#pragma unroll
    for (int k = 0; k < 8; ++k) {
      float4 a0 = *(const float4*)&As[k][tm * 8];
      float4 a1 = *(const float4*)&As[k][tm * 8 + 4];
      float4 w0 = *(const float4*)&Bs[k][tn * 8];
      float4 w1 = *(const float4*)&Bs[k][tn * 8 + 4];
      float av[8] = {a0.x, a0.y, a0.z, a0.w, a1.x, a1.y, a1.z, a1.w};
      float wv[8] = {w0.x, w0.y, w0.z, w0.w, w1.x, w1.y, w1.z, w1.w};
#pragma unroll
      for (int i = 0; i < 8; ++i)
#pragma unroll
        for (int j = 0; j < 8; ++j) acc[i][j] += av[i] * wv[j];
    }
  }
#pragma unroll
  for (int i = 0; i < 8; ++i) {
    const int row = m0 + tm * 8 + i;
#pragma unroll
    for (int jj = 0; jj < 2; ++jj) {
      const int col = n0 + tn * 8 + jj * 4;
      float4 o = make_float4(acc[i][jj * 4 + 0], acc[i][jj * 4 + 1],
                             acc[i][jj * 4 + 2], acc[i][jj * 4 + 3]);
      if (bias) {
        float4 bv = *(const float4*)(bias + col);
        o.x += bv.x; o.y += bv.y; o.z += bv.z; o.w += bv.w;
      }
      if (res) {
        float4 rv = *(const float4*)(res + (size_t)row * N + col);
        o.x += rv.x; o.y += rv.y; o.z += rv.z; o.w += rv.w;
      }
      if (RELU) {
        o.x = fmaxf(o.x, 0.f); o.y = fmaxf(o.y, 0.f);
        o.z = fmaxf(o.z, 0.f); o.w = fmaxf(o.w, 0.f);
      }
      *(float4*)(C + (size_t)row * N + col) = o;
    }
  }
}

// ---------------- split-K 64x64 GEMM: P[slice][M][N] partials ----------------
__global__ __launch_bounds__(256) void gemm_nt_sk(const float* __restrict__ A,
                                                  const float* __restrict__ Wt,
                                                  float* __restrict__ P,
                                                  int M, int N, int K, int KS) {
  __shared__ float As[16 * 68];
  __shared__ float Ws[16 * 68];
  const int tm = threadIdx.x & 15;
  const int tn = threadIdx.x >> 4;
  const int m0 = blockIdx.x * 64, n0 = blockIdx.y * 64;
  const int kb = blockIdx.z * KS;
  const int lr = threadIdx.x >> 2;
  const int lk = (threadIdx.x & 3) * 4;
  float acc[4][4] = {};
  for (int k0 = kb; k0 < kb + KS; k0 += 16) {
    float4 a4 = *(const float4*)(A + (size_t)(m0 + lr) * K + k0 + lk);
    float4 w4 = *(const float4*)(Wt + (size_t)(n0 + lr) * K + k0 + lk);
    As[(lk + 0) * 68 + lr] = a4.x;
    As[(lk + 1) * 68 + lr] = a4.y;
    As[(lk + 2) * 68 + lr] = a4.z;
    As[(lk + 3) * 68 + lr] = a4.w;
    Ws[(lk + 0) * 68 + lr] = w4.x;
    Ws[(lk + 1) * 68 + lr] = w4.y;
    Ws[(lk + 2) * 68 + lr] = w4.z;
    Ws[(lk + 3) * 68 + lr] = w4.w;
    __syncthreads();
#pragma unroll
    for (int k = 0; k < 16; ++k) {
      float4 av = *(const float4*)&As[k * 68 + tm * 4];
      float4 wv = *(const float4*)&Ws[k * 68 + tn * 4];
      float a[4] = {av.x, av.y, av.z, av.w};
      float w[4] = {wv.x, wv.y, wv.z, wv.w};
#pragma unroll
      for (int i = 0; i < 4; ++i)
#pragma unroll
        for (int j = 0; j < 4; ++j) acc[i][j] += a[i] * w[j];
    }
    __syncthreads();
  }
  float* Pb = P + (size_t)blockIdx.z * M * N;
#pragma unroll
  for (int i = 0; i < 4; ++i) {
    const int row = m0 + tm * 4 + i;
    const int col = n0 + tn * 4;
    *(float4*)(Pb + (size_t)row * N + col) =
        make_float4(acc[i][0], acc[i][1], acc[i][2], acc[i][3]);
  }
}

// ---------------- split-K reduce (+bias+res), N must be 256 ----------------
__global__ __launch_bounds__(256) void skred_kernel(const float* __restrict__ P,
                                                    const float* __restrict__ bias,
                                                    const float* __restrict__ res,
                                                    float* __restrict__ C) {
  const int idx = blockIdx.x * 256 + threadIdx.x;   // MROWS*CM/4 = 131072
  const int col4 = idx & 63;
  const int row = idx >> 6;
  const float4* P4 = (const float4*)P;
  const int MN4 = MROWS * CM / 4;
  float4 s = P4[idx];
  float4 s1 = P4[idx + MN4];
  float4 s2 = P4[idx + 2 * MN4];
  float4 s3 = P4[idx + 3 * MN4];
  s.x += s1.x + s2.x + s3.x;
  s.y += s1.y + s2.y + s3.y;
  s.z += s1.z + s2.z + s3.z;
  s.w += s1.w + s2.w + s3.w;
  float4 bv = ((const float4*)bias)[col4];
  float4 rv = ((const float4*)(res + (size_t)row * CM))[col4];
  s.x += bv.x + rv.x; s.y += bv.y + rv.y;
  s.z += bv.z + rv.z; s.w += bv.w + rv.w;
  ((float4*)C)[idx] = s;
}

// ---------------- self-attention: single-pass flash (scores provably tiny -> no max) ----------------
#define SKC 64
#define SNC (NQ / SKC)
__global__ __launch_bounds__(256) void sa_flash_kernel(const float* __restrict__ qkv,
                                                       float* __restrict__ o) {
  __shared__ float Qs[16][36];
  __shared__ float Ks[SKC][36];
  __shared__ float Vs[SKC][36];
  __shared__ float Ps[16][68];
  __shared__ float Ored[8 * 16 * 32];

  const int swz = (blockIdx.x & 7) * 128 + (blockIdx.x >> 3);
  const int bh = swz >> 6, qt = swz & 63;
  const int n0 = qt * 16;
  const int b = bh >> 3, h = bh & 7;
  const int tid = threadIdx.x;
  const int lane = tid & 63, wave = tid >> 6;

  const float* rowbase = qkv + (size_t)b * NQ * 768 + h * DH;

  if (tid < 128) {
    const int r = tid >> 3, c4 = (tid & 7) * 4;
    *(float4*)&Qs[r][c4] = *(const float4*)(rowbase + (size_t)(n0 + r) * 768 + c4);
  }
  __syncthreads();

  const int dslot = (tid >> 3) & 7;
  const int kg = tid & 7;
  float ssum[4] = {0.f, 0.f, 0.f, 0.f};
  float o0[4] = {}, o1[4] = {}, o2[4] = {}, o3[4] = {};

#pragma unroll 1
  for (int c = 0; c < SNC; ++c) {
    {
      const int r0 = tid >> 3, c40 = (tid & 7) * 4;
      const int r1 = r0 + 32;
      *(float4*)&Ks[r0][c40] =
          *(const float4*)(rowbase + (size_t)(c * SKC + r0) * 768 + 256 + c40);
      *(float4*)&Ks[r1][c40] =
          *(const float4*)(rowbase + (size_t)(c * SKC + r1) * 768 + 256 + c40);
      *(float4*)&Vs[r0][c40] =
          *(const float4*)(rowbase + (size_t)(c * SKC + r0) * 768 + 512 + c40);
      *(float4*)&Vs[r1][c40] =
          *(const float4*)(rowbase + (size_t)(c * SKC + r1) * 768 + 512 + c40);
    }
    __syncthreads();
    float4 kr[8];
#pragma unroll
    for (int d4 = 0; d4 < 8; ++d4) kr[d4] = *(const float4*)&Ks[lane][d4 * 4];
#pragma unroll
    for (int qi = 0; qi < 4; ++qi) {
      const int q = wave * 4 + qi;
      float s = 0.f;
#pragma unroll
      for (int d4 = 0; d4 < 8; ++d4) {
        float4 q4 = *(const float4*)&Qs[q][d4 * 4];
        s += q4.x * kr[d4].x + q4.y * kr[d4].y + q4.z * kr[d4].z + q4.w * kr[d4].w;
      }
      const float e = __expf(s * 0.17677669529663687f);
      ssum[qi] += e;
      Ps[q][lane] = e;
    }
#pragma unroll
    for (int j = 0; j < 8; ++j) {
      const int kk = kg * 8 + j;
      float4 v4 = *(const float4*)&Vs[kk][dslot * 4];
      const float p0 = Ps[wave * 4 + 0][kk];
      const float p1 = Ps[wave * 4 + 1][kk];
      const float p2 = Ps[wave * 4 + 2][kk];
      const float p3 = Ps[wave * 4 + 3][kk];
      o0[0] += p0 * v4.x; o0[1] += p0 * v4.y; o0[2] += p0 * v4.z; o0[3] += p0 * v4.w;
      o1[0] += p1 * v4.x; o1[1] += p1 * v4.y; o1[2] += p1 * v4.z; o1[3] += p1 * v4.w;
      o2[0] += p2 * v4.x; o2[1] += p2 * v4.y; o2[2] += p2 * v4.z; o2[3] += p2 * v4.w;
      o3[0] += p3 * v4.x; o3[1] += p3 * v4.y; o3[2] += p3 * v4.z; o3[3] += p3 * v4.w;
    }
    __syncthreads();
  }

  float inv[4];
#pragma unroll
  for (int qi = 0; qi < 4; ++qi) {
    float ss = ssum[qi];
#pragma unroll
    for (int off = 32; off > 0; off >>= 1) ss += __shfl_xor(ss, off, 64);
    inv[qi] = 1.f / ss;
  }

#pragma unroll
  for (int j = 0; j < 4; ++j) {
    Ored[kg * (16 * 32) + (wave * 4 + 0) * 32 + dslot * 4 + j] = o0[j] * inv[0];
    Ored[kg * (16 * 32) + (wave * 4 + 1) * 32 + dslot * 4 + j] = o1[j] * inv[1];
    Ored[kg * (16 * 32) + (wave * 4 + 2) * 32 + dslot * 4 + j] = o2[j] * inv[2];
    Ored[kg * (16 * 32) + (wave * 4 + 3) * 32 + dslot * 4 + j] = o3[j] * inv[3];
  }
  __syncthreads();
#pragma unroll
  for (int i = 0; i < 2; ++i) {
    const int idx = tid * 2 + i;
    const int q = idx >> 5, d = idx & 31;
    float s = 0.f;
#pragma unroll
    for (int k = 0; k < 8; ++k) s += Ored[k * (16 * 32) + q * 32 + d];
    o[((size_t)(b * NQ + n0 + q)) * CM + h * DH + d] = s;
  }
}

// ---------------- layer norm (one wave per 256-dim row), f32 out ----------------
__global__ __launch_bounds__(256) void ln_kernel(const float* __restrict__ in,
                                                 const float* __restrict__ w,
                                                 const float* __restrict__ b,
                                                 float* __restrict__ out) {
  const int wv = threadIdx.x >> 6, lane = threadIdx.x & 63;
  const int row = blockIdx.x * 4 + wv;
  float4 v = ((const float4*)(in + (size_t)row * CM))[lane];
  float s = v.x + v.y + v.z + v.w;
#pragma unroll
  for (int off = 32; off > 0; off >>= 1) s += __shfl_xor(s, off, 64);
  const float mu = s * (1.f / 256.f);
  float dx = v.x - mu, dy = v.y - mu, dz = v.z - mu, dw = v.w - mu;
  float q = dx * dx + dy * dy + dz * dz + dw * dw;
#pragma unroll
  for (int off = 32; off > 0; off >>= 1) q += __shfl_xor(q, off, 64);
  const float r = rsqrtf(q * (1.f / 256.f) + 1e-5f);
  float4 wv4 = ((const float4*)w)[lane];
  float4 bv4 = ((const float4*)b)[lane];
  float4 o;
  o.x = dx * r * wv4.x + bv4.x;
  o.y = dy * r * wv4.y + bv4.y;
  o.z = dz * r * wv4.z + bv4.z;
  o.w = dw * r * wv4.w + bv4.w;
  ((float4*)(out + (size_t)row * CM))[lane] = o;
}

// ---------------- depthwise strided conv v4: register windows, float4, no LDS staging ----
// block = cid (512 blocks), 256 threads = (zq 0..3 = wave, txo 0..3, yo 0..15).
// Thread computes 4 x-outputs x 1 y x zo-pair (2zq, 2zq+1). Window per row = 34 floats:
// 1 scalar + 8 aligned float4 + 1 scalar, 100% byte use, feeds up to 80 FMA.
__global__ __launch_bounds__(256) void conv_off4_kernel(const float* __restrict__ gt,
                                                        const float* __restrict__ w1,
                                                        const float* __restrict__ b1,
                                                        float* __restrict__ off1) {
  const int cid = blockIdx.x;          // bg*32 + c
  const int c = cid & 31;
  const int tid = threadIdx.x;
  const int yo = tid & 15;
  const int txo = (tid >> 4) & 3;
  const int zq = tid >> 6;             // wave-uniform
  __shared__ float wsm[400];
  for (int i = tid; i < 400; i += 256) wsm[i] = w1[c * 400 + i];
  __syncthreads();

  const float* __restrict__ xp = gt + (size_t)cid * (TV * HV * WV);
  const int xb = txo * 32;
  float acc0[4] = {}, acc1[4] = {};    // zo0 = 2zq, zo1 = 2zq+1

#pragma unroll
  for (int zz = 0; zz < 6; ++zz) {
    const int z = 4 * zq - 1 + zz;     // wave-uniform
    if (z < 0 || z > 15) continue;
    const float* __restrict__ zp = xp + (size_t)z * (HV * WV);
    // compile-time: zz<4 -> contributes (zo0, kz=zz); zz>=2 -> (zo1, kz=zz-2)
#pragma unroll 1
    for (int ky = 0; ky < 10; ++ky) {
      const int y = yo * 8 - 1 + ky;
      if ((unsigned)y >= 128u) continue;   // only yo=0/ky=0 and yo=15/ky=9 lanes
      const float* __restrict__ row = zp + y * WV;
      float v[34];
      v[0] = (txo > 0) ? row[xb - 1] : 0.f;
#pragma unroll
      for (int k = 0; k < 8; ++k) {
        float4 f = *(const float4*)(row + xb + 4 * k);
        v[1 + 4 * k] = f.x; v[2 + 4 * k] = f.y;
        v[3 + 4 * k] = f.z; v[4 + 4 * k] = f.w;
      }
      v[33] = (txo < 3) ? row[xb + 32] : 0.f;
      if (zz < 4) {
        const float* __restrict__ wr = wsm + zz * 100 + ky * 10;
#pragma unroll
        for (int j = 0; j < 4; ++j) {
          float s = 0.f;
#pragma unroll
          for (int kx = 0; kx < 10; ++kx) s += wr[kx] * v[8 * j + kx];
          acc0[j] += s;
        }
      }
      if (zz >= 2) {
        const float* __restrict__ wr = wsm + (zz - 2) * 100 + ky * 10;
#pragma unroll
        for (int j = 0; j < 4; ++j) {
          float s = 0.f;
#pragma unroll
          for (int kx = 0; kx < 10; ++kx) s += wr[kx] * v[8 * j + kx];
          acc1[j] += s;
        }
      }
    }
  }

  const float bias = b1[c];
#pragma unroll
  for (int j = 0; j < 4; ++j) {
    const int xo_out = txo * 4 + j;
    {
      float a = acc0[j] + bias;
      const float u = 0.7978845608028654f * (a + 0.044715f * a * a * a);
      const float gv = 0.5f * a * (1.f + tanhf(u));
      off1[((size_t)cid * TD + 2 * zq) * (HD * WD) + yo * WD + xo_out] = gv;
    }
    {
      float a = acc1[j] + bias;
      const float u = 0.7978845608028654f * (a + 0.044715f * a * a * a);
      const float gv = 0.5f * a * (1.f + tanhf(u));
      off1[((size_t)cid * TD + 2 * zq + 1) * (HD * WD) + yo * WD + xo_out] = gv;
    }
  }
}

// ---------------- offset projection + tanh*scale + pixel coords ----------------
__global__ __launch_bounds__(256) void offproj_kernel(const float* __restrict__ off1,
                                                      const float* __restrict__ w2,
                                                      float* __restrict__ pc) {
  const int gid = blockIdx.x * 256 + threadIdx.x;  // 16*2048
  const int bg = gid >> 11, sp = gid & 2047;
  const float* base = off1 + (size_t)bg * 32 * LS + sp;
  float o0 = 0.f, o1 = 0.f, o2 = 0.f;
#pragma unroll
  for (int c = 0; c < 32; ++c) {
    const float v = base[(size_t)c * LS];
    o0 += w2[c] * v;
    o1 += w2[32 + c] * v;
    o2 += w2[64 + c] * v;
  }
  const int gz = sp >> 8, gy = (sp >> 4) & 15, gx = sp & 15;
  const float oz = tanhf(o0) * 2.f;
  const float oy = tanhf(o1) * 8.f;
  const float ox = tanhf(o2) * 8.f;
  float* p = pc + (size_t)gid * 3;
  p[0] = ((float)gz + oz) * (16.f / 7.f) - 0.5f;
  p[1] = ((float)gy + oy) * (128.f / 15.f) - 0.5f;
  p[2] = ((float)gx + ox) * (128.f / 15.f) - 0.5f;
}

// ---------------- trilinear grid sample + per-group k/v projection ----------------
__global__ __launch_bounds__(256) void gsample_kernel(const float* __restrict__ gt,
                                                      const float* __restrict__ pc,
                                                      const float* __restrict__ kw,
                                                      const float* __restrict__ vw,
                                                      float* __restrict__ kbuf,
                                                      float* __restrict__ vbuf) {
  __shared__ float kvv[8][33];
  __shared__ float kws[32][33], vws[32][33];
  const int swz = (blockIdx.x & 7) * 512 + (blockIdx.x >> 3);
  const int bg = swz >> 8, l0 = (swz & 255) * 8;
  const int g = bg & 7;
  const int s = threadIdx.x >> 5, c = threadIdx.x & 31;
  for (int i = threadIdx.x; i < 1024; i += 256) {
    kws[i >> 5][i & 31] = kw[g * 1024 + i];
    vws[i >> 5][i & 31] = vw[g * 1024 + i];
  }
  const int l = l0 + s;
  const float* p = pc + ((size_t)bg * LS + l) * 3;
  const float pz = p[0], py = p[1], px = p[2];
  const float zf = floorf(pz), yf = floorf(py), xf = floorf(px);
  const int z0 = (int)zf, y0 = (int)yf, x0 = (int)xf;
  const float fz = pz - zf, fy = py - yf, fx = px - xf;
  const float* vp = gt + (size_t)(bg * 32 + c) * (TV * HV * WV);
  float acc = 0.f;
#pragma unroll
  for (int dz = 0; dz < 2; ++dz) {
    const int z = z0 + dz;
    if ((unsigned)z >= (unsigned)TV) continue;
    const float wz = dz ? fz : 1.f - fz;
#pragma unroll
    for (int dy = 0; dy < 2; ++dy) {
      const int y = y0 + dy;
      if ((unsigned)y >= (unsigned)HV) continue;
      const float wzy = wz * (dy ? fy : 1.f - fy);
#pragma unroll
      for (int dx = 0; dx < 2; ++dx) {
        const int x = x0 + dx;
        if ((unsigned)x >= (unsigned)WV) continue;
        acc += wzy * (dx ? fx : 1.f - fx) * vp[((size_t)z * HV + y) * WV + x];
      }
    }
  }
  kvv[s][c] = acc;
  __syncthreads();
  float ka = 0.f, va = 0.f;
#pragma unroll
  for (int f = 0; f < 32; ++f) {
    const float kv = kvv[s][f];
    ka += kws[c][f] * kv;
    va += vws[c][f] * kv;
  }
  kbuf[((size_t)bg * LS + l) * 32 + c] = ka;
  vbuf[((size_t)bg * LS + l) * 32 + c] = va;
}

// ---------------- deformable attention: single pass + in-kernel normalize tail ----------------
#define DQT 16
#define DKC 64
#define DNC (LS / DKC)
__global__ __launch_bounds__(256) void dattn_kernel(const float* __restrict__ qb,
                                                    const float* __restrict__ kbuf,
                                                    const float* __restrict__ vbuf,
                                                    float* __restrict__ da_o,
                                                    float* __restrict__ attn_out) {
  __shared__ float Qs[DQT][36];
  __shared__ float Ks[DKC][36];
  __shared__ float Vs[DKC][36];
  __shared__ float Ps[DQT][68];
  __shared__ float Ored[8 * DQT * 32];
  __shared__ float invs[DQT];

  const int swz = (blockIdx.x & 7) * 128 + (blockIdx.x >> 3);
  const int bg = swz >> 6, qt = swz & 63;
  const int n0 = qt * DQT;
  const int b = bg >> 3, g = bg & 7;
  const int tid = threadIdx.x;
  const int lane = tid & 63, wave = tid >> 6;

  const float* kB = kbuf + (size_t)bg * LS * 32;
  const float* vB = vbuf + (size_t)bg * LS * 32;

  if (tid < 128) {
    const int r = tid >> 3, c4 = (tid & 7) * 4;
    *(float4*)&Qs[r][c4] =
        *(const float4*)(qb + ((size_t)(b * NQ + n0 + r)) * CM + g * DH + c4);
  }
  __syncthreads();

  const int dslot = (tid >> 3) & 7;
  const int kg = tid & 7;
  float ssum[4] = {0.f, 0.f, 0.f, 0.f};
  float o0[4] = {}, o1[4] = {}, o2[4] = {}, o3[4] = {};

#pragma unroll 1
  for (int c = 0; c < DNC; ++c) {
    {
      const int r0 = tid >> 3, c40 = (tid & 7) * 4;
      const int r1 = r0 + 32;
      *(float4*)&Ks[r0][c40] = *(const float4*)(kB + (size_t)(c * DKC + r0) * 32 + c40);
      *(float4*)&Ks[r1][c40] = *(const float4*)(kB + (size_t)(c * DKC + r1) * 32 + c40);
      *(float4*)&Vs[r0][c40] = *(const float4*)(vB + (size_t)(c * DKC + r0) * 32 + c40);
      *(float4*)&Vs[r1][c40] = *(const float4*)(vB + (size_t)(c * DKC + r1) * 32 + c40);
    }
    __syncthreads();
    float4 kr[8];
#pragma unroll
    for (int d4 = 0; d4 < 8; ++d4) kr[d4] = *(const float4*)&Ks[lane][d4 * 4];
#pragma unroll
    for (int qi = 0; qi < 4; ++qi) {
      const int q = wave * 4 + qi;
      float s = 0.f;
#pragma unroll
      for (int d4 = 0; d4 < 8; ++d4) {
        float4 q4 = *(const float4*)&Qs[q][d4 * 4];
        s += q4.x * kr[d4].x + q4.y * kr[d4].y + q4.z * kr[d4].z + q4.w * kr[d4].w;
      }
      const float e = __expf(s * 0.17677669529663687f);
      ssum[qi] += e;
      Ps[q][lane] = e;
      attn_out[((size_t)(bg * NQ + n0 + q)) * LS + c * DKC + lane] = e;  // unnormalized
    }
#pragma unroll
    for (int j = 0; j < 8; ++j) {
      const int kk = kg * 8 + j;
      float4 v4 = *(const float4*)&Vs[kk][dslot * 4];
      const float p0 = Ps[wave * 4 + 0][kk];
      const float p1 = Ps[wave * 4 + 1][kk];
      const float p2 = Ps[wave * 4 + 2][kk];
      const float p3 = Ps[wave * 4 + 3][kk];
      o0[0] += p0 * v4.x; o0[1] += p0 * v4.y; o0[2] += p0 * v4.z; o0[3] += p0 * v4.w;
      o1[0] += p1 * v4.x; o1[1] += p1 * v4.y; o1[2] += p1 * v4.z; o1[3] += p1 * v4.w;
      o2[0] += p2 * v4.x; o2[1] += p2 * v4.y; o2[2] += p2 * v4.z; o2[3] += p2 * v4.w;
      o3[0] += p3 * v4.x; o3[1] += p3 * v4.y; o3[2] += p3 * v4.z; o3[3] += p3 * v4.w;
    }
    __syncthreads();
  }

  float inv[4];
#pragma unroll
  for (int qi = 0; qi < 4; ++qi) {
    float ss = ssum[qi];
#pragma unroll
    for (int off = 32; off > 0; off >>= 1) ss += __shfl_xor(ss, off, 64);
    inv[qi] = 1.f / ss;
  }
  if (lane == 0) {
#pragma unroll
    for (int qi = 0; qi < 4; ++qi) invs[wave * 4 + qi] = inv[qi];
  }

#pragma unroll
  for (int j = 0; j < 4; ++j) {
    Ored[kg * (DQT * 32) + (wave * 4 + 0) * 32 + dslot * 4 + j] = o0[j] * inv[0];
    Ored[kg * (DQT * 32) + (wave * 4 + 1) * 32 + dslot * 4 + j] = o1[j] * inv[1];
    Ored[kg * (DQT * 32) + (wave * 4 + 2) * 32 + dslot * 4 + j] = o2[j] * inv[2];
    Ored[kg * (DQT * 32) + (wave * 4 + 3) * 32 + dslot * 4 + j] = o3[j] * inv[3];
  }
  __syncthreads();
#pragma unroll
  for (int i = 0; i < 2; ++i) {
    const int idx = tid * 2 + i;
    const int q = idx >> 5, d = idx & 31;
    float s = 0.f;
#pragma unroll
    for (int k = 0; k < 8; ++k) s += Ored[k * (DQT * 32) + q * 32 + d];
    da_o[((size_t)(b * NQ + n0 + q)) * CM + g * DH + d] = s;
  }

  // ---- normalize attn rows in-place (rows just written -> L2-hot) ----
  const int qrow = tid >> 4;
  const float qinv = invs[qrow];
  float4* arow = (float4*)(attn_out + ((size_t)(bg * NQ + n0 + qrow)) * LS);
#pragma unroll 4
  for (int j = 0; j < 32; ++j) {
    const int col = (tid & 15) + j * 16;
    float4 a = arow[col];
    a.x *= qinv; a.y *= qinv; a.z *= qinv; a.w *= qinv;
    arow[col] = a;
  }
}

// ---------------- launch ----------------
extern "C" void kernel_launch(void* const* d_in, const int* in_sizes, int n_in,
                              void* d_out, int out_size, void* d_ws, size_t ws_size,
                              hipStream_t stream) {
  const float* query    = (const float*)d_in[0];
  const float* gt       = (const float*)d_in[1];
  const float* sa_in_w  = (const float*)d_in[2];
  const float* sa_in_b  = (const float*)d_in[3];
  const float* sa_out_w = (const float*)d_in[4];
  const float* sa_out_b = (const float*)d_in[5];
  const float* q_w      = (const float*)d_in[6];
  const float* off_w1   = (const float*)d_in[7];
  const float* off_b1   = (const float*)d_in[8];
  const float* off_w2   = (const float*)d_in[9];
  const float* k_w      = (const float*)d_in[10];
  const float* v_w      = (const float*)d_in[11];
  const float* da_out_w = (const float*)d_in[12];
  const float* da_out_b = (const float*)d_in[13];
  const float* lin1_w   = (const float*)d_in[14];
  const float* lin1_b   = (const float*)d_in[15];
  const float* lin2_w   = (const float*)d_in[16];
  const float* lin2_b   = (const float*)d_in[17];
  const float* ln1_w    = (const float*)d_in[18];
  const float* ln1_b    = (const float*)d_in[19];
  const float* ln2_w    = (const float*)d_in[20];
  const float* ln2_b    = (const float*)d_in[21];
  const float* ln3_w    = (const float*)d_in[22];
  const float* ln3_b    = (const float*)d_in[23];

  float* ws = (float*)d_ws;
  float* t1      = ws + 0;            // 524288
  float* t2      = ws + 524288;       // 524288
  float* off1    = ws + 1048576;      // 1048576
  float* pcoords = ws + 2097152;      // 98304
  float* k_buf   = ws + 2195456;      // 1048576
  float* v_buf   = ws + 3244032;      // 1048576
  float* q_buf   = ws + 4292608;      // 524288
  float* da_o    = ws + 4816896;      // 524288
  float* qkv_buf = ws + 5341184;      // 1572864
  float* sa_o    = ws + 6914048;      // 524288
  float* t0      = ws + 7438336;      // 524288
  float* u2      = ws + 7962624;      // 524288
  float* skp     = ws + 8486912;      // 2097152 (split-K partials, 4 x 2048 x 256)
  float* hbuf    = ws + 2097152;      // 4194304 (reuses pcoords/k/v/q regions, dead by then)
  float* u3      = ws + 6291456;      // 524288  (reuses qkv region)

  float* out_t    = (float*)d_out;
  float* out_attn = out_t + (size_t)MROWS * CM;

  gemm_nt128<false><<<dim3(MROWS / 128, 768 / 128), 256, 0, stream>>>(
      query, sa_in_w, sa_in_b, nullptr, qkv_buf, MROWS, 768, CM);
  sa_flash_kernel<<<1024, 256, 0, stream>>>(qkv_buf, sa_o);
  gemm_nt<false><<<dim3(MROWS / 64, CM / 64), 256, 0, stream>>>(
      sa_o, sa_out_w, sa_out_b, query, t0, MROWS, CM, CM);
  ln_kernel<<<512, 256, 0, stream>>>(t0, ln1_w, ln1_b, t1);
  conv_off4_kernel<<<512, 256, 0, stream>>>(gt, off_w1, off_b1, off1);
  offproj_kernel<<<128, 256, 0, stream>>>(off1, off_w2, pcoords);
  gsample_kernel<<<4096, 256, 0, stream>>>(gt, pcoords, k_w, v_w, k_buf, v_buf);
  gemm_nt<false><<<dim3(MROWS / 64, CM / 64), 256, 0, stream>>>(
      t1, q_w, nullptr, nullptr, q_buf, MROWS, CM, CM);
  dattn_kernel<<<1024, 256, 0, stream>>>(q_buf, k_buf, v_buf, da_o, out_attn);
  gemm_nt<false><<<dim3(MROWS / 64, CM / 64), 256, 0, stream>>>(
      da_o, da_out_w, da_out_b, t1, u2, MROWS, CM, CM);
  ln_kernel<<<512, 256, 0, stream>>>(u2, ln2_w, ln2_b, t2);
  gemm_nt128<true><<<dim3(MROWS / 128, FFD / 128), 256, 0, stream>>>(
      t2, lin1_w, lin1_b, nullptr, hbuf, MROWS, FFD, CM);
  gemm_nt_sk<<<dim3(MROWS / 64, CM / 64, 4), 256, 0, stream>>>(
      hbuf, lin2_w, skp, MROWS, CM, FFD, FFD / 4);
  skred_kernel<<<512, 256, 0, stream>>>(skp, lin2_b, t2, u3);
  ln_kernel<<<512, 256, 0, stream>>>(u3, ln3_w, ln3_b, out_t);
}

// Round 11
// 756.599 us; speedup vs baseline: 1.1657x; 1.0342x over previous
//
#include <hip/hip_runtime.h>
#include <hip/hip_bf16.h>

// ---------------- constants ----------------
#define BQ 2
#define NQ 1024
#define CM 256
#define HEADS 8
#define DH 32
#define FFD 2048
#define TV 16
#define HV 128
#define WV 128
#define TD 8
#define HD 16
#define WD 16
#define LS 2048              // TD*HD*WD samples per group
#define NG 16                // B * HEADS groups
#define MROWS 2048           // B*NQ token rows

// ---------------- generic f32 NT GEMM 64x64: C = A@W^T (+bias)(+res)(+relu) ----------------
template <bool RELU>
__global__ __launch_bounds__(256) void gemm_nt(const float* __restrict__ A,
                                               const float* __restrict__ Wt,
                                               const float* __restrict__ bias,
                                               const float* __restrict__ res,
                                               float* __restrict__ C,
                                               int M, int N, int K) {
  __shared__ float As[16 * 68];
  __shared__ float Ws[16 * 68];
  const int tm = threadIdx.x & 15;
  const int tn = threadIdx.x >> 4;
  const int m0 = blockIdx.x * 64, n0 = blockIdx.y * 64;
  const int lr = threadIdx.x >> 2;
  const int lk = (threadIdx.x & 3) * 4;
  float acc[4][4] = {};
  for (int k0 = 0; k0 < K; k0 += 16) {
    float4 a4 = *(const float4*)(A + (size_t)(m0 + lr) * K + k0 + lk);
    float4 w4 = *(const float4*)(Wt + (size_t)(n0 + lr) * K + k0 + lk);
    As[(lk + 0) * 68 + lr] = a4.x;
    As[(lk + 1) * 68 + lr] = a4.y;
    As[(lk + 2) * 68 + lr] = a4.z;
    As[(lk + 3) * 68 + lr] = a4.w;
    Ws[(lk + 0) * 68 + lr] = w4.x;
    Ws[(lk + 1) * 68 + lr] = w4.y;
    Ws[(lk + 2) * 68 + lr] = w4.z;
    Ws[(lk + 3) * 68 + lr] = w4.w;
    __syncthreads();
#pragma unroll
    for (int k = 0; k < 16; ++k) {
      float4 av = *(const float4*)&As[k * 68 + tm * 4];
      float4 wv = *(const float4*)&Ws[k * 68 + tn * 4];
      float a[4] = {av.x, av.y, av.z, av.w};
      float w[4] = {wv.x, wv.y, wv.z, wv.w};
#pragma unroll
      for (int i = 0; i < 4; ++i)
#pragma unroll
        for (int j = 0; j < 4; ++j) acc[i][j] += a[i] * w[j];
    }
    __syncthreads();
  }
#pragma unroll
  for (int i = 0; i < 4; ++i) {
    const int row = m0 + tm * 4 + i;
    const int col = n0 + tn * 4;
    float4 bv = bias ? *(const float4*)(bias + col) : make_float4(0.f, 0.f, 0.f, 0.f);
    float4 rv = res ? *(const float4*)(res + (size_t)row * N + col) : make_float4(0.f, 0.f, 0.f, 0.f);
    float4 o;
    o.x = acc[i][0] + bv.x + rv.x;
    o.y = acc[i][1] + bv.y + rv.y;
    o.z = acc[i][2] + bv.z + rv.z;
    o.w = acc[i][3] + bv.w + rv.w;
    if (RELU) {
      o.x = fmaxf(o.x, 0.f); o.y = fmaxf(o.y, 0.f);
      o.z = fmaxf(o.z, 0.f); o.w = fmaxf(o.w, 0.f);
    }
    *(float4*)(C + (size_t)row * N + col) = o;
  }
}

// ---------------- 128x128-tile f32 NT GEMM, 8x8 acc/thread ----------------
template <bool RELU>
__global__ __launch_bounds__(256) void gemm_nt128(const float* __restrict__ A,
                                                  const float* __restrict__ Wt,
                                                  const float* __restrict__ bias,
                                                  const float* __restrict__ res,
                                                  float* __restrict__ C,
                                                  int M, int N, int K) {
  __shared__ float As[8][132];
  __shared__ float Bs[8][132];
  const int tid = threadIdx.x;
  const int tm = tid & 15, tn = tid >> 4;
  const int m0 = blockIdx.x * 128, n0 = blockIdx.y * 128;
  const int lr = tid >> 1, lk = (tid & 1) * 4;
  float acc[8][8] = {};
  const float* Ap = A + (size_t)(m0 + lr) * K + lk;
  const float* Wp = Wt + (size_t)(n0 + lr) * K + lk;
  for (int k0 = 0; k0 < K; k0 += 8) {
    float4 a4 = *(const float4*)(Ap + k0);
    float4 w4 = *(const float4*)(Wp + k0);
    __syncthreads();
    As[lk + 0][lr] = a4.x; As[lk + 1][lr] = a4.y; As[lk + 2][lr] = a4.z; As[lk + 3][lr] = a4.w;
    Bs[lk + 0][lr] = w4.x; Bs[lk + 1][lr] = w4.y; Bs[lk + 2][lr] = w4.z; Bs[lk + 3][lr] = w4.w;
    __syncthreads();
#pragma unroll
    for (int k = 0; k < 8; ++k) {
      float4 a0 = *(const float4*)&As[k][tm * 8];
      float4 a1 = *(const float4*)&As[k][tm * 8 + 4];
      float4 w0 = *(const float4*)&Bs[k][tn * 8];
      float4 w1 = *(const float4*)&Bs[k][tn * 8 + 4];
      float av[8] = {a0.x, a0.y, a0.z, a0.w, a1.x, a1.y, a1.z, a1.w};
      float wv[8] = {w0.x, w0.y, w0.z, w0.w, w1.x, w1.y, w1.z, w1.w};
#pragma unroll
      for (int i = 0; i < 8; ++i)
#pragma unroll
        for (int j = 0; j < 8; ++j) acc[i][j] += av[i] * wv[j];
    }
  }
#pragma unroll
  for (int i = 0; i < 8; ++i) {
    const int row = m0 + tm * 8 + i;
#pragma unroll
    for (int jj = 0; jj < 2; ++jj) {
      const int col = n0 + tn * 8 + jj * 4;
      float4 o = make_float4(acc[i][jj * 4 + 0], acc[i][jj * 4 + 1],
                             acc[i][jj * 4 + 2], acc[i][jj * 4 + 3]);
      if (bias) {
        float4 bv = *(const float4*)(bias + col);
        o.x += bv.x; o.y += bv.y; o.z += bv.z; o.w += bv.w;
      }
      if (res) {
        float4 rv = *(const float4*)(res + (size_t)row * N + col);
        o.x += rv.x; o.y += rv.y; o.z += rv.z; o.w += rv.w;
      }
      if (RELU) {
        o.x = fmaxf(o.x, 0.f); o.y = fmaxf(o.y, 0.f);
        o.z = fmaxf(o.z, 0.f); o.w = fmaxf(o.w, 0.f);
      }
      *(float4*)(C + (size_t)row * N + col) = o;
    }
  }
}

// ---------------- split-K 64x64 GEMM: P[slice][M][N] partials ----------------
__global__ __launch_bounds__(256) void gemm_nt_sk(const float* __restrict__ A,
                                                  const float* __restrict__ Wt,
                                                  float* __restrict__ P,
                                                  int M, int N, int K, int KS) {
  __shared__ float As[16 * 68];
  __shared__ float Ws[16 * 68];
  const int tm = threadIdx.x & 15;
  const int tn = threadIdx.x >> 4;
  const int m0 = blockIdx.x * 64, n0 = blockIdx.y * 64;
  const int kb = blockIdx.z * KS;
  const int lr = threadIdx.x >> 2;
  const int lk = (threadIdx.x & 3) * 4;
  float acc[4][4] = {};
  for (int k0 = kb; k0 < kb + KS; k0 += 16) {
    float4 a4 = *(const float4*)(A + (size_t)(m0 + lr) * K + k0 + lk);
    float4 w4 = *(const float4*)(Wt + (size_t)(n0 + lr) * K + k0 + lk);
    As[(lk + 0) * 68 + lr] = a4.x;
    As[(lk + 1) * 68 + lr] = a4.y;
    As[(lk + 2) * 68 + lr] = a4.z;
    As[(lk + 3) * 68 + lr] = a4.w;
    Ws[(lk + 0) * 68 + lr] = w4.x;
    Ws[(lk + 1) * 68 + lr] = w4.y;
    Ws[(lk + 2) * 68 + lr] = w4.z;
    Ws[(lk + 3) * 68 + lr] = w4.w;
    __syncthreads();
#pragma unroll
    for (int k = 0; k < 16; ++k) {
      float4 av = *(const float4*)&As[k * 68 + tm * 4];
      float4 wv = *(const float4*)&Ws[k * 68 + tn * 4];
      float a[4] = {av.x, av.y, av.z, av.w};
      float w[4] = {wv.x, wv.y, wv.z, wv.w};
#pragma unroll
      for (int i = 0; i < 4; ++i)
#pragma unroll
        for (int j = 0; j < 4; ++j) acc[i][j] += a[i] * w[j];
    }
    __syncthreads();
  }
  float* Pb = P + (size_t)blockIdx.z * M * N;
#pragma unroll
  for (int i = 0; i < 4; ++i) {
    const int row = m0 + tm * 4 + i;
    const int col = n0 + tn * 4;
    *(float4*)(Pb + (size_t)row * N + col) =
        make_float4(acc[i][0], acc[i][1], acc[i][2], acc[i][3]);
  }
}

// ---------------- split-K reduce (+bias+res), N must be 256 ----------------
__global__ __launch_bounds__(256) void skred_kernel(const float* __restrict__ P,
                                                    const float* __restrict__ bias,
                                                    const float* __restrict__ res,
                                                    float* __restrict__ C) {
  const int idx = blockIdx.x * 256 + threadIdx.x;   // MROWS*CM/4 = 131072
  const int col4 = idx & 63;
  const int row = idx >> 6;
  const float4* P4 = (const float4*)P;
  const int MN4 = MROWS * CM / 4;
  float4 s = P4[idx];
  float4 s1 = P4[idx + MN4];
  float4 s2 = P4[idx + 2 * MN4];
  float4 s3 = P4[idx + 3 * MN4];
  s.x += s1.x + s2.x + s3.x;
  s.y += s1.y + s2.y + s3.y;
  s.z += s1.z + s2.z + s3.z;
  s.w += s1.w + s2.w + s3.w;
  float4 bv = ((const float4*)bias)[col4];
  float4 rv = ((const float4*)(res + (size_t)row * CM))[col4];
  s.x += bv.x + rv.x; s.y += bv.y + rv.y;
  s.z += bv.z + rv.z; s.w += bv.w + rv.w;
  ((float4*)C)[idx] = s;
}

// ---------------- self-attention: single-pass flash (scores provably tiny -> no max) ----------------
#define SKC 64
#define SNC (NQ / SKC)
__global__ __launch_bounds__(256) void sa_flash_kernel(const float* __restrict__ qkv,
                                                       float* __restrict__ o) {
  __shared__ float Qs[16][36];
  __shared__ float Ks[SKC][36];
  __shared__ float Vs[SKC][36];
  __shared__ float Ps[16][68];
  __shared__ float Ored[8 * 16 * 32];

  const int swz = (blockIdx.x & 7) * 128 + (blockIdx.x >> 3);
  const int bh = swz >> 6, qt = swz & 63;
  const int n0 = qt * 16;
  const int b = bh >> 3, h = bh & 7;
  const int tid = threadIdx.x;
  const int lane = tid & 63, wave = tid >> 6;

  const float* rowbase = qkv + (size_t)b * NQ * 768 + h * DH;

  if (tid < 128) {
    const int r = tid >> 3, c4 = (tid & 7) * 4;
    *(float4*)&Qs[r][c4] = *(const float4*)(rowbase + (size_t)(n0 + r) * 768 + c4);
  }
  __syncthreads();

  const int dslot = (tid >> 3) & 7;
  const int kg = tid & 7;
  float ssum[4] = {0.f, 0.f, 0.f, 0.f};
  float o0[4] = {}, o1[4] = {}, o2[4] = {}, o3[4] = {};

#pragma unroll 1
  for (int c = 0; c < SNC; ++c) {
    {
      const int r0 = tid >> 3, c40 = (tid & 7) * 4;
      const int r1 = r0 + 32;
      *(float4*)&Ks[r0][c40] =
          *(const float4*)(rowbase + (size_t)(c * SKC + r0) * 768 + 256 + c40);
      *(float4*)&Ks[r1][c40] =
          *(const float4*)(rowbase + (size_t)(c * SKC + r1) * 768 + 256 + c40);
      *(float4*)&Vs[r0][c40] =
          *(const float4*)(rowbase + (size_t)(c * SKC + r0) * 768 + 512 + c40);
      *(float4*)&Vs[r1][c40] =
          *(const float4*)(rowbase + (size_t)(c * SKC + r1) * 768 + 512 + c40);
    }
    __syncthreads();
    float4 kr[8];
#pragma unroll
    for (int d4 = 0; d4 < 8; ++d4) kr[d4] = *(const float4*)&Ks[lane][d4 * 4];
#pragma unroll
    for (int qi = 0; qi < 4; ++qi) {
      const int q = wave * 4 + qi;
      float s = 0.f;
#pragma unroll
      for (int d4 = 0; d4 < 8; ++d4) {
        float4 q4 = *(const float4*)&Qs[q][d4 * 4];
        s += q4.x * kr[d4].x + q4.y * kr[d4].y + q4.z * kr[d4].z + q4.w * kr[d4].w;
      }
      const float e = __expf(s * 0.17677669529663687f);
      ssum[qi] += e;
      Ps[q][lane] = e;
    }
#pragma unroll
    for (int j = 0; j < 8; ++j) {
      const int kk = kg * 8 + j;
      float4 v4 = *(const float4*)&Vs[kk][dslot * 4];
      const float p0 = Ps[wave * 4 + 0][kk];
      const float p1 = Ps[wave * 4 + 1][kk];
      const float p2 = Ps[wave * 4 + 2][kk];
      const float p3 = Ps[wave * 4 + 3][kk];
      o0[0] += p0 * v4.x; o0[1] += p0 * v4.y; o0[2] += p0 * v4.z; o0[3] += p0 * v4.w;
      o1[0] += p1 * v4.x; o1[1] += p1 * v4.y; o1[2] += p1 * v4.z; o1[3] += p1 * v4.w;
      o2[0] += p2 * v4.x; o2[1] += p2 * v4.y; o2[2] += p2 * v4.z; o2[3] += p2 * v4.w;
      o3[0] += p3 * v4.x; o3[1] += p3 * v4.y; o3[2] += p3 * v4.z; o3[3] += p3 * v4.w;
    }
    __syncthreads();
  }

  float inv[4];
#pragma unroll
  for (int qi = 0; qi < 4; ++qi) {
    float ss = ssum[qi];
#pragma unroll
    for (int off = 32; off > 0; off >>= 1) ss += __shfl_xor(ss, off, 64);
    inv[qi] = 1.f / ss;
  }

#pragma unroll
  for (int j = 0; j < 4; ++j) {
    Ored[kg * (16 * 32) + (wave * 4 + 0) * 32 + dslot * 4 + j] = o0[j] * inv[0];
    Ored[kg * (16 * 32) + (wave * 4 + 1) * 32 + dslot * 4 + j] = o1[j] * inv[1];
    Ored[kg * (16 * 32) + (wave * 4 + 2) * 32 + dslot * 4 + j] = o2[j] * inv[2];
    Ored[kg * (16 * 32) + (wave * 4 + 3) * 32 + dslot * 4 + j] = o3[j] * inv[3];
  }
  __syncthreads();
#pragma unroll
  for (int i = 0; i < 2; ++i) {
    const int idx = tid * 2 + i;
    const int q = idx >> 5, d = idx & 31;
    float s = 0.f;
#pragma unroll
    for (int k = 0; k < 8; ++k) s += Ored[k * (16 * 32) + q * 32 + d];
    o[((size_t)(b * NQ + n0 + q)) * CM + h * DH + d] = s;
  }
}

// ---------------- layer norm (one wave per 256-dim row), f32 out ----------------
__global__ __launch_bounds__(256) void ln_kernel(const float* __restrict__ in,
                                                 const float* __restrict__ w,
                                                 const float* __restrict__ b,
                                                 float* __restrict__ out) {
  const int wv = threadIdx.x >> 6, lane = threadIdx.x & 63;
  const int row = blockIdx.x * 4 + wv;
  float4 v = ((const float4*)(in + (size_t)row * CM))[lane];
  float s = v.x + v.y + v.z + v.w;
#pragma unroll
  for (int off = 32; off > 0; off >>= 1) s += __shfl_xor(s, off, 64);
  const float mu = s * (1.f / 256.f);
  float dx = v.x - mu, dy = v.y - mu, dz = v.z - mu, dw = v.w - mu;
  float q = dx * dx + dy * dy + dz * dz + dw * dw;
#pragma unroll
  for (int off = 32; off > 0; off >>= 1) q += __shfl_xor(q, off, 64);
  const float r = rsqrtf(q * (1.f / 256.f) + 1e-5f);
  float4 wv4 = ((const float4*)w)[lane];
  float4 bv4 = ((const float4*)b)[lane];
  float4 o;
  o.x = dx * r * wv4.x + bv4.x;
  o.y = dy * r * wv4.y + bv4.y;
  o.z = dz * r * wv4.z + bv4.z;
  o.w = dw * r * wv4.w + bv4.w;
  ((float4*)(out + (size_t)row * CM))[lane] = o;
}

// ---------------- depthwise strided conv v5: LDS slab staging + XOR bank swizzle ----
// block = (cid, zh, yh): 2048 blocks x 256 threads = (xo16, yo8_8, zoq2).
// Slab pl[66][128] stores plane rows y = 64*yh-1 .. 64*yh+64 with float4-index
// swizzle f' = f ^ ((r>>3)&3) -> read banks cover all 8 groups (conflict-free).
// Thread accumulates 2 zo outputs; z and kz are wave-uniform (zoq = tid>>7).
__global__ __launch_bounds__(256) void conv_off5_kernel(const float* __restrict__ gt,
                                                        const float* __restrict__ w1,
                                                        const float* __restrict__ b1,
                                                        float* __restrict__ off1) {
  const int bid = blockIdx.x;
  const int yh = bid & 1, zh = (bid >> 1) & 1, cid = bid >> 2;
  const int c = cid & 31;
  const int tid = threadIdx.x;
  const int xo = tid & 15;
  const int yo8 = (tid >> 4) & 7;
  const int zoq = tid >> 7;               // wave-uniform (waves 0,1 -> 0; 2,3 -> 1)
  __shared__ float wsm[400];
  __shared__ float pl[66 * 128];
  for (int i = tid; i < 400; i += 256) wsm[i] = w1[c * 400 + i];

  const float* __restrict__ xp = gt + (size_t)cid * (TV * HV * WV);
  const int zo0 = zh * 4 + zoq * 2;       // thread's zo pair: zo0, zo0+1
  const int ygbase = yh * 64 - 1;
  float acc0 = 0.f, acc1 = 0.f;

#pragma unroll 1
  for (int zz = 0; zz < 10; ++zz) {
    const int z = 8 * zh - 1 + zz;
    if (z < 0 || z > 15) continue;        // block-uniform
    const int kzA = z + 1 - 2 * zo0;      // wave-uniform
    const int kzB = kzA - 2;
    const bool actA = (unsigned)kzA <= 3u;
    const bool actB = (unsigned)kzB <= 3u;
    __syncthreads();
    {
      const float* __restrict__ zp = xp + (size_t)z * (HV * WV);
      for (int i = tid; i < 66 * 32; i += 256) {
        const int r = i >> 5, f = i & 31;
        const int y = ygbase + r;
        float4 v = make_float4(0.f, 0.f, 0.f, 0.f);
        if ((unsigned)y < 128u) v = *(const float4*)(zp + y * WV + 4 * f);
        const int fp = f ^ ((r >> 3) & 3);
        *(float4*)&pl[r * 128 + 4 * fp] = v;
      }
    }
    __syncthreads();
    if (!(actA || actB)) continue;        // wave-uniform; syncs above already done
    const float* __restrict__ wrA = wsm + (actA ? kzA : 0) * 100;
    const float* __restrict__ wrB = wsm + (actB ? kzB : 0) * 100;
#pragma unroll 2
    for (int ky = 0; ky < 10; ++ky) {
      const int r = yo8 * 8 + ky;
      const int s = (r >> 3) & 3;
      const float* __restrict__ rp = &pl[r * 128];
      const float4 a0 = *(const float4*)&rp[((2 * xo) ^ s) * 4];
      const float4 a1 = *(const float4*)&rp[((2 * xo + 1) ^ s) * 4];
      float left = 0.f, right = 0.f;
      if (xo > 0) {
        const int cc = 8 * xo - 1;
        left = rp[((((cc >> 2) ^ s)) << 2) | (cc & 3)];
      }
      if (xo < 15) {
        const int cc = 8 * xo + 8;
        right = rp[((((cc >> 2) ^ s)) << 2) | (cc & 3)];
      }
      if (actA) {
        const float* __restrict__ w = wrA + ky * 10;
        acc0 += w[0] * left + w[1] * a0.x + w[2] * a0.y + w[3] * a0.z + w[4] * a0.w +
                w[5] * a1.x + w[6] * a1.y + w[7] * a1.z + w[8] * a1.w + w[9] * right;
      }
      if (actB) {
        const float* __restrict__ w = wrB + ky * 10;
        acc1 += w[0] * left + w[1] * a0.x + w[2] * a0.y + w[3] * a0.z + w[4] * a0.w +
                w[5] * a1.x + w[6] * a1.y + w[7] * a1.z + w[8] * a1.w + w[9] * right;
      }
    }
  }

  const float bias = b1[c];
  const int yout = yh * 8 + yo8;
  {
    float a = acc0 + bias;
    const float u = 0.7978845608028654f * (a + 0.044715f * a * a * a);
    const float gv = 0.5f * a * (1.f + tanhf(u));
    off1[((size_t)cid * TD + zo0) * (HD * WD) + yout * WD + xo] = gv;
  }
  {
    float a = acc1 + bias;
    const float u = 0.7978845608028654f * (a + 0.044715f * a * a * a);
    const float gv = 0.5f * a * (1.f + tanhf(u));
    off1[((size_t)cid * TD + zo0 + 1) * (HD * WD) + yout * WD + xo] = gv;
  }
}

// ---------------- offset projection + tanh*scale + pixel coords ----------------
__global__ __launch_bounds__(256) void offproj_kernel(const float* __restrict__ off1,
                                                      const float* __restrict__ w2,
                                                      float* __restrict__ pc) {
  const int gid = blockIdx.x * 256 + threadIdx.x;  // 16*2048
  const int bg = gid >> 11, sp = gid & 2047;
  const float* base = off1 + (size_t)bg * 32 * LS + sp;
  float o0 = 0.f, o1 = 0.f, o2 = 0.f;
#pragma unroll
  for (int c = 0; c < 32; ++c) {
    const float v = base[(size_t)c * LS];
    o0 += w2[c] * v;
    o1 += w2[32 + c] * v;
    o2 += w2[64 + c] * v;
  }
  const int gz = sp >> 8, gy = (sp >> 4) & 15, gx = sp & 15;
  const float oz = tanhf(o0) * 2.f;
  const float oy = tanhf(o1) * 8.f;
  const float ox = tanhf(o2) * 8.f;
  float* p = pc + (size_t)gid * 3;
  p[0] = ((float)gz + oz) * (16.f / 7.f) - 0.5f;
  p[1] = ((float)gy + oy) * (128.f / 15.f) - 0.5f;
  p[2] = ((float)gx + ox) * (128.f / 15.f) - 0.5f;
}

// ---------------- trilinear grid sample + per-group k/v projection ----------------
__global__ __launch_bounds__(256) void gsample_kernel(const float* __restrict__ gt,
                                                      const float* __restrict__ pc,
                                                      const float* __restrict__ kw,
                                                      const float* __restrict__ vw,
                                                      float* __restrict__ kbuf,
                                                      float* __restrict__ vbuf) {
  __shared__ float kvv[8][33];
  __shared__ float kws[32][33], vws[32][33];
  const int swz = (blockIdx.x & 7) * 512 + (blockIdx.x >> 3);
  const int bg = swz >> 8, l0 = (swz & 255) * 8;
  const int g = bg & 7;
  const int s = threadIdx.x >> 5, c = threadIdx.x & 31;
  for (int i = threadIdx.x; i < 1024; i += 256) {
    kws[i >> 5][i & 31] = kw[g * 1024 + i];
    vws[i >> 5][i & 31] = vw[g * 1024 + i];
  }
  const int l = l0 + s;
  const float* p = pc + ((size_t)bg * LS + l) * 3;
  const float pz = p[0], py = p[1], px = p[2];
  const float zf = floorf(pz), yf = floorf(py), xf = floorf(px);
  const int z0 = (int)zf, y0 = (int)yf, x0 = (int)xf;
  const float fz = pz - zf, fy = py - yf, fx = px - xf;
  const float* vp = gt + (size_t)(bg * 32 + c) * (TV * HV * WV);
  float acc = 0.f;
#pragma unroll
  for (int dz = 0; dz < 2; ++dz) {
    const int z = z0 + dz;
    if ((unsigned)z >= (unsigned)TV) continue;
    const float wz = dz ? fz : 1.f - fz;
#pragma unroll
    for (int dy = 0; dy < 2; ++dy) {
      const int y = y0 + dy;
      if ((unsigned)y >= (unsigned)HV) continue;
      const float wzy = wz * (dy ? fy : 1.f - fy);
#pragma unroll
      for (int dx = 0; dx < 2; ++dx) {
        const int x = x0 + dx;
        if ((unsigned)x >= (unsigned)WV) continue;
        acc += wzy * (dx ? fx : 1.f - fx) * vp[((size_t)z * HV + y) * WV + x];
      }
    }
  }
  kvv[s][c] = acc;
  __syncthreads();
  float ka = 0.f, va = 0.f;
#pragma unroll
  for (int f = 0; f < 32; ++f) {
    const float kv = kvv[s][f];
    ka += kws[c][f] * kv;
    va += vws[c][f] * kv;
  }
  kbuf[((size_t)bg * LS + l) * 32 + c] = ka;
  vbuf[((size_t)bg * LS + l) * 32 + c] = va;
}

// ---------------- deformable attention: single pass + in-kernel normalize tail ----------------
#define DQT 16
#define DKC 64
#define DNC (LS / DKC)
__global__ __launch_bounds__(256) void dattn_kernel(const float* __restrict__ qb,
                                                    const float* __restrict__ kbuf,
                                                    const float* __restrict__ vbuf,
                                                    float* __restrict__ da_o,
                                                    float* __restrict__ attn_out) {
  __shared__ float Qs[DQT][36];
  __shared__ float Ks[DKC][36];
  __shared__ float Vs[DKC][36];
  __shared__ float Ps[DQT][68];
  __shared__ float Ored[8 * DQT * 32];
  __shared__ float invs[DQT];

  const int swz = (blockIdx.x & 7) * 128 + (blockIdx.x >> 3);
  const int bg = swz >> 6, qt = swz & 63;
  const int n0 = qt * DQT;
  const int b = bg >> 3, g = bg & 7;
  const int tid = threadIdx.x;
  const int lane = tid & 63, wave = tid >> 6;

  const float* kB = kbuf + (size_t)bg * LS * 32;
  const float* vB = vbuf + (size_t)bg * LS * 32;

  if (tid < 128) {
    const int r = tid >> 3, c4 = (tid & 7) * 4;
    *(float4*)&Qs[r][c4] =
        *(const float4*)(qb + ((size_t)(b * NQ + n0 + r)) * CM + g * DH + c4);
  }
  __syncthreads();

  const int dslot = (tid >> 3) & 7;
  const int kg = tid & 7;
  float ssum[4] = {0.f, 0.f, 0.f, 0.f};
  float o0[4] = {}, o1[4] = {}, o2[4] = {}, o3[4] = {};

#pragma unroll 1
  for (int c = 0; c < DNC; ++c) {
    {
      const int r0 = tid >> 3, c40 = (tid & 7) * 4;
      const int r1 = r0 + 32;
      *(float4*)&Ks[r0][c40] = *(const float4*)(kB + (size_t)(c * DKC + r0) * 32 + c40);
      *(float4*)&Ks[r1][c40] = *(const float4*)(kB + (size_t)(c * DKC + r1) * 32 + c40);
      *(float4*)&Vs[r0][c40] = *(const float4*)(vB + (size_t)(c * DKC + r0) * 32 + c40);
      *(float4*)&Vs[r1][c40] = *(const float4*)(vB + (size_t)(c * DKC + r1) * 32 + c40);
    }
    __syncthreads();
    float4 kr[8];
#pragma unroll
    for (int d4 = 0; d4 < 8; ++d4) kr[d4] = *(const float4*)&Ks[lane][d4 * 4];
#pragma unroll
    for (int qi = 0; qi < 4; ++qi) {
      const int q = wave * 4 + qi;
      float s = 0.f;
#pragma unroll
      for (int d4 = 0; d4 < 8; ++d4) {
        float4 q4 = *(const float4*)&Qs[q][d4 * 4];
        s += q4.x * kr[d4].x + q4.y * kr[d4].y + q4.z * kr[d4].z + q4.w * kr[d4].w;
      }
      const float e = __expf(s * 0.17677669529663687f);
      ssum[qi] += e;
      Ps[q][lane] = e;
      attn_out[((size_t)(bg * NQ + n0 + q)) * LS + c * DKC + lane] = e;  // unnormalized
    }
#pragma unroll
    for (int j = 0; j < 8; ++j) {
      const int kk = kg * 8 + j;
      float4 v4 = *(const float4*)&Vs[kk][dslot * 4];
      const float p0 = Ps[wave * 4 + 0][kk];
      const float p1 = Ps[wave * 4 + 1][kk];
      const float p2 = Ps[wave * 4 + 2][kk];
      const float p3 = Ps[wave * 4 + 3][kk];
      o0[0] += p0 * v4.x; o0[1] += p0 * v4.y; o0[2] += p0 * v4.z; o0[3] += p0 * v4.w;
      o1[0] += p1 * v4.x; o1[1] += p1 * v4.y; o1[2] += p1 * v4.z; o1[3] += p1 * v4.w;
      o2[0] += p2 * v4.x; o2[1] += p2 * v4.y; o2[2] += p2 * v4.z; o2[3] += p2 * v4.w;
      o3[0] += p3 * v4.x; o3[1] += p3 * v4.y; o3[2] += p3 * v4.z; o3[3] += p3 * v4.w;
    }
    __syncthreads();
  }

  float inv[4];
#pragma unroll
  for (int qi = 0; qi < 4; ++qi) {
    float ss = ssum[qi];
#pragma unroll
    for (int off = 32; off > 0; off >>= 1) ss += __shfl_xor(ss, off, 64);
    inv[qi] = 1.f / ss;
  }
  if (lane == 0) {
#pragma unroll
    for (int qi = 0; qi < 4; ++qi) invs[wave * 4 + qi] = inv[qi];
  }

#pragma unroll
  for (int j = 0; j < 4; ++j) {
    Ored[kg * (DQT * 32) + (wave * 4 + 0) * 32 + dslot * 4 + j] = o0[j] * inv[0];
    Ored[kg * (DQT * 32) + (wave * 4 + 1) * 32 + dslot * 4 + j] = o1[j] * inv[1];
    Ored[kg * (DQT * 32) + (wave * 4 + 2) * 32 + dslot * 4 + j] = o2[j] * inv[2];
    Ored[kg * (DQT * 32) + (wave * 4 + 3) * 32 + dslot * 4 + j] = o3[j] * inv[3];
  }
  __syncthreads();
#pragma unroll
  for (int i = 0; i < 2; ++i) {
    const int idx = tid * 2 + i;
    const int q = idx >> 5, d = idx & 31;
    float s = 0.f;
#pragma unroll
    for (int k = 0; k < 8; ++k) s += Ored[k * (DQT * 32) + q * 32 + d];
    da_o[((size_t)(b * NQ + n0 + q)) * CM + g * DH + d] = s;
  }

  // ---- normalize attn rows in-place (rows just written -> L2-hot) ----
  const int qrow = tid >> 4;
  const float qinv = invs[qrow];
  float4* arow = (float4*)(attn_out + ((size_t)(bg * NQ + n0 + qrow)) * LS);
#pragma unroll 4
  for (int j = 0; j < 32; ++j) {
    const int col = (tid & 15) + j * 16;
    float4 a = arow[col];
    a.x *= qinv; a.y *= qinv; a.z *= qinv; a.w *= qinv;
    arow[col] = a;
  }
}

// ---------------- launch ----------------
extern "C" void kernel_launch(void* const* d_in, const int* in_sizes, int n_in,
                              void* d_out, int out_size, void* d_ws, size_t ws_size,
                              hipStream_t stream) {
  const float* query    = (const float*)d_in[0];
  const float* gt       = (const float*)d_in[1];
  const float* sa_in_w  = (const float*)d_in[2];
  const float* sa_in_b  = (const float*)d_in[3];
  const float* sa_out_w = (const float*)d_in[4];
  const float* sa_out_b = (const float*)d_in[5];
  const float* q_w      = (const float*)d_in[6];
  const float* off_w1   = (const float*)d_in[7];
  const float* off_b1   = (const float*)d_in[8];
  const float* off_w2   = (const float*)d_in[9];
  const float* k_w      = (const float*)d_in[10];
  const float* v_w      = (const float*)d_in[11];
  const float* da_out_w = (const float*)d_in[12];
  const float* da_out_b = (const float*)d_in[13];
  const float* lin1_w   = (const float*)d_in[14];
  const float* lin1_b   = (const float*)d_in[15];
  const float* lin2_w   = (const float*)d_in[16];
  const float* lin2_b   = (const float*)d_in[17];
  const float* ln1_w    = (const float*)d_in[18];
  const float* ln1_b    = (const float*)d_in[19];
  const float* ln2_w    = (const float*)d_in[20];
  const float* ln2_b    = (const float*)d_in[21];
  const float* ln3_w    = (const float*)d_in[22];
  const float* ln3_b    = (const float*)d_in[23];

  float* ws = (float*)d_ws;
  float* t1      = ws + 0;            // 524288
  float* t2      = ws + 524288;       // 524288
  float* off1    = ws + 1048576;      // 1048576
  float* pcoords = ws + 2097152;      // 98304
  float* k_buf   = ws + 2195456;      // 1048576
  float* v_buf   = ws + 3244032;      // 1048576
  float* q_buf   = ws + 4292608;      // 524288
  float* da_o    = ws + 4816896;      // 524288
  float* qkv_buf = ws + 5341184;      // 1572864
  float* sa_o    = ws + 6914048;      // 524288
  float* t0      = ws + 7438336;      // 524288
  float* u2      = ws + 7962624;      // 524288
  float* skp     = ws + 8486912;      // 2097152 (split-K partials, 4 x 2048 x 256)
  float* hbuf    = ws + 2097152;      // 4194304 (reuses pcoords/k/v/q regions, dead by then)
  float* u3      = ws + 6291456;      // 524288  (reuses qkv region)

  float* out_t    = (float*)d_out;
  float* out_attn = out_t + (size_t)MROWS * CM;

  gemm_nt128<false><<<dim3(MROWS / 128, 768 / 128), 256, 0, stream>>>(
      query, sa_in_w, sa_in_b, nullptr, qkv_buf, MROWS, 768, CM);
  sa_flash_kernel<<<1024, 256, 0, stream>>>(qkv_buf, sa_o);
  gemm_nt<false><<<dim3(MROWS / 64, CM / 64), 256, 0, stream>>>(
      sa_o, sa_out_w, sa_out_b, query, t0, MROWS, CM, CM);
  ln_kernel<<<512, 256, 0, stream>>>(t0, ln1_w, ln1_b, t1);
  conv_off5_kernel<<<2048, 256, 0, stream>>>(gt, off_w1, off_b1, off1);
  offproj_kernel<<<128, 256, 0, stream>>>(off1, off_w2, pcoords);
  gsample_kernel<<<4096, 256, 0, stream>>>(gt, pcoords, k_w, v_w, k_buf, v_buf);
  gemm_nt<false><<<dim3(MROWS / 64, CM / 64), 256, 0, stream>>>(
      t1, q_w, nullptr, nullptr, q_buf, MROWS, CM, CM);
  dattn_kernel<<<1024, 256, 0, stream>>>(q_buf, k_buf, v_buf, da_o, out_attn);
  gemm_nt<false><<<dim3(MROWS / 64, CM / 64), 256, 0, stream>>>(
      da_o, da_out_w, da_out_b, t1, u2, MROWS, CM, CM);
  ln_kernel<<<512, 256, 0, stream>>>(u2, ln2_w, ln2_b, t2);
  gemm_nt128<true><<<dim3(MROWS / 128, FFD / 128), 256, 0, stream>>>(
      t2, lin1_w, lin1_b, nullptr, hbuf, MROWS, FFD, CM);
  gemm_nt_sk<<<dim3(MROWS / 64, CM / 64, 4), 256, 0, stream>>>(
      hbuf, lin2_w, skp, MROWS, CM, FFD, FFD / 4);
  skred_kernel<<<512, 256, 0, stream>>>(skp, lin2_b, t2, u3);
  ln_kernel<<<512, 256, 0, stream>>>(u3, ln3_w, ln3_b, out_t);
}

// Round 13
// 682.414 us; speedup vs baseline: 1.2924x; 1.1087x over previous
//
#include <hip/hip_runtime.h>
#include <hip/hip_bf16.h>

// ---------------- constants ----------------
#define BQ 2
#define NQ 1024
#define CM 256
#define HEADS 8
#define DH 32
#define FFD 2048
#define TV 16
#define HV 128
#define WV 128
#define TD 8
#define HD 16
#define WD 16
#define LS 2048
#define NG 16
#define MROWS 2048

typedef __attribute__((ext_vector_type(8))) short bf16x8;
typedef __attribute__((ext_vector_type(4))) float f32x4;

// ---------------- generic f32 NT GEMM 64x64: C = A@W^T (+bias)(+res)(+relu) ----------------
template <bool RELU>
__global__ __launch_bounds__(256) void gemm_nt(const float* __restrict__ A,
                                               const float* __restrict__ Wt,
                                               const float* __restrict__ bias,
                                               const float* __restrict__ res,
                                               float* __restrict__ C,
                                               int M, int N, int K) {
  __shared__ float As[16 * 68];
  __shared__ float Ws[16 * 68];
  const int tm = threadIdx.x & 15;
  const int tn = threadIdx.x >> 4;
  const int m0 = blockIdx.x * 64, n0 = blockIdx.y * 64;
  const int lr = threadIdx.x >> 2;
  const int lk = (threadIdx.x & 3) * 4;
  float acc[4][4] = {};
  for (int k0 = 0; k0 < K; k0 += 16) {
    float4 a4 = *(const float4*)(A + (size_t)(m0 + lr) * K + k0 + lk);
    float4 w4 = *(const float4*)(Wt + (size_t)(n0 + lr) * K + k0 + lk);
    As[(lk + 0) * 68 + lr] = a4.x;
    As[(lk + 1) * 68 + lr] = a4.y;
    As[(lk + 2) * 68 + lr] = a4.z;
    As[(lk + 3) * 68 + lr] = a4.w;
    Ws[(lk + 0) * 68 + lr] = w4.x;
    Ws[(lk + 1) * 68 + lr] = w4.y;
    Ws[(lk + 2) * 68 + lr] = w4.z;
    Ws[(lk + 3) * 68 + lr] = w4.w;
    __syncthreads();
#pragma unroll
    for (int k = 0; k < 16; ++k) {
      float4 av = *(const float4*)&As[k * 68 + tm * 4];
      float4 wv = *(const float4*)&Ws[k * 68 + tn * 4];
      float a[4] = {av.x, av.y, av.z, av.w};
      float w[4] = {wv.x, wv.y, wv.z, wv.w};
#pragma unroll
      for (int i = 0; i < 4; ++i)
#pragma unroll
        for (int j = 0; j < 4; ++j) acc[i][j] += a[i] * w[j];
    }
    __syncthreads();
  }
#pragma unroll
  for (int i = 0; i < 4; ++i) {
    const int row = m0 + tm * 4 + i;
    const int col = n0 + tn * 4;
    float4 bv = bias ? *(const float4*)(bias + col) : make_float4(0.f, 0.f, 0.f, 0.f);
    float4 rv = res ? *(const float4*)(res + (size_t)row * N + col) : make_float4(0.f, 0.f, 0.f, 0.f);
    float4 o;
    o.x = acc[i][0] + bv.x + rv.x;
    o.y = acc[i][1] + bv.y + rv.y;
    o.z = acc[i][2] + bv.z + rv.z;
    o.w = acc[i][3] + bv.w + rv.w;
    if (RELU) {
      o.x = fmaxf(o.x, 0.f); o.y = fmaxf(o.y, 0.f);
      o.z = fmaxf(o.z, 0.f); o.w = fmaxf(o.w, 0.f);
    }
    *(float4*)(C + (size_t)row * N + col) = o;
  }
}

// ---------------- 128x128-tile f32 NT GEMM, 8x8 acc/thread (qkv) ----------------
template <bool RELU>
__global__ __launch_bounds__(256) void gemm_nt128(const float* __restrict__ A,
                                                  const float* __restrict__ Wt,
                                                  const float* __restrict__ bias,
                                                  const float* __restrict__ res,
                                                  float* __restrict__ C,
                                                  int M, int N, int K) {
  __shared__ float As[8][132];
  __shared__ float Bs[8][132];
  const int tid = threadIdx.x;
  const int tm = tid & 15, tn = tid >> 4;
  const int m0 = blockIdx.x * 128, n0 = blockIdx.y * 128;
  const int lr = tid >> 1, lk = (tid & 1) * 4;
  float acc[8][8] = {};
  const float* Ap = A + (size_t)(m0 + lr) * K + lk;
  const float* Wp = Wt + (size_t)(n0 + lr) * K + lk;
  for (int k0 = 0; k0 < K; k0 += 8) {
    float4 a4 = *(const float4*)(Ap + k0);
    float4 w4 = *(const float4*)(Wp + k0);
    __syncthreads();
    As[lk + 0][lr] = a4.x; As[lk + 1][lr] = a4.y; As[lk + 2][lr] = a4.z; As[lk + 3][lr] = a4.w;
    Bs[lk + 0][lr] = w4.x; Bs[lk + 1][lr] = w4.y; Bs[lk + 2][lr] = w4.z; Bs[lk + 3][lr] = w4.w;
    __syncthreads();
#pragma unroll
    for (int k = 0; k < 8; ++k) {
      float4 a0 = *(const float4*)&As[k][tm * 8];
      float4 a1 = *(const float4*)&As[k][tm * 8 + 4];
      float4 w0 = *(const float4*)&Bs[k][tn * 8];
      float4 w1 = *(const float4*)&Bs[k][tn * 8 + 4];
      float av[8] = {a0.x, a0.y, a0.z, a0.w, a1.x, a1.y, a1.z, a1.w};
      float wv[8] = {w0.x, w0.y, w0.z, w0.w, w1.x, w1.y, w1.z, w1.w};
#pragma unroll
      for (int i = 0; i < 8; ++i)
#pragma unroll
        for (int j = 0; j < 8; ++j) acc[i][j] += av[i] * wv[j];
    }
  }
#pragma unroll
  for (int i = 0; i < 8; ++i) {
    const int row = m0 + tm * 8 + i;
#pragma unroll
    for (int jj = 0; jj < 2; ++jj) {
      const int col = n0 + tn * 8 + jj * 4;
      float4 o = make_float4(acc[i][jj * 4 + 0], acc[i][jj * 4 + 1],
                             acc[i][jj * 4 + 2], acc[i][jj * 4 + 3]);
      if (bias) {
        float4 bv = *(const float4*)(bias + col);
        o.x += bv.x; o.y += bv.y; o.z += bv.z; o.w += bv.w;
      }
      if (res) {
        float4 rv = *(const float4*)(res + (size_t)row * N + col);
        o.x += rv.x; o.y += rv.y; o.z += rv.z; o.w += rv.w;
      }
      if (RELU) {
        o.x = fmaxf(o.x, 0.f); o.y = fmaxf(o.y, 0.f);
        o.z = fmaxf(o.z, 0.f); o.w = fmaxf(o.w, 0.f);
      }
      *(float4*)(C + (size_t)row * N + col) = o;
    }
  }
}

// ---------------- weight cast f32 -> bf16 (lin1_w, lin2_w) ----------------
__global__ __launch_bounds__(256) void castw_kernel(const float* __restrict__ w1,
                                                    const float* __restrict__ w2,
                                                    __hip_bfloat16* __restrict__ w1b,
                                                    __hip_bfloat16* __restrict__ w2b) {
  const int idx = blockIdx.x * 256 + threadIdx.x;   // 262144 float4s total
  const float4* src;
  __hip_bfloat16* dst;
  int off;
  if (idx < 131072) { src = (const float4*)w1; dst = w1b; off = idx; }
  else              { src = (const float4*)w2; dst = w2b; off = idx - 131072; }
  float4 v = src[off];
  dst[off * 4 + 0] = __float2bfloat16(v.x);
  dst[off * 4 + 1] = __float2bfloat16(v.y);
  dst[off * 4 + 2] = __float2bfloat16(v.z);
  dst[off * 4 + 3] = __float2bfloat16(v.w);
}

// ---------------- bf16 MFMA NT GEMM, 128x128 tile, 4 waves (2x2), K-step 32 ----------------
// LIN1: epilogue = +bias, relu, bf16 out. else: f32 partial to Cf + z*M*N (split-K).
template <bool LIN1>
__global__ __launch_bounds__(256) void gemm_bf16_mfma(const ushort* __restrict__ A,
                                                      const ushort* __restrict__ B,
                                                      const float* __restrict__ bias,
                                                      __hip_bfloat16* __restrict__ Cbf,
                                                      float* __restrict__ Cf,
                                                      int M, int N, int K, int kslen) {
  __shared__ ushort Asm[128][40];
  __shared__ ushort Bsm[128][40];
  const int tid = threadIdx.x;
  const int lane = tid & 63, wave = tid >> 6;
  const int wr = wave >> 1, wc = wave & 1;
  const int m0 = blockIdx.x * 128, n0 = blockIdx.y * 128;
  const int kb = blockIdx.z * kslen;
  f32x4 acc[4][4] = {};

  const int r0 = tid >> 1, c0 = (tid & 1) * 16;   // two 8-elt chunks per thread per matrix
  for (int k0 = kb; k0 < kb + kslen; k0 += 32) {
    uint4 ar0 = *(const uint4*)(A + (size_t)(m0 + r0) * K + k0 + c0);
    uint4 ar1 = *(const uint4*)(A + (size_t)(m0 + r0) * K + k0 + c0 + 8);
    uint4 br0 = *(const uint4*)(B + (size_t)(n0 + r0) * K + k0 + c0);
    uint4 br1 = *(const uint4*)(B + (size_t)(n0 + r0) * K + k0 + c0 + 8);
    __syncthreads();
    *(uint4*)&Asm[r0][c0] = ar0;
    *(uint4*)&Asm[r0][c0 + 8] = ar1;
    *(uint4*)&Bsm[r0][c0] = br0;
    *(uint4*)&Bsm[r0][c0 + 8] = br1;
    __syncthreads();
    bf16x8 af[4], bfr[4];
#pragma unroll
    for (int mi = 0; mi < 4; ++mi)
      af[mi] = *(const bf16x8*)&Asm[wr * 64 + mi * 16 + (lane & 15)][(lane >> 4) * 8];
#pragma unroll
    for (int ni = 0; ni < 4; ++ni)
      bfr[ni] = *(const bf16x8*)&Bsm[wc * 64 + ni * 16 + (lane & 15)][(lane >> 4) * 8];
#pragma unroll
    for (int mi = 0; mi < 4; ++mi)
#pragma unroll
      for (int ni = 0; ni < 4; ++ni)
        acc[mi][ni] = __builtin_amdgcn_mfma_f32_16x16x32_bf16(af[mi], bfr[ni], acc[mi][ni], 0, 0, 0);
  }

  const int rbase = (lane >> 4) * 4;
  const int cl = lane & 15;
#pragma unroll
  for (int mi = 0; mi < 4; ++mi) {
    const int rowb = m0 + wr * 64 + mi * 16 + rbase;
#pragma unroll
    for (int ni = 0; ni < 4; ++ni) {
      const int col = n0 + wc * 64 + ni * 16 + cl;
      if (LIN1) {
        const float bv = bias[col];
#pragma unroll
        for (int reg = 0; reg < 4; ++reg) {
          float x = acc[mi][ni][reg] + bv;
          x = fmaxf(x, 0.f);
          Cbf[(size_t)(rowb + reg) * N + col] = __float2bfloat16(x);
        }
      } else {
        float* Pb = Cf + (size_t)blockIdx.z * M * N;
#pragma unroll
        for (int reg = 0; reg < 4; ++reg)
          Pb[(size_t)(rowb + reg) * N + col] = acc[mi][ni][reg];
      }
    }
  }
}

// ---------------- split-K(8) reduce (+bias+res), N = 256 ----------------
__global__ __launch_bounds__(256) void skred8_kernel(const float* __restrict__ P,
                                                     const float* __restrict__ bias,
                                                     const float* __restrict__ res,
                                                     float* __restrict__ C) {
  const int idx = blockIdx.x * 256 + threadIdx.x;   // MROWS*CM/4 = 131072
  const int col4 = idx & 63;
  const int row = idx >> 6;
  const float4* P4 = (const float4*)P;
  const int MN4 = MROWS * CM / 4;
  float4 s = make_float4(0.f, 0.f, 0.f, 0.f);
#pragma unroll
  for (int sl = 0; sl < 8; ++sl) {
    float4 p = P4[idx + sl * MN4];
    s.x += p.x; s.y += p.y; s.z += p.z; s.w += p.w;
  }
  float4 bv = ((const float4*)bias)[col4];
  float4 rv = ((const float4*)(res + (size_t)row * CM))[col4];
  s.x += bv.x + rv.x; s.y += bv.y + rv.y;
  s.z += bv.z + rv.z; s.w += bv.w + rv.w;
  ((float4*)C)[idx] = s;
}

// ---------------- self-attention: single-pass flash ----------------
#define SKC 64
#define SNC (NQ / SKC)
__global__ __launch_bounds__(256) void sa_flash_kernel(const float* __restrict__ qkv,
                                                       float* __restrict__ o) {
  __shared__ float Qs[16][36];
  __shared__ float Ks[SKC][36];
  __shared__ float Vs[SKC][36];
  __shared__ float Ps[16][68];
  __shared__ float Ored[8 * 16 * 32];

  const int swz = (blockIdx.x & 7) * 128 + (blockIdx.x >> 3);
  const int bh = swz >> 6, qt = swz & 63;
  const int n0 = qt * 16;
  const int b = bh >> 3, h = bh & 7;
  const int tid = threadIdx.x;
  const int lane = tid & 63, wave = tid >> 6;

  const float* rowbase = qkv + (size_t)b * NQ * 768 + h * DH;

  if (tid < 128) {
    const int r = tid >> 3, c4 = (tid & 7) * 4;
    *(float4*)&Qs[r][c4] = *(const float4*)(rowbase + (size_t)(n0 + r) * 768 + c4);
  }
  __syncthreads();

  const int dslot = (tid >> 3) & 7;
  const int kg = tid & 7;
  float ssum[4] = {0.f, 0.f, 0.f, 0.f};
  float o0[4] = {}, o1[4] = {}, o2[4] = {}, o3[4] = {};

#pragma unroll 1
  for (int c = 0; c < SNC; ++c) {
    {
      const int r0 = tid >> 3, c40 = (tid & 7) * 4;
      const int r1 = r0 + 32;
      *(float4*)&Ks[r0][c40] =
          *(const float4*)(rowbase + (size_t)(c * SKC + r0) * 768 + 256 + c40);
      *(float4*)&Ks[r1][c40] =
          *(const float4*)(rowbase + (size_t)(c * SKC + r1) * 768 + 256 + c40);
      *(float4*)&Vs[r0][c40] =
          *(const float4*)(rowbase + (size_t)(c * SKC + r0) * 768 + 512 + c40);
      *(float4*)&Vs[r1][c40] =
          *(const float4*)(rowbase + (size_t)(c * SKC + r1) * 768 + 512 + c40);
    }
    __syncthreads();
    float4 kr[8];
#pragma unroll
    for (int d4 = 0; d4 < 8; ++d4) kr[d4] = *(const float4*)&Ks[lane][d4 * 4];
#pragma unroll
    for (int qi = 0; qi < 4; ++qi) {
      const int q = wave * 4 + qi;
      float s = 0.f;
#pragma unroll
      for (int d4 = 0; d4 < 8; ++d4) {
        float4 q4 = *(const float4*)&Qs[q][d4 * 4];
        s += q4.x * kr[d4].x + q4.y * kr[d4].y + q4.z * kr[d4].z + q4.w * kr[d4].w;
      }
      const float e = __expf(s * 0.17677669529663687f);
      ssum[qi] += e;
      Ps[q][lane] = e;
    }
#pragma unroll
    for (int j = 0; j < 8; ++j) {
      const int kk = kg * 8 + j;
      float4 v4 = *(const float4*)&Vs[kk][dslot * 4];
      const float p0 = Ps[wave * 4 + 0][kk];
      const float p1 = Ps[wave * 4 + 1][kk];
      const float p2 = Ps[wave * 4 + 2][kk];
      const float p3 = Ps[wave * 4 + 3][kk];
      o0[0] += p0 * v4.x; o0[1] += p0 * v4.y; o0[2] += p0 * v4.z; o0[3] += p0 * v4.w;
      o1[0] += p1 * v4.x; o1[1] += p1 * v4.y; o1[2] += p1 * v4.z; o1[3] += p1 * v4.w;
      o2[0] += p2 * v4.x; o2[1] += p2 * v4.y; o2[2] += p2 * v4.z; o2[3] += p2 * v4.w;
      o3[0] += p3 * v4.x; o3[1] += p3 * v4.y; o3[2] += p3 * v4.z; o3[3] += p3 * v4.w;
    }
    __syncthreads();
  }

  float inv[4];
#pragma unroll
  for (int qi = 0; qi < 4; ++qi) {
    float ss = ssum[qi];
#pragma unroll
    for (int off = 32; off > 0; off >>= 1) ss += __shfl_xor(ss, off, 64);
    inv[qi] = 1.f / ss;
  }

#pragma unroll
  for (int j = 0; j < 4; ++j) {
    Ored[kg * (16 * 32) + (wave * 4 + 0) * 32 + dslot * 4 + j] = o0[j] * inv[0];
    Ored[kg * (16 * 32) + (wave * 4 + 1) * 32 + dslot * 4 + j] = o1[j] * inv[1];
    Ored[kg * (16 * 32) + (wave * 4 + 2) * 32 + dslot * 4 + j] = o2[j] * inv[2];
    Ored[kg * (16 * 32) + (wave * 4 + 3) * 32 + dslot * 4 + j] = o3[j] * inv[3];
  }
  __syncthreads();
#pragma unroll
  for (int i = 0; i < 2; ++i) {
    const int idx = tid * 2 + i;
    const int q = idx >> 5, d = idx & 31;
    float s = 0.f;
#pragma unroll
    for (int k = 0; k < 8; ++k) s += Ored[k * (16 * 32) + q * 32 + d];
    o[((size_t)(b * NQ + n0 + q)) * CM + h * DH + d] = s;
  }
}

// ---------------- layer norm; optional extra bf16 output ----------------
__global__ __launch_bounds__(256) void ln_kernel(const float* __restrict__ in,
                                                 const float* __restrict__ w,
                                                 const float* __restrict__ b,
                                                 float* __restrict__ out,
                                                 __hip_bfloat16* __restrict__ out_bf) {
  const int wv = threadIdx.x >> 6, lane = threadIdx.x & 63;
  const int row = blockIdx.x * 4 + wv;
  float4 v = ((const float4*)(in + (size_t)row * CM))[lane];
  float s = v.x + v.y + v.z + v.w;
#pragma unroll
  for (int off = 32; off > 0; off >>= 1) s += __shfl_xor(s, off, 64);
  const float mu = s * (1.f / 256.f);
  float dx = v.x - mu, dy = v.y - mu, dz = v.z - mu, dw = v.w - mu;
  float q = dx * dx + dy * dy + dz * dz + dw * dw;
#pragma unroll
  for (int off = 32; off > 0; off >>= 1) q += __shfl_xor(q, off, 64);
  const float r = rsqrtf(q * (1.f / 256.f) + 1e-5f);
  float4 wv4 = ((const float4*)w)[lane];
  float4 bv4 = ((const float4*)b)[lane];
  float4 o;
  o.x = dx * r * wv4.x + bv4.x;
  o.y = dy * r * wv4.y + bv4.y;
  o.z = dz * r * wv4.z + bv4.z;
  o.w = dw * r * wv4.w + bv4.w;
  ((float4*)(out + (size_t)row * CM))[lane] = o;
  if (out_bf) {
    __hip_bfloat16* op = out_bf + (size_t)row * CM + lane * 4;
    op[0] = __float2bfloat16(o.x);
    op[1] = __float2bfloat16(o.y);
    op[2] = __float2bfloat16(o.z);
    op[3] = __float2bfloat16(o.w);
  }
}

// ---------------- depthwise strided conv v6: double-buffered LDS staging (T14) ----
__global__ __launch_bounds__(256) void conv_off6_kernel(const float* __restrict__ gt,
                                                        const float* __restrict__ w1,
                                                        const float* __restrict__ b1,
                                                        float* __restrict__ off1) {
  const int bid = blockIdx.x;
  const int yh = bid & 1, zh = (bid >> 1) & 1, cid = bid >> 2;
  const int c = cid & 31;
  const int tid = threadIdx.x;
  const int xo = tid & 15;
  const int yo8 = (tid >> 4) & 7;
  const int zoq = tid >> 7;
  __shared__ float wsm[400];
  __shared__ float pl[2][66 * 128];
  for (int i = tid; i < 400; i += 256) wsm[i] = w1[c * 400 + i];

  const float* __restrict__ xp = gt + (size_t)cid * (TV * HV * WV);
  const int zo0 = zh * 4 + zoq * 2;
  const int ygbase = yh * 64 - 1;
  const int zlo = zh ? 7 : 0;
  const int zhi = zh ? 15 : 8;
  float acc0 = 0.f, acc1 = 0.f;
  float4 rv[9];

  // prologue: stage plane zlo into buf 0
  {
    const float* __restrict__ zp = xp + (size_t)zlo * (HV * WV);
#pragma unroll
    for (int k = 0; k < 9; ++k) {
      const int i = tid + k * 256;
      if (i < 2112) {
        const int r = i >> 5, f = i & 31;
        const int y = ygbase + r;
        float4 v = make_float4(0.f, 0.f, 0.f, 0.f);
        if ((unsigned)y < 128u) v = *(const float4*)(zp + y * WV + 4 * f);
        const int fp = f ^ ((r >> 3) & 3);
        *(float4*)&pl[0][r * 128 + 4 * fp] = v;
      }
    }
  }
  __syncthreads();

  int cur = 0;
#pragma unroll 1
  for (int z = zlo; z <= zhi; ++z) {
    if (z < zhi) {
      const float* __restrict__ zp = xp + (size_t)(z + 1) * (HV * WV);
#pragma unroll
      for (int k = 0; k < 9; ++k) {
        const int i = tid + k * 256;
        rv[k] = make_float4(0.f, 0.f, 0.f, 0.f);
        if (i < 2112) {
          const int y = ygbase + (i >> 5);
          if ((unsigned)y < 128u) rv[k] = *(const float4*)(zp + y * WV + 4 * (i & 31));
        }
      }
    }
    {
      const int kzA = z + 1 - 2 * zo0;
      const int kzB = kzA - 2;
      const bool actA = (unsigned)kzA <= 3u;
      const bool actB = (unsigned)kzB <= 3u;
      if (actA || actB) {
        const float* __restrict__ wrA = wsm + (actA ? kzA : 0) * 100;
        const float* __restrict__ wrB = wsm + (actB ? kzB : 0) * 100;
#pragma unroll 2
        for (int ky = 0; ky < 10; ++ky) {
          const int r = yo8 * 8 + ky;
          const int s = (r >> 3) & 3;
          const float* __restrict__ rp = &pl[cur][r * 128];
          const float4 a0 = *(const float4*)&rp[((2 * xo) ^ s) * 4];
          const float4 a1 = *(const float4*)&rp[((2 * xo + 1) ^ s) * 4];
          float left = 0.f, right = 0.f;
          if (xo > 0) {
            const int cc = 8 * xo - 1;
            left = rp[((((cc >> 2) ^ s)) << 2) | (cc & 3)];
          }
          if (xo < 15) {
            const int cc = 8 * xo + 8;
            right = rp[((((cc >> 2) ^ s)) << 2) | (cc & 3)];
          }
          if (actA) {
            const float* __restrict__ w = wrA + ky * 10;
            acc0 += w[0] * left + w[1] * a0.x + w[2] * a0.y + w[3] * a0.z + w[4] * a0.w +
                    w[5] * a1.x + w[6] * a1.y + w[7] * a1.z + w[8] * a1.w + w[9] * right;
          }
          if (actB) {
            const float* __restrict__ w = wrB + ky * 10;
            acc1 += w[0] * left + w[1] * a0.x + w[2] * a0.y + w[3] * a0.z + w[4] * a0.w +
                    w[5] * a1.x + w[6] * a1.y + w[7] * a1.z + w[8] * a1.w + w[9] * right;
          }
        }
      }
    }
    if (z < zhi) {
#pragma unroll
      for (int k = 0; k < 9; ++k) {
        const int i = tid + k * 256;
        if (i < 2112) {
          const int r = i >> 5, f = i & 31;
          const int fp = f ^ ((r >> 3) & 3);
          *(float4*)&pl[cur ^ 1][r * 128 + 4 * fp] = rv[k];
        }
      }
    }
    __syncthreads();
    cur ^= 1;
  }

  const float bias = b1[c];
  const int yout = yh * 8 + yo8;
  {
    float a = acc0 + bias;
    const float u = 0.7978845608028654f * (a + 0.044715f * a * a * a);
    const float gv = 0.5f * a * (1.f + tanhf(u));
    off1[((size_t)cid * TD + zo0) * (HD * WD) + yout * WD + xo] = gv;
  }
  {
    float a = acc1 + bias;
    const float u = 0.7978845608028654f * (a + 0.044715f * a * a * a);
    const float gv = 0.5f * a * (1.f + tanhf(u));
    off1[((size_t)cid * TD + zo0 + 1) * (HD * WD) + yout * WD + xo] = gv;
  }
}

// ---------------- offset projection + tanh*scale + pixel coords ----------------
__global__ __launch_bounds__(256) void offproj_kernel(const float* __restrict__ off1,
                                                      const float* __restrict__ w2,
                                                      float* __restrict__ pc) {
  const int gid = blockIdx.x * 256 + threadIdx.x;
  const int bg = gid >> 11, sp = gid & 2047;
  const float* base = off1 + (size_t)bg * 32 * LS + sp;
  float o0 = 0.f, o1 = 0.f, o2 = 0.f;
#pragma unroll
  for (int c = 0; c < 32; ++c) {
    const float v = base[(size_t)c * LS];
    o0 += w2[c] * v;
    o1 += w2[32 + c] * v;
    o2 += w2[64 + c] * v;
  }
  const int gz = sp >> 8, gy = (sp >> 4) & 15, gx = sp & 15;
  const float oz = tanhf(o0) * 2.f;
  const float oy = tanhf(o1) * 8.f;
  const float ox = tanhf(o2) * 8.f;
  float* p = pc + (size_t)gid * 3;
  p[0] = ((float)gz + oz) * (16.f / 7.f) - 0.5f;
  p[1] = ((float)gy + oy) * (128.f / 15.f) - 0.5f;
  p[2] = ((float)gx + ox) * (128.f / 15.f) - 0.5f;
}

// ---------------- trilinear grid sample + per-group k/v projection ----------------
__global__ __launch_bounds__(256) void gsample_kernel(const float* __restrict__ gt,
                                                      const float* __restrict__ pc,
                                                      const float* __restrict__ kw,
                                                      const float* __restrict__ vw,
                                                      float* __restrict__ kbuf,
                                                      float* __restrict__ vbuf) {
  __shared__ float kvv[8][33];
  __shared__ float kws[32][33], vws[32][33];
  const int swz = (blockIdx.x & 7) * 512 + (blockIdx.x >> 3);
  const int bg = swz >> 8, l0 = (swz & 255) * 8;
  const int g = bg & 7;
  const int s = threadIdx.x >> 5, c = threadIdx.x & 31;
  for (int i = threadIdx.x; i < 1024; i += 256) {
    kws[i >> 5][i & 31] = kw[g * 1024 + i];
    vws[i >> 5][i & 31] = vw[g * 1024 + i];
  }
  const int l = l0 + s;
  const float* p = pc + ((size_t)bg * LS + l) * 3;
  const float pz = p[0], py = p[1], px = p[2];
  const float zf = floorf(pz), yf = floorf(py), xf = floorf(px);
  const int z0 = (int)zf, y0 = (int)yf, x0 = (int)xf;
  const float fz = pz - zf, fy = py - yf, fx = px - xf;
  const float* vp = gt + (size_t)(bg * 32 + c) * (TV * HV * WV);
  float acc = 0.f;
#pragma unroll
  for (int dz = 0; dz < 2; ++dz) {
    const int z = z0 + dz;
    if ((unsigned)z >= (unsigned)TV) continue;
    const float wz = dz ? fz : 1.f - fz;
#pragma unroll
    for (int dy = 0; dy < 2; ++dy) {
      const int y = y0 + dy;
      if ((unsigned)y >= (unsigned)HV) continue;
      const float wzy = wz * (dy ? fy : 1.f - fy);
#pragma unroll
      for (int dx = 0; dx < 2; ++dx) {
        const int x = x0 + dx;
        if ((unsigned)x >= (unsigned)WV) continue;
        acc += wzy * (dx ? fx : 1.f - fx) * vp[((size_t)z * HV + y) * WV + x];
      }
    }
  }
  kvv[s][c] = acc;
  __syncthreads();
  float ka = 0.f, va = 0.f;
#pragma unroll
  for (int f = 0; f < 32; ++f) {
    const float kv = kvv[s][f];
    ka += kws[c][f] * kv;
    va += vws[c][f] * kv;
  }
  kbuf[((size_t)bg * LS + l) * 32 + c] = ka;
  vbuf[((size_t)bg * LS + l) * 32 + c] = va;
}

// ---------------- deformable attention: single pass + in-kernel normalize tail ----------------
#define DQT 16
#define DKC 64
#define DNC (LS / DKC)
__global__ __launch_bounds__(256) void dattn_kernel(const float* __restrict__ qb,
                                                    const float* __restrict__ kbuf,
                                                    const float* __restrict__ vbuf,
                                                    float* __restrict__ da_o,
                                                    float* __restrict__ attn_out) {
  __shared__ float Qs[DQT][36];
  __shared__ float Ks[DKC][36];
  __shared__ float Vs[DKC][36];
  __shared__ float Ps[DQT][68];
  __shared__ float Ored[8 * DQT * 32];
  __shared__ float invs[DQT];

  const int swz = (blockIdx.x & 7) * 128 + (blockIdx.x >> 3);
  const int bg = swz >> 6, qt = swz & 63;
  const int n0 = qt * DQT;
  const int b = bg >> 3, g = bg & 7;
  const int tid = threadIdx.x;
  const int lane = tid & 63, wave = tid >> 6;

  const float* kB = kbuf + (size_t)bg * LS * 32;
  const float* vB = vbuf + (size_t)bg * LS * 32;

  if (tid < 128) {
    const int r = tid >> 3, c4 = (tid & 7) * 4;
    *(float4*)&Qs[r][c4] =
        *(const float4*)(qb + ((size_t)(b * NQ + n0 + r)) * CM + g * DH + c4);
  }
  __syncthreads();

  const int dslot = (tid >> 3) & 7;
  const int kg = tid & 7;
  float ssum[4] = {0.f, 0.f, 0.f, 0.f};
  float o0[4] = {}, o1[4] = {}, o2[4] = {}, o3[4] = {};

#pragma unroll 1
  for (int c = 0; c < DNC; ++c) {
    {
      const int r0 = tid >> 3, c40 = (tid & 7) * 4;
      const int r1 = r0 + 32;
      *(float4*)&Ks[r0][c40] = *(const float4*)(kB + (size_t)(c * DKC + r0) * 32 + c40);
      *(float4*)&Ks[r1][c40] = *(const float4*)(kB + (size_t)(c * DKC + r1) * 32 + c40);
      *(float4*)&Vs[r0][c40] = *(const float4*)(vB + (size_t)(c * DKC + r0) * 32 + c40);
      *(float4*)&Vs[r1][c40] = *(const float4*)(vB + (size_t)(c * DKC + r1) * 32 + c40);
    }
    __syncthreads();
    float4 kr[8];
#pragma unroll
    for (int d4 = 0; d4 < 8; ++d4) kr[d4] = *(const float4*)&Ks[lane][d4 * 4];
#pragma unroll
    for (int qi = 0; qi < 4; ++qi) {
      const int q = wave * 4 + qi;
      float s = 0.f;
#pragma unroll
      for (int d4 = 0; d4 < 8; ++d4) {
        float4 q4 = *(const float4*)&Qs[q][d4 * 4];
        s += q4.x * kr[d4].x + q4.y * kr[d4].y + q4.z * kr[d4].z + q4.w * kr[d4].w;
      }
      const float e = __expf(s * 0.17677669529663687f);
      ssum[qi] += e;
      Ps[q][lane] = e;
      attn_out[((size_t)(bg * NQ + n0 + q)) * LS + c * DKC + lane] = e;
    }
#pragma unroll
    for (int j = 0; j < 8; ++j) {
      const int kk = kg * 8 + j;
      float4 v4 = *(const float4*)&Vs[kk][dslot * 4];
      const float p0 = Ps[wave * 4 + 0][kk];
      const float p1 = Ps[wave * 4 + 1][kk];
      const float p2 = Ps[wave * 4 + 2][kk];
      const float p3 = Ps[wave * 4 + 3][kk];
      o0[0] += p0 * v4.x; o0[1] += p0 * v4.y; o0[2] += p0 * v4.z; o0[3] += p0 * v4.w;
      o1[0] += p1 * v4.x; o1[1] += p1 * v4.y; o1[2] += p1 * v4.z; o1[3] += p1 * v4.w;
      o2[0] += p2 * v4.x; o2[1] += p2 * v4.y; o2[2] += p2 * v4.z; o2[3] += p2 * v4.w;
      o3[0] += p3 * v4.x; o3[1] += p3 * v4.y; o3[2] += p3 * v4.z; o3[3] += p3 * v4.w;
    }
    __syncthreads();
  }

  float inv[4];
#pragma unroll
  for (int qi = 0; qi < 4; ++qi) {
    float ss = ssum[qi];
#pragma unroll
    for (int off = 32; off > 0; off >>= 1) ss += __shfl_xor(ss, off, 64);
    inv[qi] = 1.f / ss;
  }
  if (lane == 0) {
#pragma unroll
    for (int qi = 0; qi < 4; ++qi) invs[wave * 4 + qi] = inv[qi];
  }

#pragma unroll
  for (int j = 0; j < 4; ++j) {
    Ored[kg * (DQT * 32) + (wave * 4 + 0) * 32 + dslot * 4 + j] = o0[j] * inv[0];
    Ored[kg * (DQT * 32) + (wave * 4 + 1) * 32 + dslot * 4 + j] = o1[j] * inv[1];
    Ored[kg * (DQT * 32) + (wave * 4 + 2) * 32 + dslot * 4 + j] = o2[j] * inv[2];
    Ored[kg * (DQT * 32) + (wave * 4 + 3) * 32 + dslot * 4 + j] = o3[j] * inv[3];
  }
  __syncthreads();
#pragma unroll
  for (int i = 0; i < 2; ++i) {
    const int idx = tid * 2 + i;
    const int q = idx >> 5, d = idx & 31;
    float s = 0.f;
#pragma unroll
    for (int k = 0; k < 8; ++k) s += Ored[k * (DQT * 32) + q * 32 + d];
    da_o[((size_t)(b * NQ + n0 + q)) * CM + g * DH + d] = s;
  }

  const int qrow = tid >> 4;
  const float qinv = invs[qrow];
  float4* arow = (float4*)(attn_out + ((size_t)(bg * NQ + n0 + qrow)) * LS);
#pragma unroll 4
  for (int j = 0; j < 32; ++j) {
    const int col = (tid & 15) + j * 16;
    float4 a = arow[col];
    a.x *= qinv; a.y *= qinv; a.z *= qinv; a.w *= qinv;
    arow[col] = a;
  }
}

// ---------------- launch ----------------
extern "C" void kernel_launch(void* const* d_in, const int* in_sizes, int n_in,
                              void* d_out, int out_size, void* d_ws, size_t ws_size,
                              hipStream_t stream) {
  const float* query    = (const float*)d_in[0];
  const float* gt       = (const float*)d_in[1];
  const float* sa_in_w  = (const float*)d_in[2];
  const float* sa_in_b  = (const float*)d_in[3];
  const float* sa_out_w = (const float*)d_in[4];
  const float* sa_out_b = (const float*)d_in[5];
  const float* q_w      = (const float*)d_in[6];
  const float* off_w1   = (const float*)d_in[7];
  const float* off_b1   = (const float*)d_in[8];
  const float* off_w2   = (const float*)d_in[9];
  const float* k_w      = (const float*)d_in[10];
  const float* v_w      = (const float*)d_in[11];
  const float* da_out_w = (const float*)d_in[12];
  const float* da_out_b = (const float*)d_in[13];
  const float* lin1_w   = (const float*)d_in[14];
  const float* lin1_b   = (const float*)d_in[15];
  const float* lin2_w   = (const float*)d_in[16];
  const float* lin2_b   = (const float*)d_in[17];
  const float* ln1_w    = (const float*)d_in[18];
  const float* ln1_b    = (const float*)d_in[19];
  const float* ln2_w    = (const float*)d_in[20];
  const float* ln2_b    = (const float*)d_in[21];
  const float* ln3_w    = (const float*)d_in[22];
  const float* ln3_b    = (const float*)d_in[23];

  float* ws = (float*)d_ws;
  float* t1      = ws + 0;            // 524288
  float* t2      = ws + 524288;       // 524288
  float* off1    = ws + 1048576;      // 1048576
  float* pcoords = ws + 2097152;      // 98304
  float* k_buf   = ws + 2195456;      // 1048576
  float* v_buf   = ws + 3244032;      // 1048576
  float* q_buf   = ws + 4292608;      // 524288
  float* da_o    = ws + 4816896;      // 524288
  float* qkv_buf = ws + 5341184;      // 1572864
  float* sa_o    = ws + 6914048;      // 524288
  float* t0      = ws + 7438336;      // 524288
  float* u2      = ws + 7962624;      // 524288
  float* skp     = ws + 8486912;      // 4194304 (split-K8 partials, 8 x 2048 x 256)
  float* u3      = ws + 6291456;      // 524288  (reuses qkv region; qkv dead by then)
  // bf16 tail — sizes in FLOAT units (bf16 count / 2):
  __hip_bfloat16* t2bf   = (__hip_bfloat16*)(ws + 12681216);  // 524288 bf16 = 262144 f
  __hip_bfloat16* w1bf   = (__hip_bfloat16*)(ws + 12943360);  // 524288 bf16 = 262144 f
  __hip_bfloat16* w2bf   = (__hip_bfloat16*)(ws + 13205504);  // 524288 bf16 = 262144 f
  __hip_bfloat16* hbufbf = (__hip_bfloat16*)(ws + 13467648);  // 4194304 bf16 = 2097152 f

  float* out_t    = (float*)d_out;
  float* out_attn = out_t + (size_t)MROWS * CM;

  castw_kernel<<<1024, 256, 0, stream>>>(lin1_w, lin2_w, w1bf, w2bf);
  gemm_nt128<false><<<dim3(MROWS / 128, 768 / 128), 256, 0, stream>>>(
      query, sa_in_w, sa_in_b, nullptr, qkv_buf, MROWS, 768, CM);
  sa_flash_kernel<<<1024, 256, 0, stream>>>(qkv_buf, sa_o);
  gemm_nt<false><<<dim3(MROWS / 64, CM / 64), 256, 0, stream>>>(
      sa_o, sa_out_w, sa_out_b, query, t0, MROWS, CM, CM);
  ln_kernel<<<512, 256, 0, stream>>>(t0, ln1_w, ln1_b, t1, nullptr);
  conv_off6_kernel<<<2048, 256, 0, stream>>>(gt, off_w1, off_b1, off1);
  offproj_kernel<<<128, 256, 0, stream>>>(off1, off_w2, pcoords);
  gsample_kernel<<<4096, 256, 0, stream>>>(gt, pcoords, k_w, v_w, k_buf, v_buf);
  gemm_nt<false><<<dim3(MROWS / 64, CM / 64), 256, 0, stream>>>(
      t1, q_w, nullptr, nullptr, q_buf, MROWS, CM, CM);
  dattn_kernel<<<1024, 256, 0, stream>>>(q_buf, k_buf, v_buf, da_o, out_attn);
  gemm_nt<false><<<dim3(MROWS / 64, CM / 64), 256, 0, stream>>>(
      da_o, da_out_w, da_out_b, t1, u2, MROWS, CM, CM);
  ln_kernel<<<512, 256, 0, stream>>>(u2, ln2_w, ln2_b, t2, t2bf);
  // FFN up: bf16 MFMA, relu+bias, bf16 out
  gemm_bf16_mfma<true><<<dim3(MROWS / 128, FFD / 128, 1), 256, 0, stream>>>(
      (const ushort*)t2bf, (const ushort*)w1bf, lin1_b, hbufbf, nullptr,
      MROWS, FFD, CM, CM);
  // FFN down: bf16 MFMA split-K(8) partials + reduce(+bias+res)
  gemm_bf16_mfma<false><<<dim3(MROWS / 128, CM / 128, 8), 256, 0, stream>>>(
      (const ushort*)hbufbf, (const ushort*)w2bf, nullptr, nullptr, skp,
      MROWS, CM, FFD, FFD / 8);
  skred8_kernel<<<512, 256, 0, stream>>>(skp, lin2_b, t2, u3);
  ln_kernel<<<512, 256, 0, stream>>>(u3, ln3_w, ln3_b, out_t, nullptr);
}

// Round 14
// 541.299 us; speedup vs baseline: 1.6293x; 1.2607x over previous
//
#include <hip/hip_runtime.h>
#include <hip/hip_bf16.h>

// ---------------- constants ----------------
#define BQ 2
#define NQ 1024
#define CM 256
#define HEADS 8
#define DH 32
#define FFD 2048
#define TV 16
#define HV 128
#define WV 128
#define TD 8
#define HD 16
#define WD 16
#define LS 2048
#define NG 16
#define MROWS 2048

typedef __attribute__((ext_vector_type(8))) short bf16x8;
typedef __attribute__((ext_vector_type(4))) float f32x4;

__device__ __forceinline__ ushort f2bf(float x) {
  __hip_bfloat16 h = __float2bfloat16(x);
  return *(ushort*)&h;
}

// ---------------- generic f32 NT GEMM 64x64: C = A@W^T (+bias)(+res)(+relu) ----------------
template <bool RELU>
__global__ __launch_bounds__(256) void gemm_nt(const float* __restrict__ A,
                                               const float* __restrict__ Wt,
                                               const float* __restrict__ bias,
                                               const float* __restrict__ res,
                                               float* __restrict__ C,
                                               int M, int N, int K) {
  __shared__ float As[16 * 68];
  __shared__ float Ws[16 * 68];
  const int tm = threadIdx.x & 15;
  const int tn = threadIdx.x >> 4;
  const int m0 = blockIdx.x * 64, n0 = blockIdx.y * 64;
  const int lr = threadIdx.x >> 2;
  const int lk = (threadIdx.x & 3) * 4;
  float acc[4][4] = {};
  for (int k0 = 0; k0 < K; k0 += 16) {
    float4 a4 = *(const float4*)(A + (size_t)(m0 + lr) * K + k0 + lk);
    float4 w4 = *(const float4*)(Wt + (size_t)(n0 + lr) * K + k0 + lk);
    As[(lk + 0) * 68 + lr] = a4.x;
    As[(lk + 1) * 68 + lr] = a4.y;
    As[(lk + 2) * 68 + lr] = a4.z;
    As[(lk + 3) * 68 + lr] = a4.w;
    Ws[(lk + 0) * 68 + lr] = w4.x;
    Ws[(lk + 1) * 68 + lr] = w4.y;
    Ws[(lk + 2) * 68 + lr] = w4.z;
    Ws[(lk + 3) * 68 + lr] = w4.w;
    __syncthreads();
#pragma unroll
    for (int k = 0; k < 16; ++k) {
      float4 av = *(const float4*)&As[k * 68 + tm * 4];
      float4 wv = *(const float4*)&Ws[k * 68 + tn * 4];
      float a[4] = {av.x, av.y, av.z, av.w};
      float w[4] = {wv.x, wv.y, wv.z, wv.w};
#pragma unroll
      for (int i = 0; i < 4; ++i)
#pragma unroll
        for (int j = 0; j < 4; ++j) acc[i][j] += a[i] * w[j];
    }
    __syncthreads();
  }
#pragma unroll
  for (int i = 0; i < 4; ++i) {
    const int row = m0 + tm * 4 + i;
    const int col = n0 + tn * 4;
    float4 bv = bias ? *(const float4*)(bias + col) : make_float4(0.f, 0.f, 0.f, 0.f);
    float4 rv = res ? *(const float4*)(res + (size_t)row * N + col) : make_float4(0.f, 0.f, 0.f, 0.f);
    float4 o;
    o.x = acc[i][0] + bv.x + rv.x;
    o.y = acc[i][1] + bv.y + rv.y;
    o.z = acc[i][2] + bv.z + rv.z;
    o.w = acc[i][3] + bv.w + rv.w;
    if (RELU) {
      o.x = fmaxf(o.x, 0.f); o.y = fmaxf(o.y, 0.f);
      o.z = fmaxf(o.z, 0.f); o.w = fmaxf(o.w, 0.f);
    }
    *(float4*)(C + (size_t)row * N + col) = o;
  }
}

// ---------------- 128x128-tile f32 NT GEMM, 8x8 acc/thread (qkv) ----------------
template <bool RELU>
__global__ __launch_bounds__(256) void gemm_nt128(const float* __restrict__ A,
                                                  const float* __restrict__ Wt,
                                                  const float* __restrict__ bias,
                                                  const float* __restrict__ res,
                                                  float* __restrict__ C,
                                                  int M, int N, int K) {
  __shared__ float As[8][132];
  __shared__ float Bs[8][132];
  const int tid = threadIdx.x;
  const int tm = tid & 15, tn = tid >> 4;
  const int m0 = blockIdx.x * 128, n0 = blockIdx.y * 128;
  const int lr = tid >> 1, lk = (tid & 1) * 4;
  float acc[8][8] = {};
  const float* Ap = A + (size_t)(m0 + lr) * K + lk;
  const float* Wp = Wt + (size_t)(n0 + lr) * K + lk;
  for (int k0 = 0; k0 < K; k0 += 8) {
    float4 a4 = *(const float4*)(Ap + k0);
    float4 w4 = *(const float4*)(Wp + k0);
    __syncthreads();
    As[lk + 0][lr] = a4.x; As[lk + 1][lr] = a4.y; As[lk + 2][lr] = a4.z; As[lk + 3][lr] = a4.w;
    Bs[lk + 0][lr] = w4.x; Bs[lk + 1][lr] = w4.y; Bs[lk + 2][lr] = w4.z; Bs[lk + 3][lr] = w4.w;
    __syncthreads();
#pragma unroll
    for (int k = 0; k < 8; ++k) {
      float4 a0 = *(const float4*)&As[k][tm * 8];
      float4 a1 = *(const float4*)&As[k][tm * 8 + 4];
      float4 w0 = *(const float4*)&Bs[k][tn * 8];
      float4 w1 = *(const float4*)&Bs[k][tn * 8 + 4];
      float av[8] = {a0.x, a0.y, a0.z, a0.w, a1.x, a1.y, a1.z, a1.w};
      float wv[8] = {w0.x, w0.y, w0.z, w0.w, w1.x, w1.y, w1.z, w1.w};
#pragma unroll
      for (int i = 0; i < 8; ++i)
#pragma unroll
        for (int j = 0; j < 8; ++j) acc[i][j] += av[i] * wv[j];
    }
  }
#pragma unroll
  for (int i = 0; i < 8; ++i) {
    const int row = m0 + tm * 8 + i;
#pragma unroll
    for (int jj = 0; jj < 2; ++jj) {
      const int col = n0 + tn * 8 + jj * 4;
      float4 o = make_float4(acc[i][jj * 4 + 0], acc[i][jj * 4 + 1],
                             acc[i][jj * 4 + 2], acc[i][jj * 4 + 3]);
      if (bias) {
        float4 bv = *(const float4*)(bias + col);
        o.x += bv.x; o.y += bv.y; o.z += bv.z; o.w += bv.w;
      }
      if (res) {
        float4 rv = *(const float4*)(res + (size_t)row * N + col);
        o.x += rv.x; o.y += rv.y; o.z += rv.z; o.w += rv.w;
      }
      if (RELU) {
        o.x = fmaxf(o.x, 0.f); o.y = fmaxf(o.y, 0.f);
        o.z = fmaxf(o.z, 0.f); o.w = fmaxf(o.w, 0.f);
      }
      *(float4*)(C + (size_t)row * N + col) = o;
    }
  }
}

// ---------------- weight cast f32 -> bf16 (lin1_w, lin2_w) ----------------
__global__ __launch_bounds__(256) void castw_kernel(const float* __restrict__ w1,
                                                    const float* __restrict__ w2,
                                                    __hip_bfloat16* __restrict__ w1b,
                                                    __hip_bfloat16* __restrict__ w2b) {
  const int idx = blockIdx.x * 256 + threadIdx.x;
  const float4* src;
  __hip_bfloat16* dst;
  int off;
  if (idx < 131072) { src = (const float4*)w1; dst = w1b; off = idx; }
  else              { src = (const float4*)w2; dst = w2b; off = idx - 131072; }
  float4 v = src[off];
  dst[off * 4 + 0] = __float2bfloat16(v.x);
  dst[off * 4 + 1] = __float2bfloat16(v.y);
  dst[off * 4 + 2] = __float2bfloat16(v.z);
  dst[off * 4 + 3] = __float2bfloat16(v.w);
}

// ---------------- bf16 MFMA NT GEMM, 128x128 tile, 4 waves (2x2), K-step 32 ----------------
template <bool LIN1>
__global__ __launch_bounds__(256) void gemm_bf16_mfma(const ushort* __restrict__ A,
                                                      const ushort* __restrict__ B,
                                                      const float* __restrict__ bias,
                                                      __hip_bfloat16* __restrict__ Cbf,
                                                      float* __restrict__ Cf,
                                                      int M, int N, int K, int kslen) {
  __shared__ ushort Asm[128][40];
  __shared__ ushort Bsm[128][40];
  const int tid = threadIdx.x;
  const int lane = tid & 63, wave = tid >> 6;
  const int wr = wave >> 1, wc = wave & 1;
  const int m0 = blockIdx.x * 128, n0 = blockIdx.y * 128;
  const int kb = blockIdx.z * kslen;
  f32x4 acc[4][4] = {};

  const int r0 = tid >> 1, c0 = (tid & 1) * 16;
  for (int k0 = kb; k0 < kb + kslen; k0 += 32) {
    uint4 ar0 = *(const uint4*)(A + (size_t)(m0 + r0) * K + k0 + c0);
    uint4 ar1 = *(const uint4*)(A + (size_t)(m0 + r0) * K + k0 + c0 + 8);
    uint4 br0 = *(const uint4*)(B + (size_t)(n0 + r0) * K + k0 + c0);
    uint4 br1 = *(const uint4*)(B + (size_t)(n0 + r0) * K + k0 + c0 + 8);
    __syncthreads();
    *(uint4*)&Asm[r0][c0] = ar0;
    *(uint4*)&Asm[r0][c0 + 8] = ar1;
    *(uint4*)&Bsm[r0][c0] = br0;
    *(uint4*)&Bsm[r0][c0 + 8] = br1;
    __syncthreads();
    bf16x8 af[4], bfr[4];
#pragma unroll
    for (int mi = 0; mi < 4; ++mi)
      af[mi] = *(const bf16x8*)&Asm[wr * 64 + mi * 16 + (lane & 15)][(lane >> 4) * 8];
#pragma unroll
    for (int ni = 0; ni < 4; ++ni)
      bfr[ni] = *(const bf16x8*)&Bsm[wc * 64 + ni * 16 + (lane & 15)][(lane >> 4) * 8];
#pragma unroll
    for (int mi = 0; mi < 4; ++mi)
#pragma unroll
      for (int ni = 0; ni < 4; ++ni)
        acc[mi][ni] = __builtin_amdgcn_mfma_f32_16x16x32_bf16(af[mi], bfr[ni], acc[mi][ni], 0, 0, 0);
  }

  const int rbase = (lane >> 4) * 4;
  const int cl = lane & 15;
#pragma unroll
  for (int mi = 0; mi < 4; ++mi) {
    const int rowb = m0 + wr * 64 + mi * 16 + rbase;
#pragma unroll
    for (int ni = 0; ni < 4; ++ni) {
      const int col = n0 + wc * 64 + ni * 16 + cl;
      if (LIN1) {
        const float bv = bias[col];
#pragma unroll
        for (int reg = 0; reg < 4; ++reg) {
          float x = acc[mi][ni][reg] + bv;
          x = fmaxf(x, 0.f);
          Cbf[(size_t)(rowb + reg) * N + col] = __float2bfloat16(x);
        }
      } else {
        float* Pb = Cf + (size_t)blockIdx.z * M * N;
#pragma unroll
        for (int reg = 0; reg < 4; ++reg)
          Pb[(size_t)(rowb + reg) * N + col] = acc[mi][ni][reg];
      }
    }
  }
}

// ---------------- split-K(8) reduce (+bias+res), N = 256 ----------------
__global__ __launch_bounds__(256) void skred8_kernel(const float* __restrict__ P,
                                                     const float* __restrict__ bias,
                                                     const float* __restrict__ res,
                                                     float* __restrict__ C) {
  const int idx = blockIdx.x * 256 + threadIdx.x;
  const int col4 = idx & 63;
  const int row = idx >> 6;
  const float4* P4 = (const float4*)P;
  const int MN4 = MROWS * CM / 4;
  float4 s = make_float4(0.f, 0.f, 0.f, 0.f);
#pragma unroll
  for (int sl = 0; sl < 8; ++sl) {
    float4 p = P4[idx + sl * MN4];
    s.x += p.x; s.y += p.y; s.z += p.z; s.w += p.w;
  }
  float4 bv = ((const float4*)bias)[col4];
  float4 rv = ((const float4*)(res + (size_t)row * CM))[col4];
  s.x += bv.x + rv.x; s.y += bv.y + rv.y;
  s.z += bv.z + rv.z; s.w += bv.w + rv.w;
  ((float4*)C)[idx] = s;
}

// ---------------- self-attention: single-pass flash ----------------
#define SKC 64
#define SNC (NQ / SKC)
__global__ __launch_bounds__(256) void sa_flash_kernel(const float* __restrict__ qkv,
                                                       float* __restrict__ o) {
  __shared__ float Qs[16][36];
  __shared__ float Ks[SKC][36];
  __shared__ float Vs[SKC][36];
  __shared__ float Ps[16][68];
  __shared__ float Ored[8 * 16 * 32];

  const int swz = (blockIdx.x & 7) * 128 + (blockIdx.x >> 3);
  const int bh = swz >> 6, qt = swz & 63;
  const int n0 = qt * 16;
  const int b = bh >> 3, h = bh & 7;
  const int tid = threadIdx.x;
  const int lane = tid & 63, wave = tid >> 6;

  const float* rowbase = qkv + (size_t)b * NQ * 768 + h * DH;

  if (tid < 128) {
    const int r = tid >> 3, c4 = (tid & 7) * 4;
    *(float4*)&Qs[r][c4] = *(const float4*)(rowbase + (size_t)(n0 + r) * 768 + c4);
  }
  __syncthreads();

  const int dslot = (tid >> 3) & 7;
  const int kg = tid & 7;
  float ssum[4] = {0.f, 0.f, 0.f, 0.f};
  float o0[4] = {}, o1[4] = {}, o2[4] = {}, o3[4] = {};

#pragma unroll 1
  for (int c = 0; c < SNC; ++c) {
    {
      const int r0 = tid >> 3, c40 = (tid & 7) * 4;
      const int r1 = r0 + 32;
      *(float4*)&Ks[r0][c40] =
          *(const float4*)(rowbase + (size_t)(c * SKC + r0) * 768 + 256 + c40);
      *(float4*)&Ks[r1][c40] =
          *(const float4*)(rowbase + (size_t)(c * SKC + r1) * 768 + 256 + c40);
      *(float4*)&Vs[r0][c40] =
          *(const float4*)(rowbase + (size_t)(c * SKC + r0) * 768 + 512 + c40);
      *(float4*)&Vs[r1][c40] =
          *(const float4*)(rowbase + (size_t)(c * SKC + r1) * 768 + 512 + c40);
    }
    __syncthreads();
    float4 kr[8];
#pragma unroll
    for (int d4 = 0; d4 < 8; ++d4) kr[d4] = *(const float4*)&Ks[lane][d4 * 4];
#pragma unroll
    for (int qi = 0; qi < 4; ++qi) {
      const int q = wave * 4 + qi;
      float s = 0.f;
#pragma unroll
      for (int d4 = 0; d4 < 8; ++d4) {
        float4 q4 = *(const float4*)&Qs[q][d4 * 4];
        s += q4.x * kr[d4].x + q4.y * kr[d4].y + q4.z * kr[d4].z + q4.w * kr[d4].w;
      }
      const float e = __expf(s * 0.17677669529663687f);
      ssum[qi] += e;
      Ps[q][lane] = e;
    }
#pragma unroll
    for (int j = 0; j < 8; ++j) {
      const int kk = kg * 8 + j;
      float4 v4 = *(const float4*)&Vs[kk][dslot * 4];
      const float p0 = Ps[wave * 4 + 0][kk];
      const float p1 = Ps[wave * 4 + 1][kk];
      const float p2 = Ps[wave * 4 + 2][kk];
      const float p3 = Ps[wave * 4 + 3][kk];
      o0[0] += p0 * v4.x; o0[1] += p0 * v4.y; o0[2] += p0 * v4.z; o0[3] += p0 * v4.w;
      o1[0] += p1 * v4.x; o1[1] += p1 * v4.y; o1[2] += p1 * v4.z; o1[3] += p1 * v4.w;
      o2[0] += p2 * v4.x; o2[1] += p2 * v4.y; o2[2] += p2 * v4.z; o2[3] += p2 * v4.w;
      o3[0] += p3 * v4.x; o3[1] += p3 * v4.y; o3[2] += p3 * v4.z; o3[3] += p3 * v4.w;
    }
    __syncthreads();
  }

  float inv[4];
#pragma unroll
  for (int qi = 0; qi < 4; ++qi) {
    float ss = ssum[qi];
#pragma unroll
    for (int off = 32; off > 0; off >>= 1) ss += __shfl_xor(ss, off, 64);
    inv[qi] = 1.f / ss;
  }

#pragma unroll
  for (int j = 0; j < 4; ++j) {
    Ored[kg * (16 * 32) + (wave * 4 + 0) * 32 + dslot * 4 + j] = o0[j] * inv[0];
    Ored[kg * (16 * 32) + (wave * 4 + 1) * 32 + dslot * 4 + j] = o1[j] * inv[1];
    Ored[kg * (16 * 32) + (wave * 4 + 2) * 32 + dslot * 4 + j] = o2[j] * inv[2];
    Ored[kg * (16 * 32) + (wave * 4 + 3) * 32 + dslot * 4 + j] = o3[j] * inv[3];
  }
  __syncthreads();
#pragma unroll
  for (int i = 0; i < 2; ++i) {
    const int idx = tid * 2 + i;
    const int q = idx >> 5, d = idx & 31;
    float s = 0.f;
#pragma unroll
    for (int k = 0; k < 8; ++k) s += Ored[k * (16 * 32) + q * 32 + d];
    o[((size_t)(b * NQ + n0 + q)) * CM + h * DH + d] = s;
  }
}

// ---------------- layer norm; optional extra bf16 output ----------------
__global__ __launch_bounds__(256) void ln_kernel(const float* __restrict__ in,
                                                 const float* __restrict__ w,
                                                 const float* __restrict__ b,
                                                 float* __restrict__ out,
                                                 __hip_bfloat16* __restrict__ out_bf) {
  const int wv = threadIdx.x >> 6, lane = threadIdx.x & 63;
  const int row = blockIdx.x * 4 + wv;
  float4 v = ((const float4*)(in + (size_t)row * CM))[lane];
  float s = v.x + v.y + v.z + v.w;
#pragma unroll
  for (int off = 32; off > 0; off >>= 1) s += __shfl_xor(s, off, 64);
  const float mu = s * (1.f / 256.f);
  float dx = v.x - mu, dy = v.y - mu, dz = v.z - mu, dw = v.w - mu;
  float q = dx * dx + dy * dy + dz * dz + dw * dw;
#pragma unroll
  for (int off = 32; off > 0; off >>= 1) q += __shfl_xor(q, off, 64);
  const float r = rsqrtf(q * (1.f / 256.f) + 1e-5f);
  float4 wv4 = ((const float4*)w)[lane];
  float4 bv4 = ((const float4*)b)[lane];
  float4 o;
  o.x = dx * r * wv4.x + bv4.x;
  o.y = dy * r * wv4.y + bv4.y;
  o.z = dz * r * wv4.z + bv4.z;
  o.w = dw * r * wv4.w + bv4.w;
  ((float4*)(out + (size_t)row * CM))[lane] = o;
  if (out_bf) {
    __hip_bfloat16* op = out_bf + (size_t)row * CM + lane * 4;
    op[0] = __float2bfloat16(o.x);
    op[1] = __float2bfloat16(o.y);
    op[2] = __float2bfloat16(o.z);
    op[3] = __float2bfloat16(o.w);
  }
}

// ---------------- depthwise strided conv v6: double-buffered LDS staging ----
__global__ __launch_bounds__(256) void conv_off6_kernel(const float* __restrict__ gt,
                                                        const float* __restrict__ w1,
                                                        const float* __restrict__ b1,
                                                        float* __restrict__ off1) {
  const int bid = blockIdx.x;
  const int yh = bid & 1, zh = (bid >> 1) & 1, cid = bid >> 2;
  const int c = cid & 31;
  const int tid = threadIdx.x;
  const int xo = tid & 15;
  const int yo8 = (tid >> 4) & 7;
  const int zoq = tid >> 7;
  __shared__ float wsm[400];
  __shared__ float pl[2][66 * 128];
  for (int i = tid; i < 400; i += 256) wsm[i] = w1[c * 400 + i];

  const float* __restrict__ xp = gt + (size_t)cid * (TV * HV * WV);
  const int zo0 = zh * 4 + zoq * 2;
  const int ygbase = yh * 64 - 1;
  const int zlo = zh ? 7 : 0;
  const int zhi = zh ? 15 : 8;
  float acc0 = 0.f, acc1 = 0.f;
  float4 rv[9];

  {
    const float* __restrict__ zp = xp + (size_t)zlo * (HV * WV);
#pragma unroll
    for (int k = 0; k < 9; ++k) {
      const int i = tid + k * 256;
      if (i < 2112) {
        const int r = i >> 5, f = i & 31;
        const int y = ygbase + r;
        float4 v = make_float4(0.f, 0.f, 0.f, 0.f);
        if ((unsigned)y < 128u) v = *(const float4*)(zp + y * WV + 4 * f);
        const int fp = f ^ ((r >> 3) & 3);
        *(float4*)&pl[0][r * 128 + 4 * fp] = v;
      }
    }
  }
  __syncthreads();

  int cur = 0;
#pragma unroll 1
  for (int z = zlo; z <= zhi; ++z) {
    if (z < zhi) {
      const float* __restrict__ zp = xp + (size_t)(z + 1) * (HV * WV);
#pragma unroll
      for (int k = 0; k < 9; ++k) {
        const int i = tid + k * 256;
        rv[k] = make_float4(0.f, 0.f, 0.f, 0.f);
        if (i < 2112) {
          const int y = ygbase + (i >> 5);
          if ((unsigned)y < 128u) rv[k] = *(const float4*)(zp + y * WV + 4 * (i & 31));
        }
      }
    }
    {
      const int kzA = z + 1 - 2 * zo0;
      const int kzB = kzA - 2;
      const bool actA = (unsigned)kzA <= 3u;
      const bool actB = (unsigned)kzB <= 3u;
      if (actA || actB) {
        const float* __restrict__ wrA = wsm + (actA ? kzA : 0) * 100;
        const float* __restrict__ wrB = wsm + (actB ? kzB : 0) * 100;
#pragma unroll 2
        for (int ky = 0; ky < 10; ++ky) {
          const int r = yo8 * 8 + ky;
          const int s = (r >> 3) & 3;
          const float* __restrict__ rp = &pl[cur][r * 128];
          const float4 a0 = *(const float4*)&rp[((2 * xo) ^ s) * 4];
          const float4 a1 = *(const float4*)&rp[((2 * xo + 1) ^ s) * 4];
          float left = 0.f, right = 0.f;
          if (xo > 0) {
            const int cc = 8 * xo - 1;
            left = rp[((((cc >> 2) ^ s)) << 2) | (cc & 3)];
          }
          if (xo < 15) {
            const int cc = 8 * xo + 8;
            right = rp[((((cc >> 2) ^ s)) << 2) | (cc & 3)];
          }
          if (actA) {
            const float* __restrict__ w = wrA + ky * 10;
            acc0 += w[0] * left + w[1] * a0.x + w[2] * a0.y + w[3] * a0.z + w[4] * a0.w +
                    w[5] * a1.x + w[6] * a1.y + w[7] * a1.z + w[8] * a1.w + w[9] * right;
          }
          if (actB) {
            const float* __restrict__ w = wrB + ky * 10;
            acc1 += w[0] * left + w[1] * a0.x + w[2] * a0.y + w[3] * a0.z + w[4] * a0.w +
                    w[5] * a1.x + w[6] * a1.y + w[7] * a1.z + w[8] * a1.w + w[9] * right;
          }
        }
      }
    }
    if (z < zhi) {
#pragma unroll
      for (int k = 0; k < 9; ++k) {
        const int i = tid + k * 256;
        if (i < 2112) {
          const int r = i >> 5, f = i & 31;
          const int fp = f ^ ((r >> 3) & 3);
          *(float4*)&pl[cur ^ 1][r * 128 + 4 * fp] = rv[k];
        }
      }
    }
    __syncthreads();
    cur ^= 1;
  }

  const float bias = b1[c];
  const int yout = yh * 8 + yo8;
  {
    float a = acc0 + bias;
    const float u = 0.7978845608028654f * (a + 0.044715f * a * a * a);
    const float gv = 0.5f * a * (1.f + tanhf(u));
    off1[((size_t)cid * TD + zo0) * (HD * WD) + yout * WD + xo] = gv;
  }
  {
    float a = acc1 + bias;
    const float u = 0.7978845608028654f * (a + 0.044715f * a * a * a);
    const float gv = 0.5f * a * (1.f + tanhf(u));
    off1[((size_t)cid * TD + zo0 + 1) * (HD * WD) + yout * WD + xo] = gv;
  }
}

// ---------------- offset projection + tanh*scale + pixel coords ----------------
__global__ __launch_bounds__(256) void offproj_kernel(const float* __restrict__ off1,
                                                      const float* __restrict__ w2,
                                                      float* __restrict__ pc) {
  const int gid = blockIdx.x * 256 + threadIdx.x;
  const int bg = gid >> 11, sp = gid & 2047;
  const float* base = off1 + (size_t)bg * 32 * LS + sp;
  float o0 = 0.f, o1 = 0.f, o2 = 0.f;
#pragma unroll
  for (int c = 0; c < 32; ++c) {
    const float v = base[(size_t)c * LS];
    o0 += w2[c] * v;
    o1 += w2[32 + c] * v;
    o2 += w2[64 + c] * v;
  }
  const int gz = sp >> 8, gy = (sp >> 4) & 15, gx = sp & 15;
  const float oz = tanhf(o0) * 2.f;
  const float oy = tanhf(o1) * 8.f;
  const float ox = tanhf(o2) * 8.f;
  float* p = pc + (size_t)gid * 3;
  p[0] = ((float)gz + oz) * (16.f / 7.f) - 0.5f;
  p[1] = ((float)gy + oy) * (128.f / 15.f) - 0.5f;
  p[2] = ((float)gx + ox) * (128.f / 15.f) - 0.5f;
}

// ---------------- trilinear grid sample + per-group k/v projection ----------------
__global__ __launch_bounds__(256) void gsample_kernel(const float* __restrict__ gt,
                                                      const float* __restrict__ pc,
                                                      const float* __restrict__ kw,
                                                      const float* __restrict__ vw,
                                                      float* __restrict__ kbuf,
                                                      float* __restrict__ vbuf) {
  __shared__ float kvv[8][33];
  __shared__ float kws[32][33], vws[32][33];
  const int swz = (blockIdx.x & 7) * 512 + (blockIdx.x >> 3);
  const int bg = swz >> 8, l0 = (swz & 255) * 8;
  const int g = bg & 7;
  const int s = threadIdx.x >> 5, c = threadIdx.x & 31;
  for (int i = threadIdx.x; i < 1024; i += 256) {
    kws[i >> 5][i & 31] = kw[g * 1024 + i];
    vws[i >> 5][i & 31] = vw[g * 1024 + i];
  }
  const int l = l0 + s;
  const float* p = pc + ((size_t)bg * LS + l) * 3;
  const float pz = p[0], py = p[1], px = p[2];
  const float zf = floorf(pz), yf = floorf(py), xf = floorf(px);
  const int z0 = (int)zf, y0 = (int)yf, x0 = (int)xf;
  const float fz = pz - zf, fy = py - yf, fx = px - xf;
  const float* vp = gt + (size_t)(bg * 32 + c) * (TV * HV * WV);
  float acc = 0.f;
#pragma unroll
  for (int dz = 0; dz < 2; ++dz) {
    const int z = z0 + dz;
    if ((unsigned)z >= (unsigned)TV) continue;
    const float wz = dz ? fz : 1.f - fz;
#pragma unroll
    for (int dy = 0; dy < 2; ++dy) {
      const int y = y0 + dy;
      if ((unsigned)y >= (unsigned)HV) continue;
      const float wzy = wz * (dy ? fy : 1.f - fy);
#pragma unroll
      for (int dx = 0; dx < 2; ++dx) {
        const int x = x0 + dx;
        if ((unsigned)x >= (unsigned)WV) continue;
        acc += wzy * (dx ? fx : 1.f - fx) * vp[((size_t)z * HV + y) * WV + x];
      }
    }
  }
  kvv[s][c] = acc;
  __syncthreads();
  float ka = 0.f, va = 0.f;
#pragma unroll
  for (int f = 0; f < 32; ++f) {
    const float kv = kvv[s][f];
    ka += kws[c][f] * kv;
    va += vws[c][f] * kv;
  }
  kbuf[((size_t)bg * LS + l) * 32 + c] = ka;
  vbuf[((size_t)bg * LS + l) * 32 + c] = va;
}

// ---------------- deformable attention v2: bf16 MFMA QK + PV ----------------
// block = (bg, 32-query tile): 512 blocks x 4 waves. wave = (qh = w>>1, kh = w&1).
// Per 64-key chunk: stage K bf16 [64][40] + V^T bf16 [32][72]; QK = 1 MFMA per
// 16-key tile (K=32 dims exactly); e written unnormalized to attn_out + bf16 Ps;
// PV = 2 MFMAs (K=64) accumulating f32x4. In-kernel normalize tail kept.
__global__ __launch_bounds__(256) void dattn_mfma_kernel(const float* __restrict__ qb,
                                                         const float* __restrict__ kbuf,
                                                         const float* __restrict__ vbuf,
                                                         float* __restrict__ da_o,
                                                         float* __restrict__ attn_out) {
  __shared__ ushort Qs[32][40];
  __shared__ ushort Ks[64][40];
  __shared__ ushort Vst[32][72];
  __shared__ ushort Ps[32][72];
  __shared__ float ssum_lds[4][16];
  __shared__ float invs[32];

  const int swz = (blockIdx.x & 7) * 64 + (blockIdx.x >> 3);
  const int bg = swz >> 5, qt = swz & 31;
  const int n0 = qt * 32;
  const int b = bg >> 3, g = bg & 7;
  const int tid = threadIdx.x;
  const int lane = tid & 63, wave = tid >> 6;
  const int qh = wave >> 1, kh = wave & 1;

  const float* kB = kbuf + (size_t)bg * LS * 32;
  const float* vB = vbuf + (size_t)bg * LS * 32;

  // stage Q (32 rows x 32 dims) -> bf16
  {
    const int r = tid >> 3, c4 = (tid & 7) * 4;
    float4 q4 = *(const float4*)(qb + ((size_t)(b * NQ + n0 + r)) * CM + g * DH + c4);
    Qs[r][c4 + 0] = f2bf(q4.x); Qs[r][c4 + 1] = f2bf(q4.y);
    Qs[r][c4 + 2] = f2bf(q4.z); Qs[r][c4 + 3] = f2bf(q4.w);
  }

  float ssum[4] = {0.f, 0.f, 0.f, 0.f};
  f32x4 accp = {};

  const int krow = tid >> 2, kc4 = (tid & 3) * 8;
  const int arow = lane & 15;
  const int ak8 = (lane >> 4) * 8;
  const int rrow = (lane >> 4) * 4;
  const int ccol = lane & 15;

#pragma unroll 1
  for (int c = 0; c < 32; ++c) {
    __syncthreads();  // prev PV done reading Ks/Vst/Ps (and Q stage at c=0)
    {
      float4 k0 = *(const float4*)(kB + (size_t)(c * 64 + krow) * 32 + kc4);
      float4 k1 = *(const float4*)(kB + (size_t)(c * 64 + krow) * 32 + kc4 + 4);
      float4 v0 = *(const float4*)(vB + (size_t)(c * 64 + krow) * 32 + kc4);
      float4 v1 = *(const float4*)(vB + (size_t)(c * 64 + krow) * 32 + kc4 + 4);
      Ks[krow][kc4 + 0] = f2bf(k0.x); Ks[krow][kc4 + 1] = f2bf(k0.y);
      Ks[krow][kc4 + 2] = f2bf(k0.z); Ks[krow][kc4 + 3] = f2bf(k0.w);
      Ks[krow][kc4 + 4] = f2bf(k1.x); Ks[krow][kc4 + 5] = f2bf(k1.y);
      Ks[krow][kc4 + 6] = f2bf(k1.z); Ks[krow][kc4 + 7] = f2bf(k1.w);
      Vst[kc4 + 0][krow] = f2bf(v0.x); Vst[kc4 + 1][krow] = f2bf(v0.y);
      Vst[kc4 + 2][krow] = f2bf(v0.z); Vst[kc4 + 3][krow] = f2bf(v0.w);
      Vst[kc4 + 4][krow] = f2bf(v1.x); Vst[kc4 + 5][krow] = f2bf(v1.y);
      Vst[kc4 + 6][krow] = f2bf(v1.z); Vst[kc4 + 7][krow] = f2bf(v1.w);
    }
    __syncthreads();
    // QK: tiles t = 2*kh, 2*kh+1 (16 keys each), K=32 dims = one MFMA
    bf16x8 aq = *(const bf16x8*)&Qs[qh * 16 + arow][ak8];
#pragma unroll
    for (int ti = 0; ti < 2; ++ti) {
      const int t = kh * 2 + ti;
      bf16x8 bk = *(const bf16x8*)&Ks[t * 16 + arow][ak8];
      f32x4 sc = {};
      sc = __builtin_amdgcn_mfma_f32_16x16x32_bf16(aq, bk, sc, 0, 0, 0);
#pragma unroll
      for (int reg = 0; reg < 4; ++reg) {
        const float e = __expf(sc[reg] * 0.17677669529663687f);
        ssum[reg] += e;
        attn_out[((size_t)(bg * NQ + n0 + qh * 16 + rrow + reg)) * LS + c * 64 + t * 16 + ccol] = e;
        Ps[qh * 16 + rrow + reg][t * 16 + ccol] = f2bf(e);
      }
    }
    __syncthreads();
    // PV: D(16q x 16d) tile (qh, dh=kh); 2 K-chunks over the 64 keys
    {
      bf16x8 ap0 = *(const bf16x8*)&Ps[qh * 16 + arow][ak8];
      bf16x8 bv0 = *(const bf16x8*)&Vst[kh * 16 + arow][ak8];
      accp = __builtin_amdgcn_mfma_f32_16x16x32_bf16(ap0, bv0, accp, 0, 0, 0);
      bf16x8 ap1 = *(const bf16x8*)&Ps[qh * 16 + arow][32 + ak8];
      bf16x8 bv1 = *(const bf16x8*)&Vst[kh * 16 + arow][32 + ak8];
      accp = __builtin_amdgcn_mfma_f32_16x16x32_bf16(ap1, bv1, accp, 0, 0, 0);
    }
  }

  // per-wave row sums (over this wave's 2 key-tiles x 32 chunks), reduce cols
#pragma unroll
  for (int reg = 0; reg < 4; ++reg) {
    float s = ssum[reg];
#pragma unroll
    for (int off = 1; off < 16; off <<= 1) s += __shfl_xor(s, off, 64);
    if ((lane & 15) == 0) ssum_lds[wave][rrow + reg] = s;
  }
  __syncthreads();
  if (tid < 32) {
    const int qh2 = tid >> 4, r = tid & 15;
    invs[tid] = 1.f / (ssum_lds[qh2 * 2][r] + ssum_lds[qh2 * 2 + 1][r]);
  }
  __syncthreads();

  // da_o write (normalized)
#pragma unroll
  for (int reg = 0; reg < 4; ++reg) {
    const int q = qh * 16 + rrow + reg;
    da_o[((size_t)(b * NQ + n0 + q)) * CM + g * DH + kh * 16 + ccol] = accp[reg] * invs[q];
  }

  // normalize attn rows in-place (L2-hot)
  const int nrow = tid >> 3;
  const float qinv = invs[nrow];
  float4* arow4 = (float4*)(attn_out + ((size_t)(bg * NQ + n0 + nrow)) * LS);
#pragma unroll 8
  for (int j = 0; j < 64; ++j) {
    const int col = (tid & 7) + j * 8;
    float4 a = arow4[col];
    a.x *= qinv; a.y *= qinv; a.z *= qinv; a.w *= qinv;
    arow4[col] = a;
  }
}

// ---------------- launch ----------------
extern "C" void kernel_launch(void* const* d_in, const int* in_sizes, int n_in,
                              void* d_out, int out_size, void* d_ws, size_t ws_size,
                              hipStream_t stream) {
  const float* query    = (const float*)d_in[0];
  const float* gt       = (const float*)d_in[1];
  const float* sa_in_w  = (const float*)d_in[2];
  const float* sa_in_b  = (const float*)d_in[3];
  const float* sa_out_w = (const float*)d_in[4];
  const float* sa_out_b = (const float*)d_in[5];
  const float* q_w      = (const float*)d_in[6];
  const float* off_w1   = (const float*)d_in[7];
  const float* off_b1   = (const float*)d_in[8];
  const float* off_w2   = (const float*)d_in[9];
  const float* k_w      = (const float*)d_in[10];
  const float* v_w      = (const float*)d_in[11];
  const float* da_out_w = (const float*)d_in[12];
  const float* da_out_b = (const float*)d_in[13];
  const float* lin1_w   = (const float*)d_in[14];
  const float* lin1_b   = (const float*)d_in[15];
  const float* lin2_w   = (const float*)d_in[16];
  const float* lin2_b   = (const float*)d_in[17];
  const float* ln1_w    = (const float*)d_in[18];
  const float* ln1_b    = (const float*)d_in[19];
  const float* ln2_w    = (const float*)d_in[20];
  const float* ln2_b    = (const float*)d_in[21];
  const float* ln3_w    = (const float*)d_in[22];
  const float* ln3_b    = (const float*)d_in[23];

  float* ws = (float*)d_ws;
  float* t1      = ws + 0;            // 524288
  float* t2      = ws + 524288;       // 524288
  float* off1    = ws + 1048576;      // 1048576
  float* pcoords = ws + 2097152;      // 98304
  float* k_buf   = ws + 2195456;      // 1048576
  float* v_buf   = ws + 3244032;      // 1048576
  float* q_buf   = ws + 4292608;      // 524288
  float* da_o    = ws + 4816896;      // 524288
  float* qkv_buf = ws + 5341184;      // 1572864
  float* sa_o    = ws + 6914048;      // 524288
  float* t0      = ws + 7438336;      // 524288
  float* u2      = ws + 7962624;      // 524288
  float* skp     = ws + 8486912;      // 4194304 (split-K8 partials)
  float* u3      = ws + 6291456;      // 524288  (reuses qkv region)
  __hip_bfloat16* t2bf   = (__hip_bfloat16*)(ws + 12681216);  // 262144 f
  __hip_bfloat16* w1bf   = (__hip_bfloat16*)(ws + 12943360);  // 262144 f
  __hip_bfloat16* w2bf   = (__hip_bfloat16*)(ws + 13205504);  // 262144 f
  __hip_bfloat16* hbufbf = (__hip_bfloat16*)(ws + 13467648);  // 2097152 f

  float* out_t    = (float*)d_out;
  float* out_attn = out_t + (size_t)MROWS * CM;

  castw_kernel<<<1024, 256, 0, stream>>>(lin1_w, lin2_w, w1bf, w2bf);
  gemm_nt128<false><<<dim3(MROWS / 128, 768 / 128), 256, 0, stream>>>(
      query, sa_in_w, sa_in_b, nullptr, qkv_buf, MROWS, 768, CM);
  sa_flash_kernel<<<1024, 256, 0, stream>>>(qkv_buf, sa_o);
  gemm_nt<false><<<dim3(MROWS / 64, CM / 64), 256, 0, stream>>>(
      sa_o, sa_out_w, sa_out_b, query, t0, MROWS, CM, CM);
  ln_kernel<<<512, 256, 0, stream>>>(t0, ln1_w, ln1_b, t1, nullptr);
  conv_off6_kernel<<<2048, 256, 0, stream>>>(gt, off_w1, off_b1, off1);
  offproj_kernel<<<128, 256, 0, stream>>>(off1, off_w2, pcoords);
  gsample_kernel<<<4096, 256, 0, stream>>>(gt, pcoords, k_w, v_w, k_buf, v_buf);
  gemm_nt<false><<<dim3(MROWS / 64, CM / 64), 256, 0, stream>>>(
      t1, q_w, nullptr, nullptr, q_buf, MROWS, CM, CM);
  dattn_mfma_kernel<<<512, 256, 0, stream>>>(q_buf, k_buf, v_buf, da_o, out_attn);
  gemm_nt<false><<<dim3(MROWS / 64, CM / 64), 256, 0, stream>>>(
      da_o, da_out_w, da_out_b, t1, u2, MROWS, CM, CM);
  ln_kernel<<<512, 256, 0, stream>>>(u2, ln2_w, ln2_b, t2, t2bf);
  gemm_bf16_mfma<true><<<dim3(MROWS / 128, FFD / 128, 1), 256, 0, stream>>>(
      (const ushort*)t2bf, (const ushort*)w1bf, lin1_b, hbufbf, nullptr,
      MROWS, FFD, CM, CM);
  gemm_bf16_mfma<false><<<dim3(MROWS / 128, CM / 128, 8), 256, 0, stream>>>(
      (const ushort*)hbufbf, (const ushort*)w2bf, nullptr, nullptr, skp,
      MROWS, CM, FFD, FFD / 8);
  skred8_kernel<<<512, 256, 0, stream>>>(skp, lin2_b, t2, u3);
  ln_kernel<<<512, 256, 0, stream>>>(u3, ln3_w, ln3_b, out_t, nullptr);
}

// Round 15
// 448.429 us; speedup vs baseline: 1.9667x; 1.2071x over previous
//
#include <hip/hip_runtime.h>
#include <hip/hip_bf16.h>

// ---------------- constants ----------------
#define BQ 2
#define NQ 1024
#define CM 256
#define HEADS 8
#define DH 32
#define FFD 2048
#define TV 16
#define HV 128
#define WV 128
#define TD 8
#define HD 16
#define WD 16
#define LS 2048
#define NG 16
#define MROWS 2048

typedef __attribute__((ext_vector_type(8))) short bf16x8;
typedef __attribute__((ext_vector_type(4))) float f32x4;

__device__ __forceinline__ ushort f2bf(float x) {
  __hip_bfloat16 h = __float2bfloat16(x);
  return *(ushort*)&h;
}

// ---------------- generic f32 NT GEMM 64x64: C = A@W^T (+bias)(+res)(+relu) ----------------
template <bool RELU>
__global__ __launch_bounds__(256) void gemm_nt(const float* __restrict__ A,
                                               const float* __restrict__ Wt,
                                               const float* __restrict__ bias,
                                               const float* __restrict__ res,
                                               float* __restrict__ C,
                                               int M, int N, int K) {
  __shared__ float As[16 * 68];
  __shared__ float Ws[16 * 68];
  const int tm = threadIdx.x & 15;
  const int tn = threadIdx.x >> 4;
  const int m0 = blockIdx.x * 64, n0 = blockIdx.y * 64;
  const int lr = threadIdx.x >> 2;
  const int lk = (threadIdx.x & 3) * 4;
  float acc[4][4] = {};
  for (int k0 = 0; k0 < K; k0 += 16) {
    float4 a4 = *(const float4*)(A + (size_t)(m0 + lr) * K + k0 + lk);
    float4 w4 = *(const float4*)(Wt + (size_t)(n0 + lr) * K + k0 + lk);
    As[(lk + 0) * 68 + lr] = a4.x;
    As[(lk + 1) * 68 + lr] = a4.y;
    As[(lk + 2) * 68 + lr] = a4.z;
    As[(lk + 3) * 68 + lr] = a4.w;
    Ws[(lk + 0) * 68 + lr] = w4.x;
    Ws[(lk + 1) * 68 + lr] = w4.y;
    Ws[(lk + 2) * 68 + lr] = w4.z;
    Ws[(lk + 3) * 68 + lr] = w4.w;
    __syncthreads();
#pragma unroll
    for (int k = 0; k < 16; ++k) {
      float4 av = *(const float4*)&As[k * 68 + tm * 4];
      float4 wv = *(const float4*)&Ws[k * 68 + tn * 4];
      float a[4] = {av.x, av.y, av.z, av.w};
      float w[4] = {wv.x, wv.y, wv.z, wv.w};
#pragma unroll
      for (int i = 0; i < 4; ++i)
#pragma unroll
        for (int j = 0; j < 4; ++j) acc[i][j] += a[i] * w[j];
    }
    __syncthreads();
  }
#pragma unroll
  for (int i = 0; i < 4; ++i) {
    const int row = m0 + tm * 4 + i;
    const int col = n0 + tn * 4;
    float4 bv = bias ? *(const float4*)(bias + col) : make_float4(0.f, 0.f, 0.f, 0.f);
    float4 rv = res ? *(const float4*)(res + (size_t)row * N + col) : make_float4(0.f, 0.f, 0.f, 0.f);
    float4 o;
    o.x = acc[i][0] + bv.x + rv.x;
    o.y = acc[i][1] + bv.y + rv.y;
    o.z = acc[i][2] + bv.z + rv.z;
    o.w = acc[i][3] + bv.w + rv.w;
    if (RELU) {
      o.x = fmaxf(o.x, 0.f); o.y = fmaxf(o.y, 0.f);
      o.z = fmaxf(o.z, 0.f); o.w = fmaxf(o.w, 0.f);
    }
    *(float4*)(C + (size_t)row * N + col) = o;
  }
}

// ---------------- cast f32 -> bf16: query, sa_in_w, lin1_w, lin2_w ----------------
__global__ __launch_bounds__(256) void castw4_kernel(const float* __restrict__ q,
                                                     const float* __restrict__ sw,
                                                     const float* __restrict__ w1,
                                                     const float* __restrict__ w2,
                                                     __hip_bfloat16* __restrict__ qb,
                                                     __hip_bfloat16* __restrict__ swb,
                                                     __hip_bfloat16* __restrict__ w1b,
                                                     __hip_bfloat16* __restrict__ w2b) {
  const int idx = blockIdx.x * 256 + threadIdx.x;   // 442368 float4s total
  const float4* src;
  __hip_bfloat16* dst;
  int off;
  if (idx < 131072)      { src = (const float4*)q;  dst = qb;  off = idx; }
  else if (idx < 180224) { src = (const float4*)sw; dst = swb; off = idx - 131072; }
  else if (idx < 311296) { src = (const float4*)w1; dst = w1b; off = idx - 180224; }
  else                   { src = (const float4*)w2; dst = w2b; off = idx - 311296; }
  float4 v = src[off];
  dst[off * 4 + 0] = __float2bfloat16(v.x);
  dst[off * 4 + 1] = __float2bfloat16(v.y);
  dst[off * 4 + 2] = __float2bfloat16(v.z);
  dst[off * 4 + 3] = __float2bfloat16(v.w);
}

// ---------------- bf16 MFMA NT GEMM, 128x128 tile, 4 waves (2x2), K-step 32 ----------------
// EPI 0: +bias, relu -> bf16 Cbf.  EPI 1: f32 partial -> Cf + z*M*N.  EPI 2: +bias -> f32 Cf.
template <int EPI>
__global__ __launch_bounds__(256) void gemm_bf16_mfma(const ushort* __restrict__ A,
                                                      const ushort* __restrict__ B,
                                                      const float* __restrict__ bias,
                                                      __hip_bfloat16* __restrict__ Cbf,
                                                      float* __restrict__ Cf,
                                                      int M, int N, int K, int kslen) {
  __shared__ ushort Asm[128][40];
  __shared__ ushort Bsm[128][40];
  const int tid = threadIdx.x;
  const int lane = tid & 63, wave = tid >> 6;
  const int wr = wave >> 1, wc = wave & 1;
  const int m0 = blockIdx.x * 128, n0 = blockIdx.y * 128;
  const int kb = blockIdx.z * kslen;
  f32x4 acc[4][4] = {};

  const int r0 = tid >> 1, c0 = (tid & 1) * 16;
  for (int k0 = kb; k0 < kb + kslen; k0 += 32) {
    uint4 ar0 = *(const uint4*)(A + (size_t)(m0 + r0) * K + k0 + c0);
    uint4 ar1 = *(const uint4*)(A + (size_t)(m0 + r0) * K + k0 + c0 + 8);
    uint4 br0 = *(const uint4*)(B + (size_t)(n0 + r0) * K + k0 + c0);
    uint4 br1 = *(const uint4*)(B + (size_t)(n0 + r0) * K + k0 + c0 + 8);
    __syncthreads();
    *(uint4*)&Asm[r0][c0] = ar0;
    *(uint4*)&Asm[r0][c0 + 8] = ar1;
    *(uint4*)&Bsm[r0][c0] = br0;
    *(uint4*)&Bsm[r0][c0 + 8] = br1;
    __syncthreads();
    bf16x8 af[4], bfr[4];
#pragma unroll
    for (int mi = 0; mi < 4; ++mi)
      af[mi] = *(const bf16x8*)&Asm[wr * 64 + mi * 16 + (lane & 15)][(lane >> 4) * 8];
#pragma unroll
    for (int ni = 0; ni < 4; ++ni)
      bfr[ni] = *(const bf16x8*)&Bsm[wc * 64 + ni * 16 + (lane & 15)][(lane >> 4) * 8];
#pragma unroll
    for (int mi = 0; mi < 4; ++mi)
#pragma unroll
      for (int ni = 0; ni < 4; ++ni)
        acc[mi][ni] = __builtin_amdgcn_mfma_f32_16x16x32_bf16(af[mi], bfr[ni], acc[mi][ni], 0, 0, 0);
  }

  const int rbase = (lane >> 4) * 4;
  const int cl = lane & 15;
#pragma unroll
  for (int mi = 0; mi < 4; ++mi) {
    const int rowb = m0 + wr * 64 + mi * 16 + rbase;
#pragma unroll
    for (int ni = 0; ni < 4; ++ni) {
      const int col = n0 + wc * 64 + ni * 16 + cl;
      if (EPI == 0) {
        const float bv = bias[col];
#pragma unroll
        for (int reg = 0; reg < 4; ++reg) {
          float x = acc[mi][ni][reg] + bv;
          x = fmaxf(x, 0.f);
          Cbf[(size_t)(rowb + reg) * N + col] = __float2bfloat16(x);
        }
      } else if (EPI == 1) {
        float* Pb = Cf + (size_t)blockIdx.z * M * N;
#pragma unroll
        for (int reg = 0; reg < 4; ++reg)
          Pb[(size_t)(rowb + reg) * N + col] = acc[mi][ni][reg];
      } else {
        const float bv = bias[col];
#pragma unroll
        for (int reg = 0; reg < 4; ++reg)
          Cf[(size_t)(rowb + reg) * N + col] = acc[mi][ni][reg] + bv;
      }
    }
  }
}

// ---------------- split-K(8) reduce (+bias+res), N = 256 ----------------
__global__ __launch_bounds__(256) void skred8_kernel(const float* __restrict__ P,
                                                     const float* __restrict__ bias,
                                                     const float* __restrict__ res,
                                                     float* __restrict__ C) {
  const int idx = blockIdx.x * 256 + threadIdx.x;
  const int col4 = idx & 63;
  const int row = idx >> 6;
  const float4* P4 = (const float4*)P;
  const int MN4 = MROWS * CM / 4;
  float4 s = make_float4(0.f, 0.f, 0.f, 0.f);
#pragma unroll
  for (int sl = 0; sl < 8; ++sl) {
    float4 p = P4[idx + sl * MN4];
    s.x += p.x; s.y += p.y; s.z += p.z; s.w += p.w;
  }
  float4 bv = ((const float4*)bias)[col4];
  float4 rv = ((const float4*)(res + (size_t)row * CM))[col4];
  s.x += bv.x + rv.x; s.y += bv.y + rv.y;
  s.z += bv.z + rv.z; s.w += bv.w + rv.w;
  ((float4*)C)[idx] = s;
}

// ---------------- self-attention v2: bf16 MFMA flash (no attn output) ----------------
// block = (bh, 32-query tile): 512 blocks x 4 waves (qh = w>>1, kh = w&1).
// K/V from qkv rows (stride 768, +256/+512). 16 chunks of 64 keys.
__global__ __launch_bounds__(256) void sa_mfma_kernel(const float* __restrict__ qkv,
                                                      float* __restrict__ o) {
  __shared__ ushort Qs[32][40];
  __shared__ ushort Ks[64][40];
  __shared__ ushort Vst[32][72];
  __shared__ ushort Ps[32][72];
  __shared__ float ssum_lds[4][16];
  __shared__ float invs[32];

  const int swz = (blockIdx.x & 7) * 64 + (blockIdx.x >> 3);
  const int bh = swz >> 5, qt = swz & 31;
  const int n0 = qt * 32;
  const int b = bh >> 3, h = bh & 7;
  const int tid = threadIdx.x;
  const int lane = tid & 63, wave = tid >> 6;
  const int qh = wave >> 1, kh = wave & 1;

  const float* rowbase = qkv + (size_t)b * NQ * 768 + h * DH;

  {
    const int r = tid >> 3, c4 = (tid & 7) * 4;
    float4 q4 = *(const float4*)(rowbase + (size_t)(n0 + r) * 768 + c4);
    Qs[r][c4 + 0] = f2bf(q4.x); Qs[r][c4 + 1] = f2bf(q4.y);
    Qs[r][c4 + 2] = f2bf(q4.z); Qs[r][c4 + 3] = f2bf(q4.w);
  }

  float ssum[4] = {0.f, 0.f, 0.f, 0.f};
  f32x4 accp = {};

  const int krow = tid >> 2, kc4 = (tid & 3) * 8;
  const int arow = lane & 15;
  const int ak8 = (lane >> 4) * 8;
  const int rrow = (lane >> 4) * 4;
  const int ccol = lane & 15;

#pragma unroll 1
  for (int c = 0; c < 16; ++c) {
    __syncthreads();
    {
      const float* kp = rowbase + (size_t)(c * 64 + krow) * 768 + 256 + kc4;
      const float* vp = rowbase + (size_t)(c * 64 + krow) * 768 + 512 + kc4;
      float4 k0 = *(const float4*)kp;
      float4 k1 = *(const float4*)(kp + 4);
      float4 v0 = *(const float4*)vp;
      float4 v1 = *(const float4*)(vp + 4);
      Ks[krow][kc4 + 0] = f2bf(k0.x); Ks[krow][kc4 + 1] = f2bf(k0.y);
      Ks[krow][kc4 + 2] = f2bf(k0.z); Ks[krow][kc4 + 3] = f2bf(k0.w);
      Ks[krow][kc4 + 4] = f2bf(k1.x); Ks[krow][kc4 + 5] = f2bf(k1.y);
      Ks[krow][kc4 + 6] = f2bf(k1.z); Ks[krow][kc4 + 7] = f2bf(k1.w);
      Vst[kc4 + 0][krow] = f2bf(v0.x); Vst[kc4 + 1][krow] = f2bf(v0.y);
      Vst[kc4 + 2][krow] = f2bf(v0.z); Vst[kc4 + 3][krow] = f2bf(v0.w);
      Vst[kc4 + 4][krow] = f2bf(v1.x); Vst[kc4 + 5][krow] = f2bf(v1.y);
      Vst[kc4 + 6][krow] = f2bf(v1.z); Vst[kc4 + 7][krow] = f2bf(v1.w);
    }
    __syncthreads();
    bf16x8 aq = *(const bf16x8*)&Qs[qh * 16 + arow][ak8];
#pragma unroll
    for (int ti = 0; ti < 2; ++ti) {
      const int t = kh * 2 + ti;
      bf16x8 bk = *(const bf16x8*)&Ks[t * 16 + arow][ak8];
      f32x4 sc = {};
      sc = __builtin_amdgcn_mfma_f32_16x16x32_bf16(aq, bk, sc, 0, 0, 0);
#pragma unroll
      for (int reg = 0; reg < 4; ++reg) {
        const float e = __expf(sc[reg] * 0.17677669529663687f);
        ssum[reg] += e;
        Ps[qh * 16 + rrow + reg][t * 16 + ccol] = f2bf(e);
      }
    }
    __syncthreads();
    {
      bf16x8 ap0 = *(const bf16x8*)&Ps[qh * 16 + arow][ak8];
      bf16x8 bv0 = *(const bf16x8*)&Vst[kh * 16 + arow][ak8];
      accp = __builtin_amdgcn_mfma_f32_16x16x32_bf16(ap0, bv0, accp, 0, 0, 0);
      bf16x8 ap1 = *(const bf16x8*)&Ps[qh * 16 + arow][32 + ak8];
      bf16x8 bv1 = *(const bf16x8*)&Vst[kh * 16 + arow][32 + ak8];
      accp = __builtin_amdgcn_mfma_f32_16x16x32_bf16(ap1, bv1, accp, 0, 0, 0);
    }
  }

#pragma unroll
  for (int reg = 0; reg < 4; ++reg) {
    float s = ssum[reg];
#pragma unroll
    for (int off = 1; off < 16; off <<= 1) s += __shfl_xor(s, off, 64);
    if ((lane & 15) == 0) ssum_lds[wave][rrow + reg] = s;
  }
  __syncthreads();
  if (tid < 32) {
    const int qh2 = tid >> 4, r = tid & 15;
    invs[tid] = 1.f / (ssum_lds[qh2 * 2][r] + ssum_lds[qh2 * 2 + 1][r]);
  }
  __syncthreads();

#pragma unroll
  for (int reg = 0; reg < 4; ++reg) {
    const int q = qh * 16 + rrow + reg;
    o[((size_t)(b * NQ + n0 + q)) * CM + h * DH + kh * 16 + ccol] = accp[reg] * invs[q];
  }
}

// ---------------- layer norm; optional extra bf16 output ----------------
__global__ __launch_bounds__(256) void ln_kernel(const float* __restrict__ in,
                                                 const float* __restrict__ w,
                                                 const float* __restrict__ b,
                                                 float* __restrict__ out,
                                                 __hip_bfloat16* __restrict__ out_bf) {
  const int wv = threadIdx.x >> 6, lane = threadIdx.x & 63;
  const int row = blockIdx.x * 4 + wv;
  float4 v = ((const float4*)(in + (size_t)row * CM))[lane];
  float s = v.x + v.y + v.z + v.w;
#pragma unroll
  for (int off = 32; off > 0; off >>= 1) s += __shfl_xor(s, off, 64);
  const float mu = s * (1.f / 256.f);
  float dx = v.x - mu, dy = v.y - mu, dz = v.z - mu, dw = v.w - mu;
  float q = dx * dx + dy * dy + dz * dz + dw * dw;
#pragma unroll
  for (int off = 32; off > 0; off >>= 1) q += __shfl_xor(q, off, 64);
  const float r = rsqrtf(q * (1.f / 256.f) + 1e-5f);
  float4 wv4 = ((const float4*)w)[lane];
  float4 bv4 = ((const float4*)b)[lane];
  float4 o;
  o.x = dx * r * wv4.x + bv4.x;
  o.y = dy * r * wv4.y + bv4.y;
  o.z = dz * r * wv4.z + bv4.z;
  o.w = dw * r * wv4.w + bv4.w;
  ((float4*)(out + (size_t)row * CM))[lane] = o;
  if (out_bf) {
    __hip_bfloat16* op = out_bf + (size_t)row * CM + lane * 4;
    op[0] = __float2bfloat16(o.x);
    op[1] = __float2bfloat16(o.y);
    op[2] = __float2bfloat16(o.z);
    op[3] = __float2bfloat16(o.w);
  }
}

// ---------------- depthwise strided conv v6: double-buffered LDS staging ----
__global__ __launch_bounds__(256) void conv_off6_kernel(const float* __restrict__ gt,
                                                        const float* __restrict__ w1,
                                                        const float* __restrict__ b1,
                                                        float* __restrict__ off1) {
  const int bid = blockIdx.x;
  const int yh = bid & 1, zh = (bid >> 1) & 1, cid = bid >> 2;
  const int c = cid & 31;
  const int tid = threadIdx.x;
  const int xo = tid & 15;
  const int yo8 = (tid >> 4) & 7;
  const int zoq = tid >> 7;
  __shared__ float wsm[400];
  __shared__ float pl[2][66 * 128];
  for (int i = tid; i < 400; i += 256) wsm[i] = w1[c * 400 + i];

  const float* __restrict__ xp = gt + (size_t)cid * (TV * HV * WV);
  const int zo0 = zh * 4 + zoq * 2;
  const int ygbase = yh * 64 - 1;
  const int zlo = zh ? 7 : 0;
  const int zhi = zh ? 15 : 8;
  float acc0 = 0.f, acc1 = 0.f;
  float4 rv[9];

  {
    const float* __restrict__ zp = xp + (size_t)zlo * (HV * WV);
#pragma unroll
    for (int k = 0; k < 9; ++k) {
      const int i = tid + k * 256;
      if (i < 2112) {
        const int r = i >> 5, f = i & 31;
        const int y = ygbase + r;
        float4 v = make_float4(0.f, 0.f, 0.f, 0.f);
        if ((unsigned)y < 128u) v = *(const float4*)(zp + y * WV + 4 * f);
        const int fp = f ^ ((r >> 3) & 3);
        *(float4*)&pl[0][r * 128 + 4 * fp] = v;
      }
    }
  }
  __syncthreads();

  int cur = 0;
#pragma unroll 1
  for (int z = zlo; z <= zhi; ++z) {
    if (z < zhi) {
      const float* __restrict__ zp = xp + (size_t)(z + 1) * (HV * WV);
#pragma unroll
      for (int k = 0; k < 9; ++k) {
        const int i = tid + k * 256;
        rv[k] = make_float4(0.f, 0.f, 0.f, 0.f);
        if (i < 2112) {
          const int y = ygbase + (i >> 5);
          if ((unsigned)y < 128u) rv[k] = *(const float4*)(zp + y * WV + 4 * (i & 31));
        }
      }
    }
    {
      const int kzA = z + 1 - 2 * zo0;
      const int kzB = kzA - 2;
      const bool actA = (unsigned)kzA <= 3u;
      const bool actB = (unsigned)kzB <= 3u;
      if (actA || actB) {
        const float* __restrict__ wrA = wsm + (actA ? kzA : 0) * 100;
        const float* __restrict__ wrB = wsm + (actB ? kzB : 0) * 100;
#pragma unroll 2
        for (int ky = 0; ky < 10; ++ky) {
          const int r = yo8 * 8 + ky;
          const int s = (r >> 3) & 3;
          const float* __restrict__ rp = &pl[cur][r * 128];
          const float4 a0 = *(const float4*)&rp[((2 * xo) ^ s) * 4];
          const float4 a1 = *(const float4*)&rp[((2 * xo + 1) ^ s) * 4];
          float left = 0.f, right = 0.f;
          if (xo > 0) {
            const int cc = 8 * xo - 1;
            left = rp[((((cc >> 2) ^ s)) << 2) | (cc & 3)];
          }
          if (xo < 15) {
            const int cc = 8 * xo + 8;
            right = rp[((((cc >> 2) ^ s)) << 2) | (cc & 3)];
          }
          if (actA) {
            const float* __restrict__ w = wrA + ky * 10;
            acc0 += w[0] * left + w[1] * a0.x + w[2] * a0.y + w[3] * a0.z + w[4] * a0.w +
                    w[5] * a1.x + w[6] * a1.y + w[7] * a1.z + w[8] * a1.w + w[9] * right;
          }
          if (actB) {
            const float* __restrict__ w = wrB + ky * 10;
            acc1 += w[0] * left + w[1] * a0.x + w[2] * a0.y + w[3] * a0.z + w[4] * a0.w +
                    w[5] * a1.x + w[6] * a1.y + w[7] * a1.z + w[8] * a1.w + w[9] * right;
          }
        }
      }
    }
    if (z < zhi) {
#pragma unroll
      for (int k = 0; k < 9; ++k) {
        const int i = tid + k * 256;
        if (i < 2112) {
          const int r = i >> 5, f = i & 31;
          const int fp = f ^ ((r >> 3) & 3);
          *(float4*)&pl[cur ^ 1][r * 128 + 4 * fp] = rv[k];
        }
      }
    }
    __syncthreads();
    cur ^= 1;
  }

  const float bias = b1[c];
  const int yout = yh * 8 + yo8;
  {
    float a = acc0 + bias;
    const float u = 0.7978845608028654f * (a + 0.044715f * a * a * a);
    const float gv = 0.5f * a * (1.f + tanhf(u));
    off1[((size_t)cid * TD + zo0) * (HD * WD) + yout * WD + xo] = gv;
  }
  {
    float a = acc1 + bias;
    const float u = 0.7978845608028654f * (a + 0.044715f * a * a * a);
    const float gv = 0.5f * a * (1.f + tanhf(u));
    off1[((size_t)cid * TD + zo0 + 1) * (HD * WD) + yout * WD + xo] = gv;
  }
}

// ---------------- offset projection + tanh*scale + pixel coords ----------------
__global__ __launch_bounds__(256) void offproj_kernel(const float* __restrict__ off1,
                                                      const float* __restrict__ w2,
                                                      float* __restrict__ pc) {
  const int gid = blockIdx.x * 256 + threadIdx.x;
  const int bg = gid >> 11, sp = gid & 2047;
  const float* base = off1 + (size_t)bg * 32 * LS + sp;
  float o0 = 0.f, o1 = 0.f, o2 = 0.f;
#pragma unroll
  for (int c = 0; c < 32; ++c) {
    const float v = base[(size_t)c * LS];
    o0 += w2[c] * v;
    o1 += w2[32 + c] * v;
    o2 += w2[64 + c] * v;
  }
  const int gz = sp >> 8, gy = (sp >> 4) & 15, gx = sp & 15;
  const float oz = tanhf(o0) * 2.f;
  const float oy = tanhf(o1) * 8.f;
  const float ox = tanhf(o2) * 8.f;
  float* p = pc + (size_t)gid * 3;
  p[0] = ((float)gz + oz) * (16.f / 7.f) - 0.5f;
  p[1] = ((float)gy + oy) * (128.f / 15.f) - 0.5f;
  p[2] = ((float)gx + ox) * (128.f / 15.f) - 0.5f;
}

// ---------------- trilinear grid sample + per-group k/v projection ----------------
__global__ __launch_bounds__(256) void gsample_kernel(const float* __restrict__ gt,
                                                      const float* __restrict__ pc,
                                                      const float* __restrict__ kw,
                                                      const float* __restrict__ vw,
                                                      float* __restrict__ kbuf,
                                                      float* __restrict__ vbuf) {
  __shared__ float kvv[8][33];
  __shared__ float kws[32][33], vws[32][33];
  const int swz = (blockIdx.x & 7) * 512 + (blockIdx.x >> 3);
  const int bg = swz >> 8, l0 = (swz & 255) * 8;
  const int g = bg & 7;
  const int s = threadIdx.x >> 5, c = threadIdx.x & 31;
  for (int i = threadIdx.x; i < 1024; i += 256) {
    kws[i >> 5][i & 31] = kw[g * 1024 + i];
    vws[i >> 5][i & 31] = vw[g * 1024 + i];
  }
  const int l = l0 + s;
  const float* p = pc + ((size_t)bg * LS + l) * 3;
  const float pz = p[0], py = p[1], px = p[2];
  const float zf = floorf(pz), yf = floorf(py), xf = floorf(px);
  const int z0 = (int)zf, y0 = (int)yf, x0 = (int)xf;
  const float fz = pz - zf, fy = py - yf, fx = px - xf;
  const float* vp = gt + (size_t)(bg * 32 + c) * (TV * HV * WV);
  float acc = 0.f;
#pragma unroll
  for (int dz = 0; dz < 2; ++dz) {
    const int z = z0 + dz;
    if ((unsigned)z >= (unsigned)TV) continue;
    const float wz = dz ? fz : 1.f - fz;
#pragma unroll
    for (int dy = 0; dy < 2; ++dy) {
      const int y = y0 + dy;
      if ((unsigned)y >= (unsigned)HV) continue;
      const float wzy = wz * (dy ? fy : 1.f - fy);
#pragma unroll
      for (int dx = 0; dx < 2; ++dx) {
        const int x = x0 + dx;
        if ((unsigned)x >= (unsigned)WV) continue;
        acc += wzy * (dx ? fx : 1.f - fx) * vp[((size_t)z * HV + y) * WV + x];
      }
    }
  }
  kvv[s][c] = acc;
  __syncthreads();
  float ka = 0.f, va = 0.f;
#pragma unroll
  for (int f = 0; f < 32; ++f) {
    const float kv = kvv[s][f];
    ka += kws[c][f] * kv;
    va += vws[c][f] * kv;
  }
  kbuf[((size_t)bg * LS + l) * 32 + c] = ka;
  vbuf[((size_t)bg * LS + l) * 32 + c] = va;
}

// ---------------- deformable attention v2: bf16 MFMA QK + PV ----------------
__global__ __launch_bounds__(256) void dattn_mfma_kernel(const float* __restrict__ qb,
                                                         const float* __restrict__ kbuf,
                                                         const float* __restrict__ vbuf,
                                                         float* __restrict__ da_o,
                                                         float* __restrict__ attn_out) {
  __shared__ ushort Qs[32][40];
  __shared__ ushort Ks[64][40];
  __shared__ ushort Vst[32][72];
  __shared__ ushort Ps[32][72];
  __shared__ float ssum_lds[4][16];
  __shared__ float invs[32];

  const int swz = (blockIdx.x & 7) * 64 + (blockIdx.x >> 3);
  const int bg = swz >> 5, qt = swz & 31;
  const int n0 = qt * 32;
  const int b = bg >> 3, g = bg & 7;
  const int tid = threadIdx.x;
  const int lane = tid & 63, wave = tid >> 6;
  const int qh = wave >> 1, kh = wave & 1;

  const float* kB = kbuf + (size_t)bg * LS * 32;
  const float* vB = vbuf + (size_t)bg * LS * 32;

  {
    const int r = tid >> 3, c4 = (tid & 7) * 4;
    float4 q4 = *(const float4*)(qb + ((size_t)(b * NQ + n0 + r)) * CM + g * DH + c4);
    Qs[r][c4 + 0] = f2bf(q4.x); Qs[r][c4 + 1] = f2bf(q4.y);
    Qs[r][c4 + 2] = f2bf(q4.z); Qs[r][c4 + 3] = f2bf(q4.w);
  }

  float ssum[4] = {0.f, 0.f, 0.f, 0.f};
  f32x4 accp = {};

  const int krow = tid >> 2, kc4 = (tid & 3) * 8;
  const int arow = lane & 15;
  const int ak8 = (lane >> 4) * 8;
  const int rrow = (lane >> 4) * 4;
  const int ccol = lane & 15;

#pragma unroll 1
  for (int c = 0; c < 32; ++c) {
    __syncthreads();
    {
      float4 k0 = *(const float4*)(kB + (size_t)(c * 64 + krow) * 32 + kc4);
      float4 k1 = *(const float4*)(kB + (size_t)(c * 64 + krow) * 32 + kc4 + 4);
      float4 v0 = *(const float4*)(vB + (size_t)(c * 64 + krow) * 32 + kc4);
      float4 v1 = *(const float4*)(vB + (size_t)(c * 64 + krow) * 32 + kc4 + 4);
      Ks[krow][kc4 + 0] = f2bf(k0.x); Ks[krow][kc4 + 1] = f2bf(k0.y);
      Ks[krow][kc4 + 2] = f2bf(k0.z); Ks[krow][kc4 + 3] = f2bf(k0.w);
      Ks[krow][kc4 + 4] = f2bf(k1.x); Ks[krow][kc4 + 5] = f2bf(k1.y);
      Ks[krow][kc4 + 6] = f2bf(k1.z); Ks[krow][kc4 + 7] = f2bf(k1.w);
      Vst[kc4 + 0][krow] = f2bf(v0.x); Vst[kc4 + 1][krow] = f2bf(v0.y);
      Vst[kc4 + 2][krow] = f2bf(v0.z); Vst[kc4 + 3][krow] = f2bf(v0.w);
      Vst[kc4 + 4][krow] = f2bf(v1.x); Vst[kc4 + 5][krow] = f2bf(v1.y);
      Vst[kc4 + 6][krow] = f2bf(v1.z); Vst[kc4 + 7][krow] = f2bf(v1.w);
    }
    __syncthreads();
    bf16x8 aq = *(const bf16x8*)&Qs[qh * 16 + arow][ak8];
#pragma unroll
    for (int ti = 0; ti < 2; ++ti) {
      const int t = kh * 2 + ti;
      bf16x8 bk = *(const bf16x8*)&Ks[t * 16 + arow][ak8];
      f32x4 sc = {};
      sc = __builtin_amdgcn_mfma_f32_16x16x32_bf16(aq, bk, sc, 0, 0, 0);
#pragma unroll
      for (int reg = 0; reg < 4; ++reg) {
        const float e = __expf(sc[reg] * 0.17677669529663687f);
        ssum[reg] += e;
        attn_out[((size_t)(bg * NQ + n0 + qh * 16 + rrow + reg)) * LS + c * 64 + t * 16 + ccol] = e;
        Ps[qh * 16 + rrow + reg][t * 16 + ccol] = f2bf(e);
      }
    }
    __syncthreads();
    {
      bf16x8 ap0 = *(const bf16x8*)&Ps[qh * 16 + arow][ak8];
      bf16x8 bv0 = *(const bf16x8*)&Vst[kh * 16 + arow][ak8];
      accp = __builtin_amdgcn_mfma_f32_16x16x32_bf16(ap0, bv0, accp, 0, 0, 0);
      bf16x8 ap1 = *(const bf16x8*)&Ps[qh * 16 + arow][32 + ak8];
      bf16x8 bv1 = *(const bf16x8*)&Vst[kh * 16 + arow][32 + ak8];
      accp = __builtin_amdgcn_mfma_f32_16x16x32_bf16(ap1, bv1, accp, 0, 0, 0);
    }
  }

#pragma unroll
  for (int reg = 0; reg < 4; ++reg) {
    float s = ssum[reg];
#pragma unroll
    for (int off = 1; off < 16; off <<= 1) s += __shfl_xor(s, off, 64);
    if ((lane & 15) == 0) ssum_lds[wave][rrow + reg] = s;
  }
  __syncthreads();
  if (tid < 32) {
    const int qh2 = tid >> 4, r = tid & 15;
    invs[tid] = 1.f / (ssum_lds[qh2 * 2][r] + ssum_lds[qh2 * 2 + 1][r]);
  }
  __syncthreads();

#pragma unroll
  for (int reg = 0; reg < 4; ++reg) {
    const int q = qh * 16 + rrow + reg;
    da_o[((size_t)(b * NQ + n0 + q)) * CM + g * DH + kh * 16 + ccol] = accp[reg] * invs[q];
  }

  const int nrow = tid >> 3;
  const float qinv = invs[nrow];
  float4* arow4 = (float4*)(attn_out + ((size_t)(bg * NQ + n0 + nrow)) * LS);
#pragma unroll 8
  for (int j = 0; j < 64; ++j) {
    const int col = (tid & 7) + j * 8;
    float4 a = arow4[col];
    a.x *= qinv; a.y *= qinv; a.z *= qinv; a.w *= qinv;
    arow4[col] = a;
  }
}

// ---------------- launch ----------------
extern "C" void kernel_launch(void* const* d_in, const int* in_sizes, int n_in,
                              void* d_out, int out_size, void* d_ws, size_t ws_size,
                              hipStream_t stream) {
  const float* query    = (const float*)d_in[0];
  const float* gt       = (const float*)d_in[1];
  const float* sa_in_w  = (const float*)d_in[2];
  const float* sa_in_b  = (const float*)d_in[3];
  const float* sa_out_w = (const float*)d_in[4];
  const float* sa_out_b = (const float*)d_in[5];
  const float* q_w      = (const float*)d_in[6];
  const float* off_w1   = (const float*)d_in[7];
  const float* off_b1   = (const float*)d_in[8];
  const float* off_w2   = (const float*)d_in[9];
  const float* k_w      = (const float*)d_in[10];
  const float* v_w      = (const float*)d_in[11];
  const float* da_out_w = (const float*)d_in[12];
  const float* da_out_b = (const float*)d_in[13];
  const float* lin1_w   = (const float*)d_in[14];
  const float* lin1_b   = (const float*)d_in[15];
  const float* lin2_w   = (const float*)d_in[16];
  const float* lin2_b   = (const float*)d_in[17];
  const float* ln1_w    = (const float*)d_in[18];
  const float* ln1_b    = (const float*)d_in[19];
  const float* ln2_w    = (const float*)d_in[20];
  const float* ln2_b    = (const float*)d_in[21];
  const float* ln3_w    = (const float*)d_in[22];
  const float* ln3_b    = (const float*)d_in[23];

  float* ws = (float*)d_ws;
  float* t1      = ws + 0;            // 524288
  float* t2      = ws + 524288;       // 524288
  float* off1    = ws + 1048576;      // 1048576
  float* pcoords = ws + 2097152;      // 98304
  float* k_buf   = ws + 2195456;      // 1048576
  float* v_buf   = ws + 3244032;      // 1048576
  float* q_buf   = ws + 4292608;      // 524288
  float* da_o    = ws + 4816896;      // 524288
  float* qkv_buf = ws + 5341184;      // 1572864
  float* sa_o    = ws + 6914048;      // 524288
  float* t0      = ws + 7438336;      // 524288
  float* u2      = ws + 7962624;      // 524288
  float* skp     = ws + 8486912;      // 4194304 (split-K8 partials; free early)
  float* u3      = ws + 6291456;      // 524288  (reuses qkv region)
  // early-phase bf16 (overlap skp region — disjoint lifetimes):
  __hip_bfloat16* qbf    = (__hip_bfloat16*)(ws + 8486912);   // 524288 bf16 = 262144 f
  __hip_bfloat16* sawbf  = (__hip_bfloat16*)(ws + 8749056);   // 196608 bf16 =  98304 f
  // late-phase bf16 tail:
  __hip_bfloat16* t2bf   = (__hip_bfloat16*)(ws + 12681216);  // 262144 f
  __hip_bfloat16* w1bf   = (__hip_bfloat16*)(ws + 12943360);  // 262144 f
  __hip_bfloat16* w2bf   = (__hip_bfloat16*)(ws + 13205504);  // 262144 f
  __hip_bfloat16* hbufbf = (__hip_bfloat16*)(ws + 13467648);  // 2097152 f

  float* out_t    = (float*)d_out;
  float* out_attn = out_t + (size_t)MROWS * CM;

  castw4_kernel<<<1728, 256, 0, stream>>>(query, sa_in_w, lin1_w, lin2_w,
                                          qbf, sawbf, w1bf, w2bf);
  // qkv projection: bf16 MFMA, +bias -> f32
  gemm_bf16_mfma<2><<<dim3(MROWS / 128, 768 / 128, 1), 256, 0, stream>>>(
      (const ushort*)qbf, (const ushort*)sawbf, sa_in_b, nullptr, qkv_buf,
      MROWS, 768, CM, CM);
  sa_mfma_kernel<<<512, 256, 0, stream>>>(qkv_buf, sa_o);
  gemm_nt<false><<<dim3(MROWS / 64, CM / 64), 256, 0, stream>>>(
      sa_o, sa_out_w, sa_out_b, query, t0, MROWS, CM, CM);
  ln_kernel<<<512, 256, 0, stream>>>(t0, ln1_w, ln1_b, t1, nullptr);
  conv_off6_kernel<<<2048, 256, 0, stream>>>(gt, off_w1, off_b1, off1);
  offproj_kernel<<<128, 256, 0, stream>>>(off1, off_w2, pcoords);
  gsample_kernel<<<4096, 256, 0, stream>>>(gt, pcoords, k_w, v_w, k_buf, v_buf);
  gemm_nt<false><<<dim3(MROWS / 64, CM / 64), 256, 0, stream>>>(
      t1, q_w, nullptr, nullptr, q_buf, MROWS, CM, CM);
  dattn_mfma_kernel<<<512, 256, 0, stream>>>(q_buf, k_buf, v_buf, da_o, out_attn);
  gemm_nt<false><<<dim3(MROWS / 64, CM / 64), 256, 0, stream>>>(
      da_o, da_out_w, da_out_b, t1, u2, MROWS, CM, CM);
  ln_kernel<<<512, 256, 0, stream>>>(u2, ln2_w, ln2_b, t2, t2bf);
  gemm_bf16_mfma<0><<<dim3(MROWS / 128, FFD / 128, 1), 256, 0, stream>>>(
      (const ushort*)t2bf, (const ushort*)w1bf, lin1_b, hbufbf, nullptr,
      MROWS, FFD, CM, CM);
  gemm_bf16_mfma<1><<<dim3(MROWS / 128, CM / 128, 8), 256, 0, stream>>>(
      (const ushort*)hbufbf, (const ushort*)w2bf, nullptr, nullptr, skp,
      MROWS, CM, FFD, FFD / 8);
  skred8_kernel<<<512, 256, 0, stream>>>(skp, lin2_b, t2, u3);
  ln_kernel<<<512, 256, 0, stream>>>(u3, ln3_w, ln3_b, out_t, nullptr);
}